// Round 1
// baseline (11675.706 us; speedup 1.0000x reference)
//
#include <hip/hip_runtime.h>
#include <math.h>

#define LNUM 4
#define H 16
#define D 1024
#define HS 64
#define DFF 5120
#define V 32000
#define BB 2
#define T 1024
#define M (BB*T)          // 2048 rows in the token stream
#define EPS 1e-5f

// ---------------------------------------------------------------------------
// embed: x[b,t,:] = tok_emb[idx[b,t],:] + pos_emb[t,:]
// ---------------------------------------------------------------------------
__global__ __launch_bounds__(256) void embed_kernel(const int* __restrict__ idx,
        const float* __restrict__ tok, const float* __restrict__ pos,
        float* __restrict__ x) {
    int row = blockIdx.x;              // b*T + t
    int t = row & (T - 1);
    int tok_id = idx[row];
    int c = threadIdx.x * 4;
    float4 a = *(const float4*)&tok[(size_t)tok_id * D + c];
    float4 p = *(const float4*)&pos[(size_t)t * D + c];
    a.x += p.x; a.y += p.y; a.z += p.z; a.w += p.w;
    *(float4*)&x[(size_t)row * D + c] = a;
}

// ---------------------------------------------------------------------------
// block-wide sum over 256 threads (4 waves)
// ---------------------------------------------------------------------------
__device__ __forceinline__ float block_sum256(float v, float* red) {
    #pragma unroll
    for (int off = 32; off > 0; off >>= 1) v += __shfl_down(v, off, 64);
    int lane = threadIdx.x & 63, w = threadIdx.x >> 6;
    __syncthreads();                    // protect red from previous use
    if (lane == 0) red[w] = v;
    __syncthreads();
    return red[0] + red[1] + red[2] + red[3];
}

// ---------------------------------------------------------------------------
// ln: out = (x-mu)/sqrt(var+eps)*g + b   (one block per row, D=1024)
// ---------------------------------------------------------------------------
__global__ __launch_bounds__(256) void ln_kernel(const float* __restrict__ in,
        const float* __restrict__ g, const float* __restrict__ b,
        float* __restrict__ out) {
    __shared__ float red[4];
    int row = blockIdx.x;
    int c = threadIdx.x * 4;
    float4 xv = *(const float4*)&in[(size_t)row * D + c];
    float mu = block_sum256(xv.x + xv.y + xv.z + xv.w, red) * (1.0f / D);
    float d0 = xv.x - mu, d1 = xv.y - mu, d2 = xv.z - mu, d3 = xv.w - mu;
    float var = block_sum256(d0*d0 + d1*d1 + d2*d2 + d3*d3, red) * (1.0f / D);
    float rs = rsqrtf(var + EPS);
    float4 gv = *(const float4*)&g[c];
    float4 bv = *(const float4*)&b[c];
    float4 o;
    o.x = d0 * rs * gv.x + bv.x;
    o.y = d1 * rs * gv.y + bv.y;
    o.z = d2 * rs * gv.z + bv.z;
    o.w = d3 * rs * gv.w + bv.w;
    *(float4*)&out[(size_t)row * D + c] = o;
}

// ---------------------------------------------------------------------------
// ln2_res: out = res + ln(ln(f, g1,b1), g2,b2)    (the quirky FFN tail)
// ---------------------------------------------------------------------------
__global__ __launch_bounds__(256) void ln2_res_kernel(const float* __restrict__ f,
        const float* __restrict__ g1, const float* __restrict__ b1,
        const float* __restrict__ g2, const float* __restrict__ b2,
        const float* __restrict__ res, float* __restrict__ out) {
    __shared__ float red[4];
    int row = blockIdx.x;
    int c = threadIdx.x * 4;
    float4 xv = *(const float4*)&f[(size_t)row * D + c];
    float mu = block_sum256(xv.x + xv.y + xv.z + xv.w, red) * (1.0f / D);
    float d0 = xv.x - mu, d1 = xv.y - mu, d2 = xv.z - mu, d3 = xv.w - mu;
    float var = block_sum256(d0*d0 + d1*d1 + d2*d2 + d3*d3, red) * (1.0f / D);
    float rs = rsqrtf(var + EPS);
    float4 g1v = *(const float4*)&g1[c];
    float4 b1v = *(const float4*)&b1[c];
    float z0 = d0 * rs * g1v.x + b1v.x;
    float z1 = d1 * rs * g1v.y + b1v.y;
    float z2 = d2 * rs * g1v.z + b1v.z;
    float z3 = d3 * rs * g1v.w + b1v.w;
    float mu2 = block_sum256(z0 + z1 + z2 + z3, red) * (1.0f / D);
    float e0 = z0 - mu2, e1 = z1 - mu2, e2 = z2 - mu2, e3 = z3 - mu2;
    float var2 = block_sum256(e0*e0 + e1*e1 + e2*e2 + e3*e3, red) * (1.0f / D);
    float rs2 = rsqrtf(var2 + EPS);
    float4 g2v = *(const float4*)&g2[c];
    float4 b2v = *(const float4*)&b2[c];
    float4 rv = *(const float4*)&res[(size_t)row * D + c];
    float4 o;
    o.x = rv.x + e0 * rs2 * g2v.x + b2v.x;
    o.y = rv.y + e1 * rs2 * g2v.y + b2v.y;
    o.z = rv.z + e2 * rs2 * g2v.z + b2v.z;
    o.w = rv.w + e3 * rs2 * g2v.w + b2v.w;
    *(float4*)&out[(size_t)row * D + c] = o;
}

// ---------------------------------------------------------------------------
// generic fp32 GEMM: C[M,N] = act(A[M,K] @ B[K,N] + bias) (+ res)
// 64x64 tile, BK=16, 256 threads, 4x4 micro-tile per thread
// ACT: 0 none, 1 leaky_relu(0.01).  RES: add res[M,N].
// ---------------------------------------------------------------------------
template<int ACT, int RES>
__global__ __launch_bounds__(256) void gemm_kernel(const float* __restrict__ A,
        const float* __restrict__ Bm, const float* __restrict__ bias,
        const float* __restrict__ res, float* __restrict__ C,
        int Mdim, int N, int K) {
    __shared__ float As[64][17];     // +1 pad: column reads conflict-free
    __shared__ float Bs[16][64];
    int tid = threadIdx.x;
    int tx = tid & 15, ty = tid >> 4;
    int n0 = blockIdx.x * 64, m0 = blockIdx.y * 64;
    float acc[4][4] = {};
    int arow = tid >> 2, ak = (tid & 3) << 2;
    int brow = tid >> 4, bc = (tid & 15) << 2;
    const float* Aptr = A + (size_t)(m0 + arow) * K + ak;
    const float* Bptr = Bm + (size_t)brow * N + n0 + bc;
    for (int k0 = 0; k0 < K; k0 += 16) {
        float4 av = *(const float4*)(Aptr + k0);
        float4 bv = *(const float4*)(Bptr + (size_t)k0 * N);
        __syncthreads();             // prev compute done before overwrite
        As[arow][ak] = av.x; As[arow][ak+1] = av.y;
        As[arow][ak+2] = av.z; As[arow][ak+3] = av.w;
        *(float4*)&Bs[brow][bc] = bv;
        __syncthreads();
        #pragma unroll
        for (int kk = 0; kk < 16; ++kk) {
            float a0 = As[ty*4+0][kk], a1 = As[ty*4+1][kk];
            float a2 = As[ty*4+2][kk], a3 = As[ty*4+3][kk];
            float4 bq = *(const float4*)&Bs[kk][tx*4];
            acc[0][0] += a0*bq.x; acc[0][1] += a0*bq.y; acc[0][2] += a0*bq.z; acc[0][3] += a0*bq.w;
            acc[1][0] += a1*bq.x; acc[1][1] += a1*bq.y; acc[1][2] += a1*bq.z; acc[1][3] += a1*bq.w;
            acc[2][0] += a2*bq.x; acc[2][1] += a2*bq.y; acc[2][2] += a2*bq.z; acc[2][3] += a2*bq.w;
            acc[3][0] += a3*bq.x; acc[3][1] += a3*bq.y; acc[3][2] += a3*bq.z; acc[3][3] += a3*bq.w;
        }
    }
    #pragma unroll
    for (int i = 0; i < 4; ++i) {
        int m = m0 + ty * 4 + i;
        int n = n0 + tx * 4;
        float4 bi = *(const float4*)&bias[n];
        float4 o;
        o.x = acc[i][0] + bi.x; o.y = acc[i][1] + bi.y;
        o.z = acc[i][2] + bi.z; o.w = acc[i][3] + bi.w;
        if (ACT == 1) {
            o.x = o.x > 0.f ? o.x : 0.01f * o.x;
            o.y = o.y > 0.f ? o.y : 0.01f * o.y;
            o.z = o.z > 0.f ? o.z : 0.01f * o.z;
            o.w = o.w > 0.f ? o.w : 0.01f * o.w;
        }
        if (RES) {
            float4 rv = *(const float4*)&res[(size_t)m * N + n];
            o.x += rv.x; o.y += rv.y; o.z += rv.z; o.w += rv.w;
        }
        *(float4*)&C[(size_t)m * N + n] = o;
    }
}

// ---------------------------------------------------------------------------
// qkv: per-head projections.  grid = (M/64, H, 3), z selects q/k/v.
// out layout [B,H,T,HS]
// ---------------------------------------------------------------------------
__global__ __launch_bounds__(256) void qkv_kernel(const float* __restrict__ xn,
        const float* __restrict__ Wq, const float* __restrict__ bq,
        const float* __restrict__ Wk, const float* __restrict__ bk,
        const float* __restrict__ Wv, const float* __restrict__ bv,
        float* __restrict__ q, float* __restrict__ k, float* __restrict__ v) {
    int h = blockIdx.y, z = blockIdx.z;
    const float* W; const float* bias; float* out;
    if (z == 0)      { W = Wq; bias = bq; out = q; }
    else if (z == 1) { W = Wk; bias = bk; out = k; }
    else             { W = Wv; bias = bv; out = v; }
    W += (size_t)h * D * HS;
    bias += h * HS;
    __shared__ float As[64][17];
    __shared__ float Bs[16][64];
    int tid = threadIdx.x;
    int tx = tid & 15, ty = tid >> 4;
    int m0 = blockIdx.x * 64;
    float acc[4][4] = {};
    int arow = tid >> 2, ak = (tid & 3) << 2;
    int brow = tid >> 4, bc = (tid & 15) << 2;
    for (int k0 = 0; k0 < D; k0 += 16) {
        float4 av = *(const float4*)&xn[(size_t)(m0 + arow) * D + k0 + ak];
        float4 bv4 = *(const float4*)&W[(size_t)(k0 + brow) * HS + bc];
        __syncthreads();
        As[arow][ak] = av.x; As[arow][ak+1] = av.y;
        As[arow][ak+2] = av.z; As[arow][ak+3] = av.w;
        *(float4*)&Bs[brow][bc] = bv4;
        __syncthreads();
        #pragma unroll
        for (int kk = 0; kk < 16; ++kk) {
            float a0 = As[ty*4+0][kk], a1 = As[ty*4+1][kk];
            float a2 = As[ty*4+2][kk], a3 = As[ty*4+3][kk];
            float4 bq4 = *(const float4*)&Bs[kk][tx*4];
            acc[0][0] += a0*bq4.x; acc[0][1] += a0*bq4.y; acc[0][2] += a0*bq4.z; acc[0][3] += a0*bq4.w;
            acc[1][0] += a1*bq4.x; acc[1][1] += a1*bq4.y; acc[1][2] += a1*bq4.z; acc[1][3] += a1*bq4.w;
            acc[2][0] += a2*bq4.x; acc[2][1] += a2*bq4.y; acc[2][2] += a2*bq4.z; acc[2][3] += a2*bq4.w;
            acc[3][0] += a3*bq4.x; acc[3][1] += a3*bq4.y; acc[3][2] += a3*bq4.z; acc[3][3] += a3*bq4.w;
        }
    }
    float4 bi = *(const float4*)&bias[tx * 4];
    #pragma unroll
    for (int i = 0; i < 4; ++i) {
        int m = m0 + ty * 4 + i;
        int b = m >> 10;          // m / T
        int t = m & 1023;         // m % T
        float4 o;
        o.x = acc[i][0] + bi.x; o.y = acc[i][1] + bi.y;
        o.z = acc[i][2] + bi.z; o.w = acc[i][3] + bi.w;
        *(float4*)&out[((size_t)(b * H + h) * T + t) * HS + tx * 4] = o;
    }
}

// ---------------------------------------------------------------------------
// flash-style attention (fp32). grid = (T/16, B*H), block 256.
// 16 query rows per block; 64-key tiles; online softmax.
// writes concat layout att[(b*T+t)*D + h*HS + e]
// ---------------------------------------------------------------------------
template<int CAUSAL>
__global__ __launch_bounds__(256) void attn_kernel(const float* __restrict__ q,
        const float* __restrict__ k, const float* __restrict__ v,
        float* __restrict__ att) {
    __shared__ float qs[16][68];
    __shared__ float ks[64][68];
    __shared__ float vs[64][68];
    __shared__ float ps[16][68];
    int bh = blockIdx.y;                 // b*H + h
    int bI = bh >> 4, h = bh & 15;
    int t0 = blockIdx.x * 16;
    const size_t base = (size_t)bh * T * HS;
    int tid = threadIdx.x;
    int c = tid & 15, r = tid >> 4;
    {   // load 16x64 q tile
        int row = tid >> 4;
        int c4 = (tid & 15) * 4;
        *(float4*)&qs[row][c4] = *(const float4*)&q[base + (size_t)(t0 + row) * HS + c4];
    }
    float m_run = -1e30f, l_run = 0.f;
    float o0 = 0, o1 = 0, o2 = 0, o3 = 0;
    int s_max = CAUSAL ? (t0 + 16) : T;
    for (int s0 = 0; s0 < s_max; s0 += 64) {
        __syncthreads();                 // prev PV done before overwriting ks/vs
        #pragma unroll
        for (int i = 0; i < 4; ++i) {
            int f4 = tid + i * 256;
            int row = f4 >> 4, c4 = (f4 & 15) * 4;
            *(float4*)&ks[row][c4] = *(const float4*)&k[base + (size_t)(s0 + row) * HS + c4];
            *(float4*)&vs[row][c4] = *(const float4*)&v[base + (size_t)(s0 + row) * HS + c4];
        }
        __syncthreads();
        float sc[4];
        #pragma unroll
        for (int sj = 0; sj < 4; ++sj) {
            int sl = sj * 16 + c;
            float dot = 0.f;
            #pragma unroll
            for (int e4 = 0; e4 < 16; ++e4) {
                float4 qv = *(const float4*)&qs[r][e4 * 4];
                float4 kv = *(const float4*)&ks[sl][e4 * 4];
                dot += qv.x * kv.x + qv.y * kv.y + qv.z * kv.z + qv.w * kv.w;
            }
            dot *= 0.125f;               // HS^-0.5
            if (CAUSAL && (s0 + sl) > (t0 + r)) dot = -1e30f;
            sc[sj] = dot;
        }
        float tm = fmaxf(fmaxf(sc[0], sc[1]), fmaxf(sc[2], sc[3]));
        #pragma unroll
        for (int off = 1; off < 16; off <<= 1) tm = fmaxf(tm, __shfl_xor(tm, off, 16));
        float m_new = fmaxf(m_run, tm);
        float lsum = 0.f;
        #pragma unroll
        for (int sj = 0; sj < 4; ++sj) {
            float p = __expf(sc[sj] - m_new);
            ps[r][sj * 16 + c] = p;
            lsum += p;
        }
        #pragma unroll
        for (int off = 1; off < 16; off <<= 1) lsum += __shfl_xor(lsum, off, 16);
        float alpha = __expf(m_run - m_new);
        l_run = l_run * alpha + lsum;
        m_run = m_new;
        o0 *= alpha; o1 *= alpha; o2 *= alpha; o3 *= alpha;
        __syncthreads();                 // ps visible
        #pragma unroll 8
        for (int s = 0; s < 64; ++s) {
            float p = ps[r][s];
            o0 += p * vs[s][c];
            o1 += p * vs[s][c + 16];
            o2 += p * vs[s][c + 32];
            o3 += p * vs[s][c + 48];
        }
    }
    float inv_l = 1.0f / l_run;
    size_t orow = ((size_t)(bI * T) + t0 + r) * D + h * HS + c;
    att[orow]      = o0 * inv_l;
    att[orow + 16] = o1 * inv_l;
    att[orow + 32] = o2 * inv_l;
    att[orow + 48] = o3 * inv_l;
}

// ---------------------------------------------------------------------------
extern "C" void kernel_launch(void* const* d_in, const int* in_sizes, int n_in,
                              void* d_out, int out_size, void* d_ws, size_t ws_size,
                              hipStream_t stream) {
    const int*   idx     = (const int*)d_in[0];
    const float* tok_emb = (const float*)d_in[1];
    const float* pos_emb = (const float*)d_in[2];
    const float* Wq_u = (const float*)d_in[3],  *bq_u = (const float*)d_in[4];
    const float* Wk_u = (const float*)d_in[5],  *bk_u = (const float*)d_in[6];
    const float* Wv_u = (const float*)d_in[7],  *bv_u = (const float*)d_in[8];
    const float* Wp_u = (const float*)d_in[9],  *bp_u = (const float*)d_in[10];
    const float* Wq_m = (const float*)d_in[11], *bq_m = (const float*)d_in[12];
    const float* Wk_m = (const float*)d_in[13], *bk_m = (const float*)d_in[14];
    const float* Wv_m = (const float*)d_in[15], *bv_m = (const float*)d_in[16];
    const float* Wp_m = (const float*)d_in[17], *bp_m = (const float*)d_in[18];
    const float* W1   = (const float*)d_in[19], *b1   = (const float*)d_in[20];
    const float* W2   = (const float*)d_in[21], *b2   = (const float*)d_in[22];
    const float* lnf_g = (const float*)d_in[23], *lnf_b = (const float*)d_in[24];
    const float* n1_g  = (const float*)d_in[25], *n1_b  = (const float*)d_in[26];
    const float* n2_g  = (const float*)d_in[27], *n2_b  = (const float*)d_in[28];
    const float* nf_g  = (const float*)d_in[29], *nf_b  = (const float*)d_in[30];
    const float* Wfin  = (const float*)d_in[31], *bfin  = (const float*)d_in[32];
    float* out = (float*)d_out;

    float* ws = (float*)d_ws;
    const size_t SZ = (size_t)M * D;        // 2,097,152 floats
    float* x    = ws;
    float* x2   = ws + 1 * SZ;
    float* xn   = ws + 2 * SZ;
    float* qb   = ws + 3 * SZ;
    float* kb   = ws + 4 * SZ;
    float* vb   = ws + 5 * SZ;
    float* att  = ws + 6 * SZ;              // reused for FFN-W2 output too
    float* hbuf = ws + 7 * SZ;              // M * DFF
    // total ws use: (7*SZ + M*DFF)*4 = ~100.7 MB

    embed_kernel<<<M, 256, 0, stream>>>(idx, tok_emb, pos_emb, x);

    for (int l = 0; l < LNUM; ++l) {
        const float *n1g = n1_g + l * D, *n1b = n1_b + l * D;
        const float *n2g = n2_g + l * D, *n2b = n2_b + l * D;
        const float *lfg = lnf_g + l * D, *lfb = lnf_b + l * D;
        const float *W1l = W1 + (size_t)l * D * DFF, *b1l = b1 + l * DFF;
        const float *W2l = W2 + (size_t)l * DFF * D, *b2l = b2 + l * D;
        for (int half = 0; half < 2; ++half) {
            const float *Wq_, *bq_, *Wk_, *bk_, *Wv_, *bv_, *Wp_, *bp_;
            if (half == 0) { Wq_ = Wq_u; bq_ = bq_u; Wk_ = Wk_u; bk_ = bk_u;
                             Wv_ = Wv_u; bv_ = bv_u; Wp_ = Wp_u; bp_ = bp_u; }
            else           { Wq_ = Wq_m; bq_ = bq_m; Wk_ = Wk_m; bk_ = bk_m;
                             Wv_ = Wv_m; bv_ = bv_m; Wp_ = Wp_m; bp_ = bp_m; }
            Wq_ += (size_t)l * H * D * HS;  bq_ += l * H * HS;
            Wk_ += (size_t)l * H * D * HS;  bk_ += l * H * HS;
            Wv_ += (size_t)l * H * D * HS;  bv_ += l * H * HS;
            Wp_ += (size_t)l * D * D;       bp_ += l * D;

            // 1. xn = ln(x, n1)
            ln_kernel<<<M, 256, 0, stream>>>(x, n1g, n1b, xn);
            // 2. q,k,v
            qkv_kernel<<<dim3(M / 64, H, 3), 256, 0, stream>>>(
                xn, Wq_, bq_, Wk_, bk_, Wv_, bv_, qb, kb, vb);
            // 3. attention -> concat
            if (half == 0)
                attn_kernel<0><<<dim3(T / 16, BB * H), 256, 0, stream>>>(qb, kb, vb, att);
            else
                attn_kernel<1><<<dim3(T / 16, BB * H), 256, 0, stream>>>(qb, kb, vb, att);
            // 4. x2 = x + att @ Wp + bp
            gemm_kernel<0, 1><<<dim3(D / 64, M / 64), 256, 0, stream>>>(
                att, Wp_, bp_, x, x2, M, D, D);
            // 5. xn = ln(x2, n2)
            ln_kernel<<<M, 256, 0, stream>>>(x2, n2g, n2b, xn);
            // 6. h = leaky(xn @ W1 + b1)
            gemm_kernel<1, 0><<<dim3(DFF / 64, M / 64), 256, 0, stream>>>(
                xn, W1l, b1l, nullptr, hbuf, M, DFF, D);
            // 7. f = h @ W2 + b2   (into att buffer, att is dead now)
            gemm_kernel<0, 0><<<dim3(D / 64, M / 64), 256, 0, stream>>>(
                hbuf, W2l, b2l, nullptr, att, M, D, DFF);
            // 8. x = x2 + ln(ln(f, lnf), n1 or n2)
            const float* og = half ? n2g : n1g;
            const float* ob = half ? n2b : n1b;
            ln2_res_kernel<<<M, 256, 0, stream>>>(att, lfg, lfb, og, ob, x2, x);
        }
    }
    // final: ln(x, nf) then logits = xn @ Wfin + bfin
    ln_kernel<<<M, 256, 0, stream>>>(x, nf_g, nf_b, xn);
    gemm_kernel<0, 0><<<dim3(V / 64, M / 64), 256, 0, stream>>>(
        xn, Wfin, bfin, nullptr, out, M, V, D);
}

// Round 2
// 3901.130 us; speedup vs baseline: 2.9929x; 2.9929x over previous
//
#include <hip/hip_runtime.h>
#include <hip/hip_bf16.h>
#include <math.h>

#define LNUM 4
#define H 16
#define D 1024
#define HS 64
#define DFF 5120
#define V 32000
#define BB 2
#define T 1024
#define M (BB*T)          // 2048 token rows
#define EPS 1e-5f

typedef __attribute__((ext_vector_type(8))) short bf16x8;
typedef __attribute__((ext_vector_type(4))) float f32x4;

// async global->LDS, 16B per lane (wave-uniform LDS base + lane*16)
__device__ __forceinline__ void gload16(const void* g, void* l) {
    __builtin_amdgcn_global_load_lds(
        (const __attribute__((address_space(1))) void*)g,
        (__attribute__((address_space(3))) void*)l, 16, 0, 0);
}

// ---------------------------------------------------------------------------
// embed
// ---------------------------------------------------------------------------
__global__ __launch_bounds__(256) void embed_kernel(const int* __restrict__ idx,
        const float* __restrict__ tok, const float* __restrict__ pos,
        float* __restrict__ x) {
    int row = blockIdx.x;
    int t = row & (T - 1);
    int tok_id = idx[row];
    int c = threadIdx.x * 4;
    float4 a = *(const float4*)&tok[(size_t)tok_id * D + c];
    float4 p = *(const float4*)&pos[(size_t)t * D + c];
    a.x += p.x; a.y += p.y; a.z += p.z; a.w += p.w;
    *(float4*)&x[(size_t)row * D + c] = a;
}

// ---------------------------------------------------------------------------
__device__ __forceinline__ float block_sum256(float v, float* red) {
    #pragma unroll
    for (int off = 32; off > 0; off >>= 1) v += __shfl_down(v, off, 64);
    int lane = threadIdx.x & 63, w = threadIdx.x >> 6;
    __syncthreads();
    if (lane == 0) red[w] = v;
    __syncthreads();
    return red[0] + red[1] + red[2] + red[3];
}

// ---------------------------------------------------------------------------
// ln -> bf16 output (feeds MFMA GEMMs)
// ---------------------------------------------------------------------------
__global__ __launch_bounds__(256) void ln_bf16_kernel(const float* __restrict__ in,
        const float* __restrict__ g, const float* __restrict__ b,
        __hip_bfloat16* __restrict__ out) {
    __shared__ float red[4];
    int row = blockIdx.x;
    int c = threadIdx.x * 4;
    float4 xv = *(const float4*)&in[(size_t)row * D + c];
    float mu = block_sum256(xv.x + xv.y + xv.z + xv.w, red) * (1.0f / D);
    float d0 = xv.x - mu, d1 = xv.y - mu, d2 = xv.z - mu, d3 = xv.w - mu;
    float var = block_sum256(d0*d0 + d1*d1 + d2*d2 + d3*d3, red) * (1.0f / D);
    float rs = rsqrtf(var + EPS);
    float4 gv = *(const float4*)&g[c];
    float4 bv = *(const float4*)&b[c];
    union { ushort4 u4; __hip_bfloat16 h[4]; } pk;
    pk.h[0] = __float2bfloat16(d0 * rs * gv.x + bv.x);
    pk.h[1] = __float2bfloat16(d1 * rs * gv.y + bv.y);
    pk.h[2] = __float2bfloat16(d2 * rs * gv.z + bv.z);
    pk.h[3] = __float2bfloat16(d3 * rs * gv.w + bv.w);
    *(ushort4*)&out[(size_t)row * D + c] = pk.u4;
}

// ---------------------------------------------------------------------------
// out = res + ln(ln(f, g1,b1), g2,b2)   (fp32)
// ---------------------------------------------------------------------------
__global__ __launch_bounds__(256) void ln2_res_kernel(const float* __restrict__ f,
        const float* __restrict__ g1, const float* __restrict__ b1,
        const float* __restrict__ g2, const float* __restrict__ b2,
        const float* __restrict__ res, float* __restrict__ out) {
    __shared__ float red[4];
    int row = blockIdx.x;
    int c = threadIdx.x * 4;
    float4 xv = *(const float4*)&f[(size_t)row * D + c];
    float mu = block_sum256(xv.x + xv.y + xv.z + xv.w, red) * (1.0f / D);
    float d0 = xv.x - mu, d1 = xv.y - mu, d2 = xv.z - mu, d3 = xv.w - mu;
    float var = block_sum256(d0*d0 + d1*d1 + d2*d2 + d3*d3, red) * (1.0f / D);
    float rs = rsqrtf(var + EPS);
    float4 g1v = *(const float4*)&g1[c];
    float4 b1v = *(const float4*)&b1[c];
    float z0 = d0 * rs * g1v.x + b1v.x;
    float z1 = d1 * rs * g1v.y + b1v.y;
    float z2 = d2 * rs * g1v.z + b1v.z;
    float z3 = d3 * rs * g1v.w + b1v.w;
    float mu2 = block_sum256(z0 + z1 + z2 + z3, red) * (1.0f / D);
    float e0 = z0 - mu2, e1 = z1 - mu2, e2 = z2 - mu2, e3 = z3 - mu2;
    float var2 = block_sum256(e0*e0 + e1*e1 + e2*e2 + e3*e3, red) * (1.0f / D);
    float rs2 = rsqrtf(var2 + EPS);
    float4 g2v = *(const float4*)&g2[c];
    float4 b2v = *(const float4*)&b2[c];
    float4 rv = *(const float4*)&res[(size_t)row * D + c];
    float4 o;
    o.x = rv.x + e0 * rs2 * g2v.x + b2v.x;
    o.y = rv.y + e1 * rs2 * g2v.y + b2v.y;
    o.z = rv.z + e2 * rs2 * g2v.z + b2v.z;
    o.w = rv.w + e3 * rs2 * g2v.w + b2v.w;
    *(float4*)&out[(size_t)row * D + c] = o;
}

// ---------------------------------------------------------------------------
// tiled transpose + fp32->bf16: in [R][C] f32  ->  out [C][R] bf16
// grid (C/32, R/32, Z); 256 threads
// ---------------------------------------------------------------------------
__global__ __launch_bounds__(256) void transpose_bf16_kernel(
        const float* __restrict__ in, __hip_bfloat16* __restrict__ out,
        int R, int C, size_t zin, size_t zout) {
    __shared__ float t[32][33];
    in += (size_t)blockIdx.z * zin; out += (size_t)blockIdx.z * zout;
    int tx = threadIdx.x & 31, ty = threadIdx.x >> 5;   // ty 0..7
    int c0 = blockIdx.x * 32, r0 = blockIdx.y * 32;
    #pragma unroll
    for (int i = 0; i < 4; ++i)
        t[ty + i * 8][tx] = in[(size_t)(r0 + ty + i * 8) * C + c0 + tx];
    __syncthreads();
    #pragma unroll
    for (int i = 0; i < 4; ++i)
        out[(size_t)(c0 + ty + i * 8) * R + r0 + tx] = __float2bfloat16(t[tx][ty + i * 8]);
}

// ---------------------------------------------------------------------------
// bf16 MFMA GEMM, m97 structure: C[M,N] = epi(A[M,K] @ BT[N,K]^T + bias)
// BM in {64,128}, BN=128, BK=32. 256 threads = 4 waves (2x2).
// EPI: 0 plain f32 -> C0 ; 1 +res f32 -> C0 ; 2 leaky -> bf16 Cbf ;
//      3 qkv scatter f32 -> C0/C1/C2 ([B,H,T,HS])
// ---------------------------------------------------------------------------
template<int BM, int EPI>
__global__ __launch_bounds__(256) void mm_bf16_kernel(
        const short* __restrict__ A, const short* __restrict__ BT,
        const float* __restrict__ bias0, const float* __restrict__ bias1,
        const float* __restrict__ bias2, const float* __restrict__ res,
        float* __restrict__ C0, float* __restrict__ C1, float* __restrict__ C2,
        __hip_bfloat16* __restrict__ Cbf, int N, int K) {
    constexpr int BK = 32, BN = 128;
    constexpr int MI = BM / 32;
    __shared__ __align__(16) short As[BM * BK];
    __shared__ __align__(16) short Bs[BN * BK];
    int tid = threadIdx.x;
    int lane = tid & 63, wid = tid >> 6;
    int wr = wid >> 1, wc = wid & 1;
    int l15 = lane & 15, l16 = lane >> 4;
    int m0 = blockIdx.y * BM, n0 = blockIdx.x * BN;
    f32x4 acc[MI][4] = {};
    int sr = tid >> 2, sk = (tid & 3) * 8;              // staging row/col
    const short* Ag = A + (size_t)(m0 + sr) * K + sk;
    const short* Bg = BT + (size_t)(n0 + sr) * K + sk;
    short* Asl = As + tid * 8;
    short* Bsl = Bs + tid * 8;
    for (int k0 = 0; k0 < K; k0 += BK) {
        #pragma unroll
        for (int i = 0; i < BM / 64; ++i)
            gload16(Ag + k0 + (size_t)(i * 64) * K, Asl + i * 2048);
        #pragma unroll
        for (int i = 0; i < 2; ++i)
            gload16(Bg + k0 + (size_t)(i * 64) * K, Bsl + i * 2048);
        __syncthreads();                 // vmcnt drained: tile ready
        bf16x8 af[MI], bfv[4];
        const short* Ab = As + (wr * (BM / 2) + l15) * BK + l16 * 8;
        const short* Bb = Bs + (wc * 64 + l15) * BK + l16 * 8;
        #pragma unroll
        for (int mi = 0; mi < MI; ++mi) af[mi] = *(const bf16x8*)(Ab + mi * 16 * BK);
        #pragma unroll
        for (int ni = 0; ni < 4; ++ni) bfv[ni] = *(const bf16x8*)(Bb + ni * 16 * BK);
        #pragma unroll
        for (int mi = 0; mi < MI; ++mi)
            #pragma unroll
            for (int ni = 0; ni < 4; ++ni)
                acc[mi][ni] = __builtin_amdgcn_mfma_f32_16x16x32_bf16(
                    af[mi], bfv[ni], acc[mi][ni], 0, 0, 0);
        __syncthreads();                 // reads done before next stage
    }
    int rbase = m0 + wr * (BM / 2) + l16 * 4;
    int cbase = n0 + wc * 64 + l15;
    #pragma unroll
    for (int mi = 0; mi < MI; ++mi) {
        #pragma unroll
        for (int ni = 0; ni < 4; ++ni) {
            int col = cbase + ni * 16;
            float bv;
            if (EPI == 3) {
                int z = col >> 10, nn = col & 1023;
                bv = (z == 0 ? bias0 : z == 1 ? bias1 : bias2)[nn];
            } else bv = bias0[col];
            #pragma unroll
            for (int r = 0; r < 4; ++r) {
                int row = rbase + mi * 16 + r;
                float v = acc[mi][ni][r] + bv;
                if (EPI == 0) {
                    C0[(size_t)row * N + col] = v;
                } else if (EPI == 1) {
                    C0[(size_t)row * N + col] = v + res[(size_t)row * N + col];
                } else if (EPI == 2) {
                    v = v > 0.f ? v : 0.01f * v;
                    Cbf[(size_t)row * N + col] = __float2bfloat16(v);
                } else {
                    int z = col >> 10;
                    int h = (col >> 6) & 15, e = col & 63;
                    int b = row >> 10, t = row & (T - 1);
                    float* dst = z == 0 ? C0 : (z == 1 ? C1 : C2);
                    dst[(((size_t)(b * H + h)) * T + t) * HS + e] = v;
                }
            }
        }
    }
}

// ---------------------------------------------------------------------------
// flash-style attention (fp32 math), writes bf16 concat output
// ---------------------------------------------------------------------------
template<int CAUSAL>
__global__ __launch_bounds__(256) void attn_kernel(const float* __restrict__ q,
        const float* __restrict__ k, const float* __restrict__ v,
        __hip_bfloat16* __restrict__ att) {
    __shared__ float qs[16][68];
    __shared__ float ks[64][68];
    __shared__ float vs[64][68];
    __shared__ float ps[16][68];
    int bh = blockIdx.y;
    int bI = bh >> 4, h = bh & 15;
    int t0 = blockIdx.x * 16;
    const size_t base = (size_t)bh * T * HS;
    int tid = threadIdx.x;
    int c = tid & 15, r = tid >> 4;
    {
        int row = tid >> 4;
        int c4 = (tid & 15) * 4;
        *(float4*)&qs[row][c4] = *(const float4*)&q[base + (size_t)(t0 + row) * HS + c4];
    }
    float m_run = -1e30f, l_run = 0.f;
    float o0 = 0, o1 = 0, o2 = 0, o3 = 0;
    int s_max = CAUSAL ? (t0 + 16) : T;
    for (int s0 = 0; s0 < s_max; s0 += 64) {
        __syncthreads();
        #pragma unroll
        for (int i = 0; i < 4; ++i) {
            int f4 = tid + i * 256;
            int row = f4 >> 4, c4 = (f4 & 15) * 4;
            *(float4*)&ks[row][c4] = *(const float4*)&k[base + (size_t)(s0 + row) * HS + c4];
            *(float4*)&vs[row][c4] = *(const float4*)&v[base + (size_t)(s0 + row) * HS + c4];
        }
        __syncthreads();
        float sc[4];
        #pragma unroll
        for (int sj = 0; sj < 4; ++sj) {
            int sl = sj * 16 + c;
            float dot = 0.f;
            #pragma unroll
            for (int e4 = 0; e4 < 16; ++e4) {
                float4 qv = *(const float4*)&qs[r][e4 * 4];
                float4 kv = *(const float4*)&ks[sl][e4 * 4];
                dot += qv.x * kv.x + qv.y * kv.y + qv.z * kv.z + qv.w * kv.w;
            }
            dot *= 0.125f;
            if (CAUSAL && (s0 + sl) > (t0 + r)) dot = -1e30f;
            sc[sj] = dot;
        }
        float tm = fmaxf(fmaxf(sc[0], sc[1]), fmaxf(sc[2], sc[3]));
        #pragma unroll
        for (int off = 1; off < 16; off <<= 1) tm = fmaxf(tm, __shfl_xor(tm, off, 16));
        float m_new = fmaxf(m_run, tm);
        float lsum = 0.f;
        #pragma unroll
        for (int sj = 0; sj < 4; ++sj) {
            float p = __expf(sc[sj] - m_new);
            ps[r][sj * 16 + c] = p;
            lsum += p;
        }
        #pragma unroll
        for (int off = 1; off < 16; off <<= 1) lsum += __shfl_xor(lsum, off, 16);
        float alpha = __expf(m_run - m_new);
        l_run = l_run * alpha + lsum;
        m_run = m_new;
        o0 *= alpha; o1 *= alpha; o2 *= alpha; o3 *= alpha;
        __syncthreads();
        #pragma unroll 8
        for (int s = 0; s < 64; ++s) {
            float p = ps[r][s];
            o0 += p * vs[s][c];
            o1 += p * vs[s][c + 16];
            o2 += p * vs[s][c + 32];
            o3 += p * vs[s][c + 48];
        }
    }
    float inv_l = 1.0f / l_run;
    size_t orow = ((size_t)(bI * T) + t0 + r) * D + h * HS + c;
    att[orow]      = __float2bfloat16(o0 * inv_l);
    att[orow + 16] = __float2bfloat16(o1 * inv_l);
    att[orow + 32] = __float2bfloat16(o2 * inv_l);
    att[orow + 48] = __float2bfloat16(o3 * inv_l);
}

// ---------------------------------------------------------------------------
extern "C" void kernel_launch(void* const* d_in, const int* in_sizes, int n_in,
                              void* d_out, int out_size, void* d_ws, size_t ws_size,
                              hipStream_t stream) {
    const int*   idx     = (const int*)d_in[0];
    const float* tok_emb = (const float*)d_in[1];
    const float* pos_emb = (const float*)d_in[2];
    const float* Wq_u = (const float*)d_in[3],  *bq_u = (const float*)d_in[4];
    const float* Wk_u = (const float*)d_in[5],  *bk_u = (const float*)d_in[6];
    const float* Wv_u = (const float*)d_in[7],  *bv_u = (const float*)d_in[8];
    const float* Wp_u = (const float*)d_in[9],  *bp_u = (const float*)d_in[10];
    const float* Wq_m = (const float*)d_in[11], *bq_m = (const float*)d_in[12];
    const float* Wk_m = (const float*)d_in[13], *bk_m = (const float*)d_in[14];
    const float* Wv_m = (const float*)d_in[15], *bv_m = (const float*)d_in[16];
    const float* Wp_m = (const float*)d_in[17], *bp_m = (const float*)d_in[18];
    const float* W1   = (const float*)d_in[19], *b1   = (const float*)d_in[20];
    const float* W2   = (const float*)d_in[21], *b2   = (const float*)d_in[22];
    const float* lnf_g = (const float*)d_in[23], *lnf_b = (const float*)d_in[24];
    const float* n1_g  = (const float*)d_in[25], *n1_b  = (const float*)d_in[26];
    const float* n2_g  = (const float*)d_in[27], *n2_b  = (const float*)d_in[28];
    const float* nf_g  = (const float*)d_in[29], *nf_b  = (const float*)d_in[30];
    const float* Wfin  = (const float*)d_in[31], *bfin  = (const float*)d_in[32];
    float* out = (float*)d_out;

    char* p = (char*)d_ws;
    auto alloc = [&](size_t bytes) { char* r = p; p += (bytes + 255) & ~255ull; return r; };
    float* x    = (float*)alloc((size_t)M * D * 4);
    float* x2   = (float*)alloc((size_t)M * D * 4);
    float* fbuf = (float*)alloc((size_t)M * D * 4);
    float* qb   = (float*)alloc((size_t)M * D * 4);
    float* kb   = (float*)alloc((size_t)M * D * 4);
    float* vb   = (float*)alloc((size_t)M * D * 4);
    short* xnb  = (short*)alloc((size_t)M * D * 2);
    short* attb = (short*)alloc((size_t)M * D * 2);
    short* hb   = (short*)alloc((size_t)M * DFF * 2);
    short* WqkvT= (short*)alloc((size_t)3 * 1024 * 1024 * 2);
    short* WpT  = (short*)alloc((size_t)1024 * 1024 * 2);
    short* W1T  = (short*)alloc((size_t)D * DFF * 2);
    short* W2T  = (short*)alloc((size_t)DFF * D * 2);
    short* WfT  = (short*)alloc((size_t)D * V * 2);

    embed_kernel<<<M, 256, 0, stream>>>(idx, tok_emb, pos_emb, x);
    // vocab head weight (done once, independent)
    transpose_bf16_kernel<<<dim3(V / 32, D / 32, 1), 256, 0, stream>>>(
        Wfin, (__hip_bfloat16*)WfT, D, V, 0, 0);

    for (int l = 0; l < LNUM; ++l) {
        const float *n1g = n1_g + l * D, *n1b = n1_b + l * D;
        const float *n2g = n2_g + l * D, *n2b = n2_b + l * D;
        const float *lfg = lnf_g + l * D, *lfb = lnf_b + l * D;
        const float *W1l = W1 + (size_t)l * D * DFF, *b1l = b1 + l * DFF;
        const float *W2l = W2 + (size_t)l * DFF * D, *b2l = b2 + l * D;
        transpose_bf16_kernel<<<dim3(DFF / 32, D / 32, 1), 256, 0, stream>>>(
            W1l, (__hip_bfloat16*)W1T, D, DFF, 0, 0);
        transpose_bf16_kernel<<<dim3(D / 32, DFF / 32, 1), 256, 0, stream>>>(
            W2l, (__hip_bfloat16*)W2T, DFF, D, 0, 0);
        for (int half = 0; half < 2; ++half) {
            const float *Wq_, *bq_, *Wk_, *bk_, *Wv_, *bv_, *Wp_, *bp_;
            if (half == 0) { Wq_ = Wq_u; bq_ = bq_u; Wk_ = Wk_u; bk_ = bk_u;
                             Wv_ = Wv_u; bv_ = bv_u; Wp_ = Wp_u; bp_ = bp_u; }
            else           { Wq_ = Wq_m; bq_ = bq_m; Wk_ = Wk_m; bk_ = bk_m;
                             Wv_ = Wv_m; bv_ = bv_m; Wp_ = Wp_m; bp_ = bp_m; }
            Wq_ += (size_t)l * H * D * HS;  bq_ += l * H * HS;
            Wk_ += (size_t)l * H * D * HS;  bk_ += l * H * HS;
            Wv_ += (size_t)l * H * D * HS;  bv_ += l * H * HS;
            Wp_ += (size_t)l * D * D;       bp_ += l * D;

            // per-half weight prep: Wqkv_T[3072][1024], Wp_T[1024][1024]
            transpose_bf16_kernel<<<dim3(HS / 32, D / 32, H), 256, 0, stream>>>(
                Wq_, (__hip_bfloat16*)WqkvT, D, HS, (size_t)D * HS, (size_t)HS * D);
            transpose_bf16_kernel<<<dim3(HS / 32, D / 32, H), 256, 0, stream>>>(
                Wk_, (__hip_bfloat16*)(WqkvT + 1024 * 1024), D, HS, (size_t)D * HS, (size_t)HS * D);
            transpose_bf16_kernel<<<dim3(HS / 32, D / 32, H), 256, 0, stream>>>(
                Wv_, (__hip_bfloat16*)(WqkvT + 2 * 1024 * 1024), D, HS, (size_t)D * HS, (size_t)HS * D);
            transpose_bf16_kernel<<<dim3(D / 32, D / 32, 1), 256, 0, stream>>>(
                Wp_, (__hip_bfloat16*)WpT, D, D, 0, 0);

            // 1. xn = ln(x, n1) -> bf16
            ln_bf16_kernel<<<M, 256, 0, stream>>>(x, n1g, n1b, (__hip_bfloat16*)xnb);
            // 2. q,k,v = xn @ Wqkv  (scatter to [B,H,T,HS] fp32)
            mm_bf16_kernel<128, 3><<<dim3(3072 / 128, M / 128), 256, 0, stream>>>(
                xnb, WqkvT, bq_, bk_, bv_, nullptr, qb, kb, vb, nullptr, 3072, D);
            // 3. attention -> bf16 concat
            if (half == 0)
                attn_kernel<0><<<dim3(T / 16, BB * H), 256, 0, stream>>>(
                    qb, kb, vb, (__hip_bfloat16*)attb);
            else
                attn_kernel<1><<<dim3(T / 16, BB * H), 256, 0, stream>>>(
                    qb, kb, vb, (__hip_bfloat16*)attb);
            // 4. x2 = x + att @ Wp + bp
            mm_bf16_kernel<64, 1><<<dim3(D / 128, M / 64), 256, 0, stream>>>(
                attb, WpT, bp_, nullptr, nullptr, x, x2, nullptr, nullptr, nullptr, D, D);
            // 5. xn = ln(x2, n2) -> bf16
            ln_bf16_kernel<<<M, 256, 0, stream>>>(x2, n2g, n2b, (__hip_bfloat16*)xnb);
            // 6. h = leaky(xn @ W1 + b1) -> bf16
            mm_bf16_kernel<128, 2><<<dim3(DFF / 128, M / 128), 256, 0, stream>>>(
                xnb, W1T, b1l, nullptr, nullptr, nullptr, nullptr, nullptr, nullptr,
                (__hip_bfloat16*)hb, DFF, D);
            // 7. f = h @ W2 + b2  (fp32)
            mm_bf16_kernel<64, 0><<<dim3(D / 128, M / 64), 256, 0, stream>>>(
                hb, W2T, b2l, nullptr, nullptr, nullptr, fbuf, nullptr, nullptr, nullptr, D, DFF);
            // 8. x = x2 + ln(ln(f, lnf), n1|n2)
            const float* og = half ? n2g : n1g;
            const float* ob = half ? n2b : n1b;
            ln2_res_kernel<<<M, 256, 0, stream>>>(fbuf, lfg, lfb, og, ob, x2, x);
        }
    }
    // final LN + vocab head
    ln_bf16_kernel<<<M, 256, 0, stream>>>(x, nf_g, nf_b, (__hip_bfloat16*)xnb);
    mm_bf16_kernel<128, 0><<<dim3(V / 128, M / 128), 256, 0, stream>>>(
        xnb, WfT, bfin, nullptr, nullptr, nullptr, out, nullptr, nullptr, nullptr, V, D);
}

// Round 3
// 2204.270 us; speedup vs baseline: 5.2969x; 1.7698x over previous
//
#include <hip/hip_runtime.h>
#include <hip/hip_bf16.h>
#include <math.h>

#define LNUM 4
#define H 16
#define D 1024
#define HS 64
#define DFF 5120
#define V 32000
#define BB 2
#define T 1024
#define M (BB*T)          // 2048 token rows
#define EPS 1e-5f

typedef __attribute__((ext_vector_type(8))) short bf16x8;
typedef __attribute__((ext_vector_type(4))) float f32x4;

// async global->LDS, 16B per lane (wave-uniform LDS base + lane*16)
__device__ __forceinline__ void gload16(const void* g, void* l) {
    __builtin_amdgcn_global_load_lds(
        (const __attribute__((address_space(1))) void*)g,
        (__attribute__((address_space(3))) void*)l, 16, 0, 0);
}

// ---------------------------------------------------------------------------
// embed
// ---------------------------------------------------------------------------
__global__ __launch_bounds__(256) void embed_kernel(const int* __restrict__ idx,
        const float* __restrict__ tok, const float* __restrict__ pos,
        float* __restrict__ x) {
    int row = blockIdx.x;
    int t = row & (T - 1);
    int tok_id = idx[row];
    int c = threadIdx.x * 4;
    float4 a = *(const float4*)&tok[(size_t)tok_id * D + c];
    float4 p = *(const float4*)&pos[(size_t)t * D + c];
    a.x += p.x; a.y += p.y; a.z += p.z; a.w += p.w;
    *(float4*)&x[(size_t)row * D + c] = a;
}

// ---------------------------------------------------------------------------
__device__ __forceinline__ float block_sum256(float v, float* red) {
    #pragma unroll
    for (int off = 32; off > 0; off >>= 1) v += __shfl_down(v, off, 64);
    int lane = threadIdx.x & 63, w = threadIdx.x >> 6;
    __syncthreads();
    if (lane == 0) red[w] = v;
    __syncthreads();
    return red[0] + red[1] + red[2] + red[3];
}

// ---------------------------------------------------------------------------
// ln -> bf16 output (feeds MFMA GEMMs)
// ---------------------------------------------------------------------------
__global__ __launch_bounds__(256) void ln_bf16_kernel(const float* __restrict__ in,
        const float* __restrict__ g, const float* __restrict__ b,
        __hip_bfloat16* __restrict__ out) {
    __shared__ float red[4];
    int row = blockIdx.x;
    int c = threadIdx.x * 4;
    float4 xv = *(const float4*)&in[(size_t)row * D + c];
    float mu = block_sum256(xv.x + xv.y + xv.z + xv.w, red) * (1.0f / D);
    float d0 = xv.x - mu, d1 = xv.y - mu, d2 = xv.z - mu, d3 = xv.w - mu;
    float var = block_sum256(d0*d0 + d1*d1 + d2*d2 + d3*d3, red) * (1.0f / D);
    float rs = rsqrtf(var + EPS);
    float4 gv = *(const float4*)&g[c];
    float4 bv = *(const float4*)&b[c];
    union { ushort4 u4; __hip_bfloat16 h[4]; } pk;
    pk.h[0] = __float2bfloat16(d0 * rs * gv.x + bv.x);
    pk.h[1] = __float2bfloat16(d1 * rs * gv.y + bv.y);
    pk.h[2] = __float2bfloat16(d2 * rs * gv.z + bv.z);
    pk.h[3] = __float2bfloat16(d3 * rs * gv.w + bv.w);
    *(ushort4*)&out[(size_t)row * D + c] = pk.u4;
}

// ---------------------------------------------------------------------------
// out = res + ln(ln(f, g1,b1), g2,b2)   (fp32)
// ---------------------------------------------------------------------------
__global__ __launch_bounds__(256) void ln2_res_kernel(const float* __restrict__ f,
        const float* __restrict__ g1, const float* __restrict__ b1,
        const float* __restrict__ g2, const float* __restrict__ b2,
        const float* __restrict__ res, float* __restrict__ out) {
    __shared__ float red[4];
    int row = blockIdx.x;
    int c = threadIdx.x * 4;
    float4 xv = *(const float4*)&f[(size_t)row * D + c];
    float mu = block_sum256(xv.x + xv.y + xv.z + xv.w, red) * (1.0f / D);
    float d0 = xv.x - mu, d1 = xv.y - mu, d2 = xv.z - mu, d3 = xv.w - mu;
    float var = block_sum256(d0*d0 + d1*d1 + d2*d2 + d3*d3, red) * (1.0f / D);
    float rs = rsqrtf(var + EPS);
    float4 g1v = *(const float4*)&g1[c];
    float4 b1v = *(const float4*)&b1[c];
    float z0 = d0 * rs * g1v.x + b1v.x;
    float z1 = d1 * rs * g1v.y + b1v.y;
    float z2 = d2 * rs * g1v.z + b1v.z;
    float z3 = d3 * rs * g1v.w + b1v.w;
    float mu2 = block_sum256(z0 + z1 + z2 + z3, red) * (1.0f / D);
    float e0 = z0 - mu2, e1 = z1 - mu2, e2 = z2 - mu2, e3 = z3 - mu2;
    float var2 = block_sum256(e0*e0 + e1*e1 + e2*e2 + e3*e3, red) * (1.0f / D);
    float rs2 = rsqrtf(var2 + EPS);
    float4 g2v = *(const float4*)&g2[c];
    float4 b2v = *(const float4*)&b2[c];
    float4 rv = *(const float4*)&res[(size_t)row * D + c];
    float4 o;
    o.x = rv.x + e0 * rs2 * g2v.x + b2v.x;
    o.y = rv.y + e1 * rs2 * g2v.y + b2v.y;
    o.z = rv.z + e2 * rs2 * g2v.z + b2v.z;
    o.w = rv.w + e3 * rs2 * g2v.w + b2v.w;
    *(float4*)&out[(size_t)row * D + c] = o;
}

// ---------------------------------------------------------------------------
// tiled transpose + fp32->bf16: in [R][C] f32  ->  out [C][R] bf16
// ---------------------------------------------------------------------------
__global__ __launch_bounds__(256) void transpose_bf16_kernel(
        const float* __restrict__ in, __hip_bfloat16* __restrict__ out,
        int R, int C, size_t zin, size_t zout) {
    __shared__ float t[32][33];
    in += (size_t)blockIdx.z * zin; out += (size_t)blockIdx.z * zout;
    int tx = threadIdx.x & 31, ty = threadIdx.x >> 5;
    int c0 = blockIdx.x * 32, r0 = blockIdx.y * 32;
    #pragma unroll
    for (int i = 0; i < 4; ++i)
        t[ty + i * 8][tx] = in[(size_t)(r0 + ty + i * 8) * C + c0 + tx];
    __syncthreads();
    #pragma unroll
    for (int i = 0; i < 4; ++i)
        out[(size_t)(c0 + ty + i * 8) * R + r0 + tx] = __float2bfloat16(t[tx][ty + i * 8]);
}

// ---------------------------------------------------------------------------
// bf16->bf16 transpose for V: in [T][HS] per bh -> out [HS][T]
// grid (HS/32, T/32, BH)
// ---------------------------------------------------------------------------
__global__ __launch_bounds__(256) void transpose_v_kernel(const short* __restrict__ in,
        short* __restrict__ out) {
    __shared__ short t[32][33];
    int z = blockIdx.z;
    in  += (size_t)z * T * HS;
    out += (size_t)z * HS * T;
    int tx = threadIdx.x & 31, ty = threadIdx.x >> 5;
    int c0 = blockIdx.x * 32, r0 = blockIdx.y * 32;   // c0: hs, r0: t
    #pragma unroll
    for (int i = 0; i < 4; ++i)
        t[ty + i * 8][tx] = in[(size_t)(r0 + ty + i * 8) * HS + c0 + tx];
    __syncthreads();
    #pragma unroll
    for (int i = 0; i < 4; ++i)
        out[(size_t)(c0 + ty + i * 8) * T + r0 + tx] = t[tx][ty + i * 8];
}

// ---------------------------------------------------------------------------
// bf16 MFMA GEMM, m97 structure: C[M,N] = epi(A[M,K] @ BT[N,K]^T + bias)
// EPI: 0 plain f32 -> C0 ; 1 +res f32 -> C0 ; 2 leaky -> bf16 Cbf ;
//      3 qkv scatter bf16 -> C0/C1/C2 ([B,H,T,HS])
// ---------------------------------------------------------------------------
template<int BM, int EPI>
__global__ __launch_bounds__(256) void mm_bf16_kernel(
        const short* __restrict__ A, const short* __restrict__ BT,
        const float* __restrict__ bias0, const float* __restrict__ bias1,
        const float* __restrict__ bias2, const float* __restrict__ res,
        float* __restrict__ C0, float* __restrict__ C1, float* __restrict__ C2,
        __hip_bfloat16* __restrict__ Cbf, int N, int K) {
    constexpr int BK = 32, BN = 128;
    constexpr int MI = BM / 32;
    __shared__ __align__(16) short As[BM * BK];
    __shared__ __align__(16) short Bs[BN * BK];
    int tid = threadIdx.x;
    int lane = tid & 63, wid = tid >> 6;
    int wr = wid >> 1, wc = wid & 1;
    int l15 = lane & 15, l16 = lane >> 4;
    int m0 = blockIdx.y * BM, n0 = blockIdx.x * BN;
    f32x4 acc[MI][4] = {};
    int sr = tid >> 2, sk = (tid & 3) * 8;
    const short* Ag = A + (size_t)(m0 + sr) * K + sk;
    const short* Bg = BT + (size_t)(n0 + sr) * K + sk;
    short* Asl = As + tid * 8;
    short* Bsl = Bs + tid * 8;
    for (int k0 = 0; k0 < K; k0 += BK) {
        #pragma unroll
        for (int i = 0; i < BM / 64; ++i)
            gload16(Ag + k0 + (size_t)(i * 64) * K, Asl + i * 2048);
        #pragma unroll
        for (int i = 0; i < 2; ++i)
            gload16(Bg + k0 + (size_t)(i * 64) * K, Bsl + i * 2048);
        __syncthreads();
        bf16x8 af[MI], bfv[4];
        const short* Ab = As + (wr * (BM / 2) + l15) * BK + l16 * 8;
        const short* Bb = Bs + (wc * 64 + l15) * BK + l16 * 8;
        #pragma unroll
        for (int mi = 0; mi < MI; ++mi) af[mi] = *(const bf16x8*)(Ab + mi * 16 * BK);
        #pragma unroll
        for (int ni = 0; ni < 4; ++ni) bfv[ni] = *(const bf16x8*)(Bb + ni * 16 * BK);
        #pragma unroll
        for (int mi = 0; mi < MI; ++mi)
            #pragma unroll
            for (int ni = 0; ni < 4; ++ni)
                acc[mi][ni] = __builtin_amdgcn_mfma_f32_16x16x32_bf16(
                    af[mi], bfv[ni], acc[mi][ni], 0, 0, 0);
        __syncthreads();
    }
    int rbase = m0 + wr * (BM / 2) + l16 * 4;
    int cbase = n0 + wc * 64 + l15;
    #pragma unroll
    for (int mi = 0; mi < MI; ++mi) {
        #pragma unroll
        for (int ni = 0; ni < 4; ++ni) {
            int col = cbase + ni * 16;
            float bv;
            if (EPI == 3) {
                int z = col >> 10, nn = col & 1023;
                bv = (z == 0 ? bias0 : z == 1 ? bias1 : bias2)[nn & 63 | (nn & 960)];
                bv = (z == 0 ? bias0 : z == 1 ? bias1 : bias2)[nn];
            } else bv = bias0[col];
            #pragma unroll
            for (int r = 0; r < 4; ++r) {
                int row = rbase + mi * 16 + r;
                float v = acc[mi][ni][r] + bv;
                if (EPI == 0) {
                    C0[(size_t)row * N + col] = v;
                } else if (EPI == 1) {
                    C0[(size_t)row * N + col] = v + res[(size_t)row * N + col];
                } else if (EPI == 2) {
                    v = v > 0.f ? v : 0.01f * v;
                    Cbf[(size_t)row * N + col] = __float2bfloat16(v);
                } else {
                    int z = col >> 10;
                    int hh = (col >> 6) & 15, e = col & 63;
                    int b = row >> 10, t = row & (T - 1);
                    __hip_bfloat16* dst = (__hip_bfloat16*)(z == 0 ? C0 : (z == 1 ? C1 : C2));
                    dst[(((size_t)(b * H + hh)) * T + t) * HS + e] = __float2bfloat16(v);
                }
            }
        }
    }
}

// ---------------------------------------------------------------------------
// MFMA flash attention, bf16. grid (T/64, B*H), 256 threads = 4 waves.
// q,k: bf16 [B,H,T,HS]; vt: bf16 [B,H,HS,T]; out: bf16 concat [M][D].
// K/V^T tiles staged swizzled (inverse-swz global source, swz ds_read).
// ---------------------------------------------------------------------------
template<int CAUSAL>
__global__ __launch_bounds__(256) void attn_mfma_kernel(
        const short* __restrict__ q, const short* __restrict__ k,
        const short* __restrict__ vt, __hip_bfloat16* __restrict__ att) {
    __shared__ __align__(16) short Ks[64 * 64];
    __shared__ __align__(16) short Vs[64 * 64];
    __shared__ __align__(16) short Ps[4][16 * 64];
    int bh = blockIdx.y;
    int bI = bh >> 4, h = bh & 15;
    int tix = blockIdx.x;
    if (CAUSAL) tix = (tix & 1) ? (15 - (tix >> 1)) : (tix >> 1);  // load balance
    int t0 = tix * 64;
    int tid = threadIdx.x;
    int lane = tid & 63, w = tid >> 6;
    int l15 = lane & 15, l16 = lane >> 4;

    // Q fragments in registers (A-operand: row=l15, k-chunk=(lane>>4)*8)
    const short* Qg = q + ((size_t)bh * T + t0 + w * 16 + l15) * HS + l16 * 8;
    bf16x8 qf0 = *(const bf16x8*)Qg;
    bf16x8 qf1 = *(const bf16x8*)(Qg + 32);

    const char* Kg = (const char*)(k + (size_t)bh * T * HS);   // row stride 128B
    const char* Vg = (const char*)(vt + (size_t)bh * HS * T);  // row stride 2048B

    float m_run[4] = {-1e30f, -1e30f, -1e30f, -1e30f};
    float l_run[4] = {0.f, 0.f, 0.f, 0.f};
    f32x4 acc_o[4] = {};
    short* Pw = Ps[w];
    int pswz = (l15 & 7) << 4;

    int n_tiles = CAUSAL ? (t0 / 64 + 1) : (T / 64);
    for (int it = 0; it < n_tiles; ++it) {
        int s0 = it * 64;
        __syncthreads();     // prev tile reads done before overwrite
        #pragma unroll
        for (int i = 0; i < 2; ++i) {
            int o = i * 4096 + tid * 16;
            int row = o >> 7, bir = o & 127;
            int sb = bir ^ ((row & 7) << 4);
            gload16(Kg + (size_t)(s0 + row) * 128 + sb, (char*)Ks + o);
            gload16(Vg + (size_t)row * 2048 + s0 * 2 + sb, (char*)Vs + o);
        }
        __syncthreads();     // vmcnt drained: tiles ready

        // S = Q @ K^T (raw)
        f32x4 acc_s[4] = {};
        #pragma unroll
        for (int c = 0; c < 4; ++c) {
            int row = c * 16 + l15;
            const char* kb_ = (const char*)Ks + row * 128;
            int swz = (row & 7) << 4;
            bf16x8 kf0 = *(const bf16x8*)(kb_ + ((l16 * 16) ^ swz));
            bf16x8 kf1 = *(const bf16x8*)(kb_ + ((64 + l16 * 16) ^ swz));
            acc_s[c] = __builtin_amdgcn_mfma_f32_16x16x32_bf16(qf0, kf0, acc_s[c], 0, 0, 0);
            acc_s[c] = __builtin_amdgcn_mfma_f32_16x16x32_bf16(qf1, kf1, acc_s[c], 0, 0, 0);
        }

        bool domask = CAUSAL && (it == n_tiles - 1);
        // online softmax; scale folded into exp: p = exp(0.125*(s-m))
        #pragma unroll
        for (int r = 0; r < 4; ++r) {
            float sc[4];
            #pragma unroll
            for (int c = 0; c < 4; ++c) {
                float s = acc_s[c][r];
                if (domask && (s0 + c * 16 + l15) > (t0 + w * 16 + l16 * 4 + r)) s = -1e30f;
                sc[c] = s;
            }
            float tm = fmaxf(fmaxf(sc[0], sc[1]), fmaxf(sc[2], sc[3]));
            tm = fmaxf(tm, __shfl_xor(tm, 1, 16));
            tm = fmaxf(tm, __shfl_xor(tm, 2, 16));
            tm = fmaxf(tm, __shfl_xor(tm, 4, 16));
            tm = fmaxf(tm, __shfl_xor(tm, 8, 16));
            float mn = fmaxf(m_run[r], tm);
            int prow = l16 * 4 + r;
            int pswzr = (prow & 7) << 4;
            float ls = 0.f;
            #pragma unroll
            for (int c = 0; c < 4; ++c) {
                float pv = __expf(0.125f * (sc[c] - mn));
                int pbyte = prow * 128 + (((c * 16 + l15) * 2) ^ pswzr);
                *(__hip_bfloat16*)((char*)Pw + pbyte) = __float2bfloat16(pv);
                ls += pv;
            }
            ls += __shfl_xor(ls, 1, 16);
            ls += __shfl_xor(ls, 2, 16);
            ls += __shfl_xor(ls, 4, 16);
            ls += __shfl_xor(ls, 8, 16);
            float alpha = __expf(0.125f * (m_run[r] - mn));
            l_run[r] = l_run[r] * alpha + ls;
            m_run[r] = mn;
            acc_o[0][r] *= alpha; acc_o[1][r] *= alpha;
            acc_o[2][r] *= alpha; acc_o[3][r] *= alpha;
        }

        // O += P @ V : A=P (row=q), B^T=V^T tile (row=hs)
        const char* Pb = (const char*)Pw + l15 * 128;
        bf16x8 pa0 = *(const bf16x8*)(Pb + ((l16 * 16) ^ pswz));
        bf16x8 pa1 = *(const bf16x8*)(Pb + ((64 + l16 * 16) ^ pswz));
        #pragma unroll
        for (int ni = 0; ni < 4; ++ni) {
            int row = ni * 16 + l15;
            const char* vb_ = (const char*)Vs + row * 128;
            int swz = (row & 7) << 4;
            bf16x8 vf0 = *(const bf16x8*)(vb_ + ((l16 * 16) ^ swz));
            bf16x8 vf1 = *(const bf16x8*)(vb_ + ((64 + l16 * 16) ^ swz));
            acc_o[ni] = __builtin_amdgcn_mfma_f32_16x16x32_bf16(pa0, vf0, acc_o[ni], 0, 0, 0);
            acc_o[ni] = __builtin_amdgcn_mfma_f32_16x16x32_bf16(pa1, vf1, acc_o[ni], 0, 0, 0);
        }
    }

    float inv[4];
    #pragma unroll
    for (int r = 0; r < 4; ++r) inv[r] = 1.0f / l_run[r];
    #pragma unroll
    for (int ni = 0; ni < 4; ++ni) {
        #pragma unroll
        for (int r = 0; r < 4; ++r) {
            size_t orow = ((size_t)(bI * T) + t0 + w * 16 + l16 * 4 + r) * D
                        + h * HS + ni * 16 + l15;
            att[orow] = __float2bfloat16(acc_o[ni][r] * inv[r]);
        }
    }
}

// ---------------------------------------------------------------------------
extern "C" void kernel_launch(void* const* d_in, const int* in_sizes, int n_in,
                              void* d_out, int out_size, void* d_ws, size_t ws_size,
                              hipStream_t stream) {
    const int*   idx     = (const int*)d_in[0];
    const float* tok_emb = (const float*)d_in[1];
    const float* pos_emb = (const float*)d_in[2];
    const float* Wq_u = (const float*)d_in[3],  *bq_u = (const float*)d_in[4];
    const float* Wk_u = (const float*)d_in[5],  *bk_u = (const float*)d_in[6];
    const float* Wv_u = (const float*)d_in[7],  *bv_u = (const float*)d_in[8];
    const float* Wp_u = (const float*)d_in[9],  *bp_u = (const float*)d_in[10];
    const float* Wq_m = (const float*)d_in[11], *bq_m = (const float*)d_in[12];
    const float* Wk_m = (const float*)d_in[13], *bk_m = (const float*)d_in[14];
    const float* Wv_m = (const float*)d_in[15], *bv_m = (const float*)d_in[16];
    const float* Wp_m = (const float*)d_in[17], *bp_m = (const float*)d_in[18];
    const float* W1   = (const float*)d_in[19], *b1   = (const float*)d_in[20];
    const float* W2   = (const float*)d_in[21], *b2   = (const float*)d_in[22];
    const float* lnf_g = (const float*)d_in[23], *lnf_b = (const float*)d_in[24];
    const float* n1_g  = (const float*)d_in[25], *n1_b  = (const float*)d_in[26];
    const float* n2_g  = (const float*)d_in[27], *n2_b  = (const float*)d_in[28];
    const float* nf_g  = (const float*)d_in[29], *nf_b  = (const float*)d_in[30];
    const float* Wfin  = (const float*)d_in[31], *bfin  = (const float*)d_in[32];
    float* out = (float*)d_out;

    char* p = (char*)d_ws;
    auto alloc = [&](size_t bytes) { char* r = p; p += (bytes + 255) & ~255ull; return r; };
    float* x    = (float*)alloc((size_t)M * D * 4);
    float* x2   = (float*)alloc((size_t)M * D * 4);
    float* fbuf = (float*)alloc((size_t)M * D * 4);
    short* qbf  = (short*)alloc((size_t)M * D * 2);
    short* kbf  = (short*)alloc((size_t)M * D * 2);
    short* vbf  = (short*)alloc((size_t)M * D * 2);
    short* vtb  = (short*)alloc((size_t)M * D * 2);
    short* xnb  = (short*)alloc((size_t)M * D * 2);
    short* attb = (short*)alloc((size_t)M * D * 2);
    short* hb   = (short*)alloc((size_t)M * DFF * 2);
    short* WqkvT= (short*)alloc((size_t)3 * 1024 * 1024 * 2);
    short* WpT  = (short*)alloc((size_t)1024 * 1024 * 2);
    short* W1T  = (short*)alloc((size_t)D * DFF * 2);
    short* W2T  = (short*)alloc((size_t)DFF * D * 2);
    short* WfT  = (short*)alloc((size_t)D * V * 2);

    embed_kernel<<<M, 256, 0, stream>>>(idx, tok_emb, pos_emb, x);
    transpose_bf16_kernel<<<dim3(V / 32, D / 32, 1), 256, 0, stream>>>(
        Wfin, (__hip_bfloat16*)WfT, D, V, 0, 0);

    for (int l = 0; l < LNUM; ++l) {
        const float *n1g = n1_g + l * D, *n1b = n1_b + l * D;
        const float *n2g = n2_g + l * D, *n2b = n2_b + l * D;
        const float *lfg = lnf_g + l * D, *lfb = lnf_b + l * D;
        const float *W1l = W1 + (size_t)l * D * DFF, *b1l = b1 + l * DFF;
        const float *W2l = W2 + (size_t)l * DFF * D, *b2l = b2 + l * D;
        transpose_bf16_kernel<<<dim3(DFF / 32, D / 32, 1), 256, 0, stream>>>(
            W1l, (__hip_bfloat16*)W1T, D, DFF, 0, 0);
        transpose_bf16_kernel<<<dim3(D / 32, DFF / 32, 1), 256, 0, stream>>>(
            W2l, (__hip_bfloat16*)W2T, DFF, D, 0, 0);
        for (int half = 0; half < 2; ++half) {
            const float *Wq_, *bq_, *Wk_, *bk_, *Wv_, *bv_, *Wp_, *bp_;
            if (half == 0) { Wq_ = Wq_u; bq_ = bq_u; Wk_ = Wk_u; bk_ = bk_u;
                             Wv_ = Wv_u; bv_ = bv_u; Wp_ = Wp_u; bp_ = bp_u; }
            else           { Wq_ = Wq_m; bq_ = bq_m; Wk_ = Wk_m; bk_ = bk_m;
                             Wv_ = Wv_m; bv_ = bv_m; Wp_ = Wp_m; bp_ = bp_m; }
            Wq_ += (size_t)l * H * D * HS;  bq_ += l * H * HS;
            Wk_ += (size_t)l * H * D * HS;  bk_ += l * H * HS;
            Wv_ += (size_t)l * H * D * HS;  bv_ += l * H * HS;
            Wp_ += (size_t)l * D * D;       bp_ += l * D;

            transpose_bf16_kernel<<<dim3(HS / 32, D / 32, H), 256, 0, stream>>>(
                Wq_, (__hip_bfloat16*)WqkvT, D, HS, (size_t)D * HS, (size_t)HS * D);
            transpose_bf16_kernel<<<dim3(HS / 32, D / 32, H), 256, 0, stream>>>(
                Wk_, (__hip_bfloat16*)(WqkvT + 1024 * 1024), D, HS, (size_t)D * HS, (size_t)HS * D);
            transpose_bf16_kernel<<<dim3(HS / 32, D / 32, H), 256, 0, stream>>>(
                Wv_, (__hip_bfloat16*)(WqkvT + 2 * 1024 * 1024), D, HS, (size_t)D * HS, (size_t)HS * D);
            transpose_bf16_kernel<<<dim3(D / 32, D / 32, 1), 256, 0, stream>>>(
                Wp_, (__hip_bfloat16*)WpT, D, D, 0, 0);

            // 1. xn = ln(x, n1) -> bf16
            ln_bf16_kernel<<<M, 256, 0, stream>>>(x, n1g, n1b, (__hip_bfloat16*)xnb);
            // 2. q,k,v = xn @ Wqkv  -> bf16 [B,H,T,HS]
            mm_bf16_kernel<128, 3><<<dim3(3072 / 128, M / 128), 256, 0, stream>>>(
                xnb, WqkvT, bq_, bk_, bv_, nullptr,
                (float*)qbf, (float*)kbf, (float*)vbf, nullptr, 3072, D);
            // 2b. V^T
            transpose_v_kernel<<<dim3(HS / 32, T / 32, BB * H), 256, 0, stream>>>(vbf, vtb);
            // 3. attention -> bf16 concat
            if (half == 0)
                attn_mfma_kernel<0><<<dim3(T / 64, BB * H), 256, 0, stream>>>(
                    qbf, kbf, vtb, (__hip_bfloat16*)attb);
            else
                attn_mfma_kernel<1><<<dim3(T / 64, BB * H), 256, 0, stream>>>(
                    qbf, kbf, vtb, (__hip_bfloat16*)attb);
            // 4. x2 = x + att @ Wp + bp
            mm_bf16_kernel<64, 1><<<dim3(D / 128, M / 64), 256, 0, stream>>>(
                attb, WpT, bp_, nullptr, nullptr, x, x2, nullptr, nullptr, nullptr, D, D);
            // 5. xn = ln(x2, n2) -> bf16
            ln_bf16_kernel<<<M, 256, 0, stream>>>(x2, n2g, n2b, (__hip_bfloat16*)xnb);
            // 6. h = leaky(xn @ W1 + b1) -> bf16
            mm_bf16_kernel<128, 2><<<dim3(DFF / 128, M / 128), 256, 0, stream>>>(
                xnb, W1T, b1l, nullptr, nullptr, nullptr, nullptr, nullptr, nullptr,
                (__hip_bfloat16*)hb, DFF, D);
            // 7. f = h @ W2 + b2  (fp32)
            mm_bf16_kernel<64, 0><<<dim3(D / 128, M / 64), 256, 0, stream>>>(
                hb, W2T, b2l, nullptr, nullptr, nullptr, fbuf, nullptr, nullptr, nullptr, D, DFF);
            // 8. x = x2 + ln(ln(f, lnf), n1|n2)
            const float* og = half ? n2g : n1g;
            const float* ob = half ? n2b : n1b;
            ln2_res_kernel<<<M, 256, 0, stream>>>(fbuf, lfg, lfb, og, ob, x2, x);
        }
    }
    ln_bf16_kernel<<<M, 256, 0, stream>>>(x, nf_g, nf_b, (__hip_bfloat16*)xnb);
    mm_bf16_kernel<128, 0><<<dim3(V / 128, M / 128), 256, 0, stream>>>(
        xnb, WfT, bfin, nullptr, nullptr, nullptr, out, nullptr, nullptr, nullptr, V, D);
}

// Round 4
// 1750.093 us; speedup vs baseline: 6.6715x; 1.2595x over previous
//
#include <hip/hip_runtime.h>
#include <hip/hip_bf16.h>
#include <math.h>

#define LNUM 4
#define H 16
#define D 1024
#define HS 64
#define DFF 5120
#define V 32000
#define BB 2
#define T 1024
#define M (BB*T)          // 2048 token rows
#define EPS 1e-5f

typedef __attribute__((ext_vector_type(8))) short bf16x8;
typedef __attribute__((ext_vector_type(4))) float f32x4;

// async global->LDS, 16B per lane (wave-uniform LDS base + lane*16)
__device__ __forceinline__ void gload16(const void* g, void* l) {
    __builtin_amdgcn_global_load_lds(
        (const __attribute__((address_space(1))) void*)g,
        (__attribute__((address_space(3))) void*)l, 16, 0, 0);
}

__device__ __forceinline__ float wred_sum(float v) {
    #pragma unroll
    for (int off = 32; off; off >>= 1) v += __shfl_xor(v, off, 64);
    return v;
}

// ---------------------------------------------------------------------------
// embed
// ---------------------------------------------------------------------------
__global__ __launch_bounds__(256) void embed_kernel(const int* __restrict__ idx,
        const float* __restrict__ tok, const float* __restrict__ pos,
        float* __restrict__ x) {
    int row = blockIdx.x;
    int t = row & (T - 1);
    int tok_id = idx[row];
    int c = threadIdx.x * 4;
    float4 a = *(const float4*)&tok[(size_t)tok_id * D + c];
    float4 p = *(const float4*)&pos[(size_t)t * D + c];
    a.x += p.x; a.y += p.y; a.z += p.z; a.w += p.w;
    *(float4*)&x[(size_t)row * D + c] = a;
}

// ---------------------------------------------------------------------------
// wave-per-row LN -> bf16 (4 rows per 256-thread block, no barriers)
// lane holds 16 elems: 4 chunks of float4 at col = c*256 + lane*4
// ---------------------------------------------------------------------------
__global__ __launch_bounds__(256) void ln_bf16_w4_kernel(const float* __restrict__ in,
        const float* __restrict__ g, const float* __restrict__ b,
        __hip_bfloat16* __restrict__ out) {
    int w = threadIdx.x >> 6, lane = threadIdx.x & 63;
    int row = blockIdx.x * 4 + w;
    const float* rp = in + (size_t)row * D;
    float4 xv[4];
    float s = 0.f;
    #pragma unroll
    for (int c = 0; c < 4; ++c) {
        xv[c] = *(const float4*)&rp[c * 256 + lane * 4];
        s += xv[c].x + xv[c].y + xv[c].z + xv[c].w;
    }
    float mu = wred_sum(s) * (1.0f / D);
    float vs = 0.f;
    #pragma unroll
    for (int c = 0; c < 4; ++c) {
        xv[c].x -= mu; xv[c].y -= mu; xv[c].z -= mu; xv[c].w -= mu;
        vs += xv[c].x*xv[c].x + xv[c].y*xv[c].y + xv[c].z*xv[c].z + xv[c].w*xv[c].w;
    }
    float rs = rsqrtf(wred_sum(vs) * (1.0f / D) + EPS);
    #pragma unroll
    for (int c = 0; c < 4; ++c) {
        int j = c * 256 + lane * 4;
        float4 gv = *(const float4*)&g[j];
        float4 bv = *(const float4*)&b[j];
        union { ushort4 u4; __hip_bfloat16 h[4]; } pk;
        pk.h[0] = __float2bfloat16(xv[c].x * rs * gv.x + bv.x);
        pk.h[1] = __float2bfloat16(xv[c].y * rs * gv.y + bv.y);
        pk.h[2] = __float2bfloat16(xv[c].z * rs * gv.z + bv.z);
        pk.h[3] = __float2bfloat16(xv[c].w * rs * gv.w + bv.w);
        *(ushort4*)&out[(size_t)row * D + j] = pk.u4;
    }
}

// ---------------------------------------------------------------------------
// FFN tail, fused:  f = sum(partials) + b2 ;  x = res + ln(ln(f,g1,b1),g2,b2g)
// then xn = ln(x, gn, bn) -> bf16   (next half's pre-attn LN / final LN)
// wave-per-row, 4 rows/block.
// ---------------------------------------------------------------------------
template<int NP>
__global__ __launch_bounds__(256) void ffn_tail_kernel(
        const float* __restrict__ part, const float* __restrict__ b2,
        const float* __restrict__ g1, const float* __restrict__ b1,
        const float* __restrict__ g2, const float* __restrict__ b2g,
        const float* __restrict__ res, float* __restrict__ xout,
        const float* __restrict__ gn, const float* __restrict__ bn,
        __hip_bfloat16* __restrict__ xnout) {
    const size_t MD = (size_t)M * D;
    int w = threadIdx.x >> 6, lane = threadIdx.x & 63;
    int row = blockIdx.x * 4 + w;
    size_t ro = (size_t)row * D;
    float4 f[4];
    float s = 0.f;
    #pragma unroll
    for (int c = 0; c < 4; ++c) {
        int j = c * 256 + lane * 4;
        float4 acc = *(const float4*)&b2[j];
        #pragma unroll
        for (int pI = 0; pI < NP; ++pI) {
            float4 pv = *(const float4*)&part[pI * MD + ro + j];
            acc.x += pv.x; acc.y += pv.y; acc.z += pv.z; acc.w += pv.w;
        }
        f[c] = acc;
        s += acc.x + acc.y + acc.z + acc.w;
    }
    // LN 1 (lnf)
    float mu = wred_sum(s) * (1.0f / D);
    float vs = 0.f;
    #pragma unroll
    for (int c = 0; c < 4; ++c) {
        f[c].x -= mu; f[c].y -= mu; f[c].z -= mu; f[c].w -= mu;
        vs += f[c].x*f[c].x + f[c].y*f[c].y + f[c].z*f[c].z + f[c].w*f[c].w;
    }
    float rs = rsqrtf(wred_sum(vs) * (1.0f / D) + EPS);
    float s2 = 0.f;
    #pragma unroll
    for (int c = 0; c < 4; ++c) {
        int j = c * 256 + lane * 4;
        float4 gv = *(const float4*)&g1[j];
        float4 bv = *(const float4*)&b1[j];
        f[c].x = f[c].x * rs * gv.x + bv.x;
        f[c].y = f[c].y * rs * gv.y + bv.y;
        f[c].z = f[c].z * rs * gv.z + bv.z;
        f[c].w = f[c].w * rs * gv.w + bv.w;
        s2 += f[c].x + f[c].y + f[c].z + f[c].w;
    }
    // LN 2 (n1|n2) + residual
    float mu2 = wred_sum(s2) * (1.0f / D);
    float vs2 = 0.f;
    #pragma unroll
    for (int c = 0; c < 4; ++c) {
        f[c].x -= mu2; f[c].y -= mu2; f[c].z -= mu2; f[c].w -= mu2;
        vs2 += f[c].x*f[c].x + f[c].y*f[c].y + f[c].z*f[c].z + f[c].w*f[c].w;
    }
    float rs2 = rsqrtf(wred_sum(vs2) * (1.0f / D) + EPS);
    float s3 = 0.f;
    #pragma unroll
    for (int c = 0; c < 4; ++c) {
        int j = c * 256 + lane * 4;
        float4 gv = *(const float4*)&g2[j];
        float4 bv = *(const float4*)&b2g[j];
        float4 rv = *(const float4*)&res[ro + j];
        f[c].x = rv.x + f[c].x * rs2 * gv.x + bv.x;
        f[c].y = rv.y + f[c].y * rs2 * gv.y + bv.y;
        f[c].z = rv.z + f[c].z * rs2 * gv.z + bv.z;
        f[c].w = rv.w + f[c].w * rs2 * gv.w + bv.w;
        *(float4*)&xout[ro + j] = f[c];
        s3 += f[c].x + f[c].y + f[c].z + f[c].w;
    }
    // LN 3 (next-half pre-attn LN, or final nf) -> bf16
    float mu3 = wred_sum(s3) * (1.0f / D);
    float vs3 = 0.f;
    #pragma unroll
    for (int c = 0; c < 4; ++c) {
        f[c].x -= mu3; f[c].y -= mu3; f[c].z -= mu3; f[c].w -= mu3;
        vs3 += f[c].x*f[c].x + f[c].y*f[c].y + f[c].z*f[c].z + f[c].w*f[c].w;
    }
    float rs3 = rsqrtf(wred_sum(vs3) * (1.0f / D) + EPS);
    #pragma unroll
    for (int c = 0; c < 4; ++c) {
        int j = c * 256 + lane * 4;
        float4 gv = *(const float4*)&gn[j];
        float4 bv = *(const float4*)&bn[j];
        union { ushort4 u4; __hip_bfloat16 h[4]; } pk;
        pk.h[0] = __float2bfloat16(f[c].x * rs3 * gv.x + bv.x);
        pk.h[1] = __float2bfloat16(f[c].y * rs3 * gv.y + bv.y);
        pk.h[2] = __float2bfloat16(f[c].z * rs3 * gv.z + bv.z);
        pk.h[3] = __float2bfloat16(f[c].w * rs3 * gv.w + bv.w);
        *(ushort4*)&xnout[ro + j] = pk.u4;
    }
}

// ---------------------------------------------------------------------------
// tiled transpose + fp32->bf16: in [R][C] f32 -> out [C][R] bf16
// ---------------------------------------------------------------------------
__global__ __launch_bounds__(256) void transpose_bf16_kernel(
        const float* __restrict__ in, __hip_bfloat16* __restrict__ out,
        int R, int C, size_t zin, size_t zout) {
    __shared__ float t[32][33];
    in += (size_t)blockIdx.z * zin; out += (size_t)blockIdx.z * zout;
    int tx = threadIdx.x & 31, ty = threadIdx.x >> 5;
    int c0 = blockIdx.x * 32, r0 = blockIdx.y * 32;
    #pragma unroll
    for (int i = 0; i < 4; ++i)
        t[ty + i * 8][tx] = in[(size_t)(r0 + ty + i * 8) * C + c0 + tx];
    __syncthreads();
    #pragma unroll
    for (int i = 0; i < 4; ++i)
        out[(size_t)(c0 + ty + i * 8) * R + r0 + tx] = __float2bfloat16(t[tx][ty + i * 8]);
}

// ---------------------------------------------------------------------------
// q/k/v weight transpose in ONE launch: z in [0,48): which=z>>4, head=z&15
// in: [H][D][HS] f32 each; out: [3][H][HS][D] bf16 contiguous
// grid (HS/32, D/32, 48)
// ---------------------------------------------------------------------------
__global__ __launch_bounds__(256) void transpose_qkv_kernel(
        const float* __restrict__ Wq, const float* __restrict__ Wk,
        const float* __restrict__ Wv, short* __restrict__ outT) {
    __shared__ float t[32][33];
    int z = blockIdx.z;
    int which = z >> 4, h = z & 15;
    const float* in = (which == 0 ? Wq : which == 1 ? Wk : Wv) + (size_t)h * D * HS;
    __hip_bfloat16* out = (__hip_bfloat16*)outT + ((size_t)which * H + h) * HS * D;
    int tx = threadIdx.x & 31, ty = threadIdx.x >> 5;
    int c0 = blockIdx.x * 32, r0 = blockIdx.y * 32;
    #pragma unroll
    for (int i = 0; i < 4; ++i)
        t[ty + i * 8][tx] = in[(size_t)(r0 + ty + i * 8) * HS + c0 + tx];
    __syncthreads();
    #pragma unroll
    for (int i = 0; i < 4; ++i)
        out[(size_t)(c0 + ty + i * 8) * D + r0 + tx] = __float2bfloat16(t[tx][ty + i * 8]);
}

// ---------------------------------------------------------------------------
// bf16->bf16 transpose for V: in [T][HS] per bh -> out [HS][T]
// ---------------------------------------------------------------------------
__global__ __launch_bounds__(256) void transpose_v_kernel(const short* __restrict__ in,
        short* __restrict__ out) {
    __shared__ short t[32][33];
    int z = blockIdx.z;
    in  += (size_t)z * T * HS;
    out += (size_t)z * HS * T;
    int tx = threadIdx.x & 31, ty = threadIdx.x >> 5;
    int c0 = blockIdx.x * 32, r0 = blockIdx.y * 32;
    #pragma unroll
    for (int i = 0; i < 4; ++i)
        t[ty + i * 8][tx] = in[(size_t)(r0 + ty + i * 8) * HS + c0 + tx];
    __syncthreads();
    #pragma unroll
    for (int i = 0; i < 4; ++i)
        out[(size_t)(c0 + ty + i * 8) * T + r0 + tx] = t[tx][ty + i * 8];
}

// ---------------------------------------------------------------------------
// bf16 MFMA GEMM (m97 structure): C = epi(A[M,Kl] @ BT[N,Kl]^T + bias)
// lda = row stride of A and BT (full K); Kloop = K extent per block.
// blockIdx.z = split-K slice (A,BT advanced by z*Kloop along K).
// XCD-aware bijective swizzle on (x,y) grid (requires nwg%8==0).
// EPI: 0 f32 C0 ; 1 +res f32 C0 ; 2 leaky bf16 Cbf ; 3 qkv scatter bf16 ;
//      4 raw partial f32 -> C0 + z*2048*N (no bias)
// ---------------------------------------------------------------------------
template<int BM, int EPI>
__global__ __launch_bounds__(256) void mm_bf16_kernel(
        const short* __restrict__ A, const short* __restrict__ BT,
        const float* __restrict__ bias0, const float* __restrict__ bias1,
        const float* __restrict__ bias2, const float* __restrict__ res,
        float* __restrict__ C0, float* __restrict__ C1, float* __restrict__ C2,
        __hip_bfloat16* __restrict__ Cbf, int N, int Kloop, int lda) {
    constexpr int BK = 32, BN = 128;
    constexpr int MI = BM / 32;
    __shared__ __align__(16) short As[BM * BK];
    __shared__ __align__(16) short Bs[BN * BK];
    int nwg = gridDim.x * gridDim.y;
    int bid = blockIdx.y * gridDim.x + blockIdx.x;
    int bx = blockIdx.x, by = blockIdx.y;
    if (!(nwg & 7)) {                       // bijective XCD swizzle
        int s = (bid & 7) * (nwg >> 3) + (bid >> 3);
        bx = s % gridDim.x; by = s / gridDim.x;
    }
    A  += (size_t)blockIdx.z * Kloop;
    BT += (size_t)blockIdx.z * Kloop;
    int tid = threadIdx.x;
    int lane = tid & 63, wid = tid >> 6;
    int wr = wid >> 1, wc = wid & 1;
    int l15 = lane & 15, l16 = lane >> 4;
    int m0 = by * BM, n0 = bx * BN;
    f32x4 acc[MI][4] = {};
    int sr = tid >> 2, sk = (tid & 3) * 8;
    const short* Ag = A + (size_t)(m0 + sr) * lda + sk;
    const short* Bg = BT + (size_t)(n0 + sr) * lda + sk;
    short* Asl = As + tid * 8;
    short* Bsl = Bs + tid * 8;
    for (int k0 = 0; k0 < Kloop; k0 += BK) {
        #pragma unroll
        for (int i = 0; i < BM / 64; ++i)
            gload16(Ag + k0 + (size_t)(i * 64) * lda, Asl + i * 2048);
        #pragma unroll
        for (int i = 0; i < 2; ++i)
            gload16(Bg + k0 + (size_t)(i * 64) * lda, Bsl + i * 2048);
        __syncthreads();
        bf16x8 af[MI], bfv[4];
        const short* Ab = As + (wr * (BM / 2) + l15) * BK + l16 * 8;
        const short* Bb = Bs + (wc * 64 + l15) * BK + l16 * 8;
        #pragma unroll
        for (int mi = 0; mi < MI; ++mi) af[mi] = *(const bf16x8*)(Ab + mi * 16 * BK);
        #pragma unroll
        for (int ni = 0; ni < 4; ++ni) bfv[ni] = *(const bf16x8*)(Bb + ni * 16 * BK);
        __builtin_amdgcn_s_setprio(1);
        #pragma unroll
        for (int mi = 0; mi < MI; ++mi)
            #pragma unroll
            for (int ni = 0; ni < 4; ++ni)
                acc[mi][ni] = __builtin_amdgcn_mfma_f32_16x16x32_bf16(
                    af[mi], bfv[ni], acc[mi][ni], 0, 0, 0);
        __builtin_amdgcn_s_setprio(0);
        __syncthreads();
    }
    int rbase = m0 + wr * (BM / 2) + l16 * 4;
    int cbase = n0 + wc * 64 + l15;
    size_t zoff = (EPI == 4) ? (size_t)blockIdx.z * 2048 * N : 0;
    #pragma unroll
    for (int mi = 0; mi < MI; ++mi) {
        #pragma unroll
        for (int ni = 0; ni < 4; ++ni) {
            int col = cbase + ni * 16;
            float bv = 0.f;
            if (EPI == 3) {
                int z = col >> 10, nn = col & 1023;
                bv = (z == 0 ? bias0 : z == 1 ? bias1 : bias2)[nn];
            } else if (EPI != 4) bv = bias0[col];
            #pragma unroll
            for (int r = 0; r < 4; ++r) {
                int row = rbase + mi * 16 + r;
                float v = acc[mi][ni][r] + bv;
                if (EPI == 0) {
                    C0[(size_t)row * N + col] = v;
                } else if (EPI == 1) {
                    C0[(size_t)row * N + col] = v + res[(size_t)row * N + col];
                } else if (EPI == 2) {
                    v = v > 0.f ? v : 0.01f * v;
                    Cbf[(size_t)row * N + col] = __float2bfloat16(v);
                } else if (EPI == 4) {
                    C0[zoff + (size_t)row * N + col] = v;
                } else {
                    int z = col >> 10;
                    int hh = (col >> 6) & 15, e = col & 63;
                    int b = row >> 10, t = row & (T - 1);
                    __hip_bfloat16* dst = (__hip_bfloat16*)(z == 0 ? C0 : (z == 1 ? C1 : C2));
                    dst[(((size_t)(b * H + hh)) * T + t) * HS + e] = __float2bfloat16(v);
                }
            }
        }
    }
}

// ---------------------------------------------------------------------------
// MFMA flash attention, bf16. grid (T/64, B*H), 256 threads = 4 waves.
// ---------------------------------------------------------------------------
template<int CAUSAL>
__global__ __launch_bounds__(256) void attn_mfma_kernel(
        const short* __restrict__ q, const short* __restrict__ k,
        const short* __restrict__ vt, __hip_bfloat16* __restrict__ att) {
    __shared__ __align__(16) short Ks[64 * 64];
    __shared__ __align__(16) short Vs[64 * 64];
    __shared__ __align__(16) short Ps[4][16 * 64];
    int bh = blockIdx.y;
    int bI = bh >> 4, h = bh & 15;
    int tix = blockIdx.x;
    if (CAUSAL) tix = (tix & 1) ? (15 - (tix >> 1)) : (tix >> 1);
    int t0 = tix * 64;
    int tid = threadIdx.x;
    int lane = tid & 63, w = tid >> 6;
    int l15 = lane & 15, l16 = lane >> 4;

    const short* Qg = q + ((size_t)bh * T + t0 + w * 16 + l15) * HS + l16 * 8;
    bf16x8 qf0 = *(const bf16x8*)Qg;
    bf16x8 qf1 = *(const bf16x8*)(Qg + 32);

    const char* Kg = (const char*)(k + (size_t)bh * T * HS);
    const char* Vg = (const char*)(vt + (size_t)bh * HS * T);

    float m_run[4] = {-1e30f, -1e30f, -1e30f, -1e30f};
    float l_run[4] = {0.f, 0.f, 0.f, 0.f};
    f32x4 acc_o[4] = {};
    short* Pw = Ps[w];
    int pswz = (l15 & 7) << 4;

    int n_tiles = CAUSAL ? (t0 / 64 + 1) : (T / 64);
    for (int it = 0; it < n_tiles; ++it) {
        int s0 = it * 64;
        __syncthreads();
        #pragma unroll
        for (int i = 0; i < 2; ++i) {
            int o = i * 4096 + tid * 16;
            int row = o >> 7, bir = o & 127;
            int sb = bir ^ ((row & 7) << 4);
            gload16(Kg + (size_t)(s0 + row) * 128 + sb, (char*)Ks + o);
            gload16(Vg + (size_t)row * 2048 + s0 * 2 + sb, (char*)Vs + o);
        }
        __syncthreads();

        f32x4 acc_s[4] = {};
        __builtin_amdgcn_s_setprio(1);
        #pragma unroll
        for (int c = 0; c < 4; ++c) {
            int row = c * 16 + l15;
            const char* kb_ = (const char*)Ks + row * 128;
            int swz = (row & 7) << 4;
            bf16x8 kf0 = *(const bf16x8*)(kb_ + ((l16 * 16) ^ swz));
            bf16x8 kf1 = *(const bf16x8*)(kb_ + ((64 + l16 * 16) ^ swz));
            acc_s[c] = __builtin_amdgcn_mfma_f32_16x16x32_bf16(qf0, kf0, acc_s[c], 0, 0, 0);
            acc_s[c] = __builtin_amdgcn_mfma_f32_16x16x32_bf16(qf1, kf1, acc_s[c], 0, 0, 0);
        }
        __builtin_amdgcn_s_setprio(0);

        bool domask = CAUSAL && (it == n_tiles - 1);
        #pragma unroll
        for (int r = 0; r < 4; ++r) {
            float sc[4];
            #pragma unroll
            for (int c = 0; c < 4; ++c) {
                float s = acc_s[c][r];
                if (domask && (s0 + c * 16 + l15) > (t0 + w * 16 + l16 * 4 + r)) s = -1e30f;
                sc[c] = s;
            }
            float tm = fmaxf(fmaxf(sc[0], sc[1]), fmaxf(sc[2], sc[3]));
            tm = fmaxf(tm, __shfl_xor(tm, 1, 16));
            tm = fmaxf(tm, __shfl_xor(tm, 2, 16));
            tm = fmaxf(tm, __shfl_xor(tm, 4, 16));
            tm = fmaxf(tm, __shfl_xor(tm, 8, 16));
            float mn = fmaxf(m_run[r], tm);
            int prow = l16 * 4 + r;
            int pswzr = (prow & 7) << 4;
            float ls = 0.f;
            #pragma unroll
            for (int c = 0; c < 4; ++c) {
                float pv = __expf(0.125f * (sc[c] - mn));
                int pbyte = prow * 128 + (((c * 16 + l15) * 2) ^ pswzr);
                *(__hip_bfloat16*)((char*)Pw + pbyte) = __float2bfloat16(pv);
                ls += pv;
            }
            ls += __shfl_xor(ls, 1, 16);
            ls += __shfl_xor(ls, 2, 16);
            ls += __shfl_xor(ls, 4, 16);
            ls += __shfl_xor(ls, 8, 16);
            float alpha = __expf(0.125f * (m_run[r] - mn));
            l_run[r] = l_run[r] * alpha + ls;
            m_run[r] = mn;
            acc_o[0][r] *= alpha; acc_o[1][r] *= alpha;
            acc_o[2][r] *= alpha; acc_o[3][r] *= alpha;
        }

        const char* Pb = (const char*)Pw + l15 * 128;
        bf16x8 pa0 = *(const bf16x8*)(Pb + ((l16 * 16) ^ pswz));
        bf16x8 pa1 = *(const bf16x8*)(Pb + ((64 + l16 * 16) ^ pswz));
        __builtin_amdgcn_s_setprio(1);
        #pragma unroll
        for (int ni = 0; ni < 4; ++ni) {
            int row = ni * 16 + l15;
            const char* vb_ = (const char*)Vs + row * 128;
            int swz = (row & 7) << 4;
            bf16x8 vf0 = *(const bf16x8*)(vb_ + ((l16 * 16) ^ swz));
            bf16x8 vf1 = *(const bf16x8*)(vb_ + ((64 + l16 * 16) ^ swz));
            acc_o[ni] = __builtin_amdgcn_mfma_f32_16x16x32_bf16(pa0, vf0, acc_o[ni], 0, 0, 0);
            acc_o[ni] = __builtin_amdgcn_mfma_f32_16x16x32_bf16(pa1, vf1, acc_o[ni], 0, 0, 0);
        }
        __builtin_amdgcn_s_setprio(0);
    }

    float inv[4];
    #pragma unroll
    for (int r = 0; r < 4; ++r) inv[r] = 1.0f / l_run[r];
    #pragma unroll
    for (int ni = 0; ni < 4; ++ni) {
        #pragma unroll
        for (int r = 0; r < 4; ++r) {
            size_t orow = ((size_t)(bI * T) + t0 + w * 16 + l16 * 4 + r) * D
                        + h * HS + ni * 16 + l15;
            att[orow] = __float2bfloat16(acc_o[ni][r] * inv[r]);
        }
    }
}

// ---------------------------------------------------------------------------
extern "C" void kernel_launch(void* const* d_in, const int* in_sizes, int n_in,
                              void* d_out, int out_size, void* d_ws, size_t ws_size,
                              hipStream_t stream) {
    const int*   idx     = (const int*)d_in[0];
    const float* tok_emb = (const float*)d_in[1];
    const float* pos_emb = (const float*)d_in[2];
    const float* Wq_u = (const float*)d_in[3],  *bq_u = (const float*)d_in[4];
    const float* Wk_u = (const float*)d_in[5],  *bk_u = (const float*)d_in[6];
    const float* Wv_u = (const float*)d_in[7],  *bv_u = (const float*)d_in[8];
    const float* Wp_u = (const float*)d_in[9],  *bp_u = (const float*)d_in[10];
    const float* Wq_m = (const float*)d_in[11], *bq_m = (const float*)d_in[12];
    const float* Wk_m = (const float*)d_in[13], *bk_m = (const float*)d_in[14];
    const float* Wv_m = (const float*)d_in[15], *bv_m = (const float*)d_in[16];
    const float* Wp_m = (const float*)d_in[17], *bp_m = (const float*)d_in[18];
    const float* W1   = (const float*)d_in[19], *b1   = (const float*)d_in[20];
    const float* W2   = (const float*)d_in[21], *b2   = (const float*)d_in[22];
    const float* lnf_g = (const float*)d_in[23], *lnf_b = (const float*)d_in[24];
    const float* n1_g  = (const float*)d_in[25], *n1_b  = (const float*)d_in[26];
    const float* n2_g  = (const float*)d_in[27], *n2_b  = (const float*)d_in[28];
    const float* nf_g  = (const float*)d_in[29], *nf_b  = (const float*)d_in[30];
    const float* Wfin  = (const float*)d_in[31], *bfin  = (const float*)d_in[32];
    float* out = (float*)d_out;

    char* p = (char*)d_ws;
    auto alloc = [&](size_t bytes) { char* r = p; p += (bytes + 255) & ~255ull; return r; };
    float* x    = (float*)alloc((size_t)M * D * 4);
    float* x2   = (float*)alloc((size_t)M * D * 4);
    float* w2p  = (float*)alloc((size_t)4 * M * D * 4);   // W2 split-K partials
    short* qbf  = (short*)alloc((size_t)M * D * 2);
    short* kbf  = (short*)alloc((size_t)M * D * 2);
    short* vbf  = (short*)alloc((size_t)M * D * 2);
    short* vtb  = (short*)alloc((size_t)M * D * 2);
    short* xnb  = (short*)alloc((size_t)M * D * 2);
    short* attb = (short*)alloc((size_t)M * D * 2);
    short* hb   = (short*)alloc((size_t)M * DFF * 2);
    short* WqkvT= (short*)alloc((size_t)3 * 1024 * 1024 * 2);
    short* WpT  = (short*)alloc((size_t)1024 * 1024 * 2);
    short* W1T  = (short*)alloc((size_t)D * DFF * 2);
    short* W2T  = (short*)alloc((size_t)DFF * D * 2);
    short* WfT  = (short*)alloc((size_t)D * V * 2);

    embed_kernel<<<M, 256, 0, stream>>>(idx, tok_emb, pos_emb, x);
    // first pre-attn LN (later ones are fused into ffn_tail)
    ln_bf16_w4_kernel<<<M / 4, 256, 0, stream>>>(x, n1_g, n1_b, (__hip_bfloat16*)xnb);
    transpose_bf16_kernel<<<dim3(V / 32, D / 32, 1), 256, 0, stream>>>(
        Wfin, (__hip_bfloat16*)WfT, D, V, 0, 0);

    for (int l = 0; l < LNUM; ++l) {
        const float *n1g = n1_g + l * D, *n1b = n1_b + l * D;
        const float *n2g = n2_g + l * D, *n2b = n2_b + l * D;
        const float *lfg = lnf_g + l * D, *lfb = lnf_b + l * D;
        const float *W1l = W1 + (size_t)l * D * DFF, *b1l = b1 + l * DFF;
        const float *W2l = W2 + (size_t)l * DFF * D, *b2l = b2 + l * D;
        transpose_bf16_kernel<<<dim3(DFF / 32, D / 32, 1), 256, 0, stream>>>(
            W1l, (__hip_bfloat16*)W1T, D, DFF, 0, 0);
        transpose_bf16_kernel<<<dim3(D / 32, DFF / 32, 1), 256, 0, stream>>>(
            W2l, (__hip_bfloat16*)W2T, DFF, D, 0, 0);
        for (int half = 0; half < 2; ++half) {
            const float *Wq_, *bq_, *Wk_, *bk_, *Wv_, *bv_, *Wp_, *bp_;
            if (half == 0) { Wq_ = Wq_u; bq_ = bq_u; Wk_ = Wk_u; bk_ = bk_u;
                             Wv_ = Wv_u; bv_ = bv_u; Wp_ = Wp_u; bp_ = bp_u; }
            else           { Wq_ = Wq_m; bq_ = bq_m; Wk_ = Wk_m; bk_ = bk_m;
                             Wv_ = Wv_m; bv_ = bv_m; Wp_ = Wp_m; bp_ = bp_m; }
            Wq_ += (size_t)l * H * D * HS;  bq_ += l * H * HS;
            Wk_ += (size_t)l * H * D * HS;  bk_ += l * H * HS;
            Wv_ += (size_t)l * H * D * HS;  bv_ += l * H * HS;
            Wp_ += (size_t)l * D * D;       bp_ += l * D;

            transpose_qkv_kernel<<<dim3(HS / 32, D / 32, 48), 256, 0, stream>>>(
                Wq_, Wk_, Wv_, WqkvT);
            transpose_bf16_kernel<<<dim3(D / 32, D / 32, 1), 256, 0, stream>>>(
                Wp_, (__hip_bfloat16*)WpT, D, D, 0, 0);

            // q,k,v = xn @ Wqkv  -> bf16 [B,H,T,HS]   (xn from previous tail)
            mm_bf16_kernel<128, 3><<<dim3(3072 / 128, M / 128), 256, 0, stream>>>(
                xnb, WqkvT, bq_, bk_, bv_, nullptr,
                (float*)qbf, (float*)kbf, (float*)vbf, nullptr, 3072, D, D);
            transpose_v_kernel<<<dim3(HS / 32, T / 32, BB * H), 256, 0, stream>>>(vbf, vtb);
            if (half == 0)
                attn_mfma_kernel<0><<<dim3(T / 64, BB * H), 256, 0, stream>>>(
                    qbf, kbf, vtb, (__hip_bfloat16*)attb);
            else
                attn_mfma_kernel<1><<<dim3(T / 64, BB * H), 256, 0, stream>>>(
                    qbf, kbf, vtb, (__hip_bfloat16*)attb);
            // x2 = x + att @ Wp + bp
            mm_bf16_kernel<64, 1><<<dim3(D / 128, M / 64), 256, 0, stream>>>(
                attb, WpT, bp_, nullptr, nullptr, x, x2, nullptr, nullptr, nullptr, D, D, D);
            // xn = ln(x2, n2) -> bf16
            ln_bf16_w4_kernel<<<M / 4, 256, 0, stream>>>(x2, n2g, n2b, (__hip_bfloat16*)xnb);
            // h = leaky(xn @ W1 + b1) -> bf16
            mm_bf16_kernel<128, 2><<<dim3(DFF / 128, M / 128), 256, 0, stream>>>(
                xnb, W1T, b1l, nullptr, nullptr, nullptr, nullptr, nullptr, nullptr,
                (__hip_bfloat16*)hb, DFF, D, D);
            // W2 split-K x4 -> partials (no bias)
            mm_bf16_kernel<128, 4><<<dim3(D / 128, M / 128, 4), 256, 0, stream>>>(
                hb, W2T, nullptr, nullptr, nullptr, nullptr, w2p, nullptr, nullptr,
                nullptr, D, DFF / 4, DFF);
            // fused FFN tail: f=sum(partials)+b2; x = x2 + ln(ln(f,lnf), n1|n2);
            // xn = ln(x, gnext) for next half (or nf at the very end)
            const float* og = half ? n2g : n1g;
            const float* ob = half ? n2b : n1b;
            const float* gn; const float* bn;
            if (half == 0)      { gn = n1g; bn = n1b; }          // same layer, masked half
            else if (l < LNUM-1){ gn = n1_g + (l+1)*D; bn = n1_b + (l+1)*D; }
            else                { gn = nf_g; bn = nf_b; }        // final LN
            ffn_tail_kernel<4><<<M / 4, 256, 0, stream>>>(
                w2p, b2l, lfg, lfb, og, ob, x2, x, gn, bn, (__hip_bfloat16*)xnb);
        }
    }
    // vocab head (xn already = ln(x, nf))
    mm_bf16_kernel<128, 0><<<dim3(V / 128, M / 128), 256, 0, stream>>>(
        xnb, WfT, bfin, nullptr, nullptr, nullptr, out, nullptr, nullptr, nullptr, V, D, D);
}

// Round 5
// 1707.224 us; speedup vs baseline: 6.8390x; 1.0251x over previous
//
#include <hip/hip_runtime.h>
#include <hip/hip_bf16.h>
#include <math.h>

#define LNUM 4
#define H 16
#define D 1024
#define HS 64
#define DFF 5120
#define V 32000
#define BB 2
#define T 1024
#define M (BB*T)          // 2048 token rows
#define EPS 1e-5f

typedef __attribute__((ext_vector_type(8))) short bf16x8;
typedef __attribute__((ext_vector_type(4))) float f32x4;

// async global->LDS, 16B per lane (wave-uniform LDS base + lane*16)
__device__ __forceinline__ void gload16(const void* g, void* l) {
    __builtin_amdgcn_global_load_lds(
        (const __attribute__((address_space(1))) void*)g,
        (__attribute__((address_space(3))) void*)l, 16, 0, 0);
}

__device__ __forceinline__ float wred_sum(float v) {
    #pragma unroll
    for (int off = 32; off; off >>= 1) v += __shfl_xor(v, off, 64);
    return v;
}

// ---------------------------------------------------------------------------
// embed
// ---------------------------------------------------------------------------
__global__ __launch_bounds__(256) void embed_kernel(const int* __restrict__ idx,
        const float* __restrict__ tok, const float* __restrict__ pos,
        float* __restrict__ x) {
    int row = blockIdx.x;
    int t = row & (T - 1);
    int tok_id = idx[row];
    int c = threadIdx.x * 4;
    float4 a = *(const float4*)&tok[(size_t)tok_id * D + c];
    float4 p = *(const float4*)&pos[(size_t)t * D + c];
    a.x += p.x; a.y += p.y; a.z += p.z; a.w += p.w;
    *(float4*)&x[(size_t)row * D + c] = a;
}

// ---------------------------------------------------------------------------
// wave-per-row LN -> bf16 (4 rows per 256-thread block, no barriers)
// ---------------------------------------------------------------------------
__global__ __launch_bounds__(256) void ln_bf16_w4_kernel(const float* __restrict__ in,
        const float* __restrict__ g, const float* __restrict__ b,
        __hip_bfloat16* __restrict__ out) {
    int w = threadIdx.x >> 6, lane = threadIdx.x & 63;
    int row = blockIdx.x * 4 + w;
    const float* rp = in + (size_t)row * D;
    float4 xv[4];
    float s = 0.f;
    #pragma unroll
    for (int c = 0; c < 4; ++c) {
        xv[c] = *(const float4*)&rp[c * 256 + lane * 4];
        s += xv[c].x + xv[c].y + xv[c].z + xv[c].w;
    }
    float mu = wred_sum(s) * (1.0f / D);
    float vs = 0.f;
    #pragma unroll
    for (int c = 0; c < 4; ++c) {
        xv[c].x -= mu; xv[c].y -= mu; xv[c].z -= mu; xv[c].w -= mu;
        vs += xv[c].x*xv[c].x + xv[c].y*xv[c].y + xv[c].z*xv[c].z + xv[c].w*xv[c].w;
    }
    float rs = rsqrtf(wred_sum(vs) * (1.0f / D) + EPS);
    #pragma unroll
    for (int c = 0; c < 4; ++c) {
        int j = c * 256 + lane * 4;
        float4 gv = *(const float4*)&g[j];
        float4 bv = *(const float4*)&b[j];
        union { ushort4 u4; __hip_bfloat16 h[4]; } pk;
        pk.h[0] = __float2bfloat16(xv[c].x * rs * gv.x + bv.x);
        pk.h[1] = __float2bfloat16(xv[c].y * rs * gv.y + bv.y);
        pk.h[2] = __float2bfloat16(xv[c].z * rs * gv.z + bv.z);
        pk.h[3] = __float2bfloat16(xv[c].w * rs * gv.w + bv.w);
        *(ushort4*)&out[(size_t)row * D + j] = pk.u4;
    }
}

// ---------------------------------------------------------------------------
// FFN tail, fused:  f = sum(partials)+b2 ; x = res + ln(ln(f,g1,b1),g2,b2g)
// then xn = ln(x, gn, bn) -> bf16
// ---------------------------------------------------------------------------
template<int NP>
__global__ __launch_bounds__(256) void ffn_tail_kernel(
        const float* __restrict__ part, const float* __restrict__ b2,
        const float* __restrict__ g1, const float* __restrict__ b1,
        const float* __restrict__ g2, const float* __restrict__ b2g,
        const float* __restrict__ res, float* __restrict__ xout,
        const float* __restrict__ gn, const float* __restrict__ bn,
        __hip_bfloat16* __restrict__ xnout) {
    const size_t MD = (size_t)M * D;
    int w = threadIdx.x >> 6, lane = threadIdx.x & 63;
    int row = blockIdx.x * 4 + w;
    size_t ro = (size_t)row * D;
    float4 f[4];
    float s = 0.f;
    #pragma unroll
    for (int c = 0; c < 4; ++c) {
        int j = c * 256 + lane * 4;
        float4 acc = *(const float4*)&b2[j];
        #pragma unroll
        for (int pI = 0; pI < NP; ++pI) {
            float4 pv = *(const float4*)&part[pI * MD + ro + j];
            acc.x += pv.x; acc.y += pv.y; acc.z += pv.z; acc.w += pv.w;
        }
        f[c] = acc;
        s += acc.x + acc.y + acc.z + acc.w;
    }
    float mu = wred_sum(s) * (1.0f / D);
    float vs = 0.f;
    #pragma unroll
    for (int c = 0; c < 4; ++c) {
        f[c].x -= mu; f[c].y -= mu; f[c].z -= mu; f[c].w -= mu;
        vs += f[c].x*f[c].x + f[c].y*f[c].y + f[c].z*f[c].z + f[c].w*f[c].w;
    }
    float rs = rsqrtf(wred_sum(vs) * (1.0f / D) + EPS);
    float s2 = 0.f;
    #pragma unroll
    for (int c = 0; c < 4; ++c) {
        int j = c * 256 + lane * 4;
        float4 gv = *(const float4*)&g1[j];
        float4 bv = *(const float4*)&b1[j];
        f[c].x = f[c].x * rs * gv.x + bv.x;
        f[c].y = f[c].y * rs * gv.y + bv.y;
        f[c].z = f[c].z * rs * gv.z + bv.z;
        f[c].w = f[c].w * rs * gv.w + bv.w;
        s2 += f[c].x + f[c].y + f[c].z + f[c].w;
    }
    float mu2 = wred_sum(s2) * (1.0f / D);
    float vs2 = 0.f;
    #pragma unroll
    for (int c = 0; c < 4; ++c) {
        f[c].x -= mu2; f[c].y -= mu2; f[c].z -= mu2; f[c].w -= mu2;
        vs2 += f[c].x*f[c].x + f[c].y*f[c].y + f[c].z*f[c].z + f[c].w*f[c].w;
    }
    float rs2 = rsqrtf(wred_sum(vs2) * (1.0f / D) + EPS);
    float s3 = 0.f;
    #pragma unroll
    for (int c = 0; c < 4; ++c) {
        int j = c * 256 + lane * 4;
        float4 gv = *(const float4*)&g2[j];
        float4 bv = *(const float4*)&b2g[j];
        float4 rv = *(const float4*)&res[ro + j];
        f[c].x = rv.x + f[c].x * rs2 * gv.x + bv.x;
        f[c].y = rv.y + f[c].y * rs2 * gv.y + bv.y;
        f[c].z = rv.z + f[c].z * rs2 * gv.z + bv.z;
        f[c].w = rv.w + f[c].w * rs2 * gv.w + bv.w;
        *(float4*)&xout[ro + j] = f[c];
        s3 += f[c].x + f[c].y + f[c].z + f[c].w;
    }
    float mu3 = wred_sum(s3) * (1.0f / D);
    float vs3 = 0.f;
    #pragma unroll
    for (int c = 0; c < 4; ++c) {
        f[c].x -= mu3; f[c].y -= mu3; f[c].z -= mu3; f[c].w -= mu3;
        vs3 += f[c].x*f[c].x + f[c].y*f[c].y + f[c].z*f[c].z + f[c].w*f[c].w;
    }
    float rs3 = rsqrtf(wred_sum(vs3) * (1.0f / D) + EPS);
    #pragma unroll
    for (int c = 0; c < 4; ++c) {
        int j = c * 256 + lane * 4;
        float4 gv = *(const float4*)&gn[j];
        float4 bv = *(const float4*)&bn[j];
        union { ushort4 u4; __hip_bfloat16 h[4]; } pk;
        pk.h[0] = __float2bfloat16(f[c].x * rs3 * gv.x + bv.x);
        pk.h[1] = __float2bfloat16(f[c].y * rs3 * gv.y + bv.y);
        pk.h[2] = __float2bfloat16(f[c].z * rs3 * gv.z + bv.z);
        pk.h[3] = __float2bfloat16(f[c].w * rs3 * gv.w + bv.w);
        *(ushort4*)&xnout[ro + j] = pk.u4;
    }
}

// ---------------------------------------------------------------------------
// tiled transpose + fp32->bf16: in [R][C] f32 -> out [C][R] bf16
// ---------------------------------------------------------------------------
__global__ __launch_bounds__(256) void transpose_bf16_kernel(
        const float* __restrict__ in, __hip_bfloat16* __restrict__ out,
        int R, int C, size_t zin, size_t zout) {
    __shared__ float t[32][33];
    in += (size_t)blockIdx.z * zin; out += (size_t)blockIdx.z * zout;
    int tx = threadIdx.x & 31, ty = threadIdx.x >> 5;
    int c0 = blockIdx.x * 32, r0 = blockIdx.y * 32;
    #pragma unroll
    for (int i = 0; i < 4; ++i)
        t[ty + i * 8][tx] = in[(size_t)(r0 + ty + i * 8) * C + c0 + tx];
    __syncthreads();
    #pragma unroll
    for (int i = 0; i < 4; ++i)
        out[(size_t)(c0 + ty + i * 8) * R + r0 + tx] = __float2bfloat16(t[tx][ty + i * 8]);
}

// ---------------------------------------------------------------------------
// q/k/v weight transpose in ONE launch
// ---------------------------------------------------------------------------
__global__ __launch_bounds__(256) void transpose_qkv_kernel(
        const float* __restrict__ Wq, const float* __restrict__ Wk,
        const float* __restrict__ Wv, short* __restrict__ outT) {
    __shared__ float t[32][33];
    int z = blockIdx.z;
    int which = z >> 4, h = z & 15;
    const float* in = (which == 0 ? Wq : which == 1 ? Wk : Wv) + (size_t)h * D * HS;
    __hip_bfloat16* out = (__hip_bfloat16*)outT + ((size_t)which * H + h) * HS * D;
    int tx = threadIdx.x & 31, ty = threadIdx.x >> 5;
    int c0 = blockIdx.x * 32, r0 = blockIdx.y * 32;
    #pragma unroll
    for (int i = 0; i < 4; ++i)
        t[ty + i * 8][tx] = in[(size_t)(r0 + ty + i * 8) * HS + c0 + tx];
    __syncthreads();
    #pragma unroll
    for (int i = 0; i < 4; ++i)
        out[(size_t)(c0 + ty + i * 8) * D + r0 + tx] = __float2bfloat16(t[tx][ty + i * 8]);
}

// ---------------------------------------------------------------------------
// bf16->bf16 transpose for V: in [T][HS] per bh -> out [HS][T]
// ---------------------------------------------------------------------------
__global__ __launch_bounds__(256) void transpose_v_kernel(const short* __restrict__ in,
        short* __restrict__ out) {
    __shared__ short t[32][33];
    int z = blockIdx.z;
    in  += (size_t)z * T * HS;
    out += (size_t)z * HS * T;
    int tx = threadIdx.x & 31, ty = threadIdx.x >> 5;
    int c0 = blockIdx.x * 32, r0 = blockIdx.y * 32;
    #pragma unroll
    for (int i = 0; i < 4; ++i)
        t[ty + i * 8][tx] = in[(size_t)(r0 + ty + i * 8) * HS + c0 + tx];
    __syncthreads();
    #pragma unroll
    for (int i = 0; i < 4; ++i)
        out[(size_t)(c0 + ty + i * 8) * T + r0 + tx] = t[tx][ty + i * 8];
}

// ---------------------------------------------------------------------------
// bf16 MFMA GEMM (m97 structure): C = epi(A[M,Kl] @ BT[N,Kl]^T + bias)
// grid = (M-tiles, N-tiles, [splitK]). After the bijective XCD swizzle each
// XCD owns a contiguous chunk of N-panels and sweeps all M-blocks per panel
// (B-panel fetched by exactly one XCD, reused M-tiles times in its L2).
// EPI: 0 f32 C0 ; 1 +res f32 C0 ; 2 leaky bf16 Cbf ; 3 qkv scatter bf16 ;
//      4 raw partial f32 -> C0 + z*M*N
// ---------------------------------------------------------------------------
template<int BM, int EPI>
__global__ __launch_bounds__(256) void mm_bf16_kernel(
        const short* __restrict__ A, const short* __restrict__ BT,
        const float* __restrict__ bias0, const float* __restrict__ bias1,
        const float* __restrict__ bias2, const float* __restrict__ res,
        float* __restrict__ C0, float* __restrict__ C1, float* __restrict__ C2,
        __hip_bfloat16* __restrict__ Cbf, int N, int Kloop, int lda) {
    constexpr int BK = 32, BN = 128;
    constexpr int MI = BM / 32;
    __shared__ __align__(16) short As[BM * BK];
    __shared__ __align__(16) short Bs[BN * BK];
    int nwg = gridDim.x * gridDim.y;
    int bid = blockIdx.y * gridDim.x + blockIdx.x;
    int bx = blockIdx.x, by = blockIdx.y;
    if (!(nwg & 7)) {                       // bijective XCD swizzle
        int s = (bid & 7) * (nwg >> 3) + (bid >> 3);
        bx = s % gridDim.x; by = s / gridDim.x;
    }
    A  += (size_t)blockIdx.z * Kloop;
    BT += (size_t)blockIdx.z * Kloop;
    int tid = threadIdx.x;
    int lane = tid & 63, wid = tid >> 6;
    int wr = wid >> 1, wc = wid & 1;
    int l15 = lane & 15, l16 = lane >> 4;
    int m0 = bx * BM, n0 = by * BN;         // M-major tiles
    f32x4 acc[MI][4] = {};
    int sr = tid >> 2, sk = (tid & 3) * 8;
    const short* Ag = A + (size_t)(m0 + sr) * lda + sk;
    const short* Bg = BT + (size_t)(n0 + sr) * lda + sk;
    short* Asl = As + tid * 8;
    short* Bsl = Bs + tid * 8;
    for (int k0 = 0; k0 < Kloop; k0 += BK) {
        #pragma unroll
        for (int i = 0; i < BM / 64; ++i)
            gload16(Ag + k0 + (size_t)(i * 64) * lda, Asl + i * 2048);
        #pragma unroll
        for (int i = 0; i < 2; ++i)
            gload16(Bg + k0 + (size_t)(i * 64) * lda, Bsl + i * 2048);
        __syncthreads();
        bf16x8 af[MI], bfv[4];
        const short* Ab = As + (wr * (BM / 2) + l15) * BK + l16 * 8;
        const short* Bb = Bs + (wc * 64 + l15) * BK + l16 * 8;
        #pragma unroll
        for (int mi = 0; mi < MI; ++mi) af[mi] = *(const bf16x8*)(Ab + mi * 16 * BK);
        #pragma unroll
        for (int ni = 0; ni < 4; ++ni) bfv[ni] = *(const bf16x8*)(Bb + ni * 16 * BK);
        __builtin_amdgcn_s_setprio(1);
        #pragma unroll
        for (int mi = 0; mi < MI; ++mi)
            #pragma unroll
            for (int ni = 0; ni < 4; ++ni)
                acc[mi][ni] = __builtin_amdgcn_mfma_f32_16x16x32_bf16(
                    af[mi], bfv[ni], acc[mi][ni], 0, 0, 0);
        __builtin_amdgcn_s_setprio(0);
        __syncthreads();
    }
    int rbase = m0 + wr * (BM / 2) + l16 * 4;
    int cbase = n0 + wc * 64 + l15;
    size_t zoff = (EPI == 4) ? (size_t)blockIdx.z * M * N : 0;
    #pragma unroll
    for (int mi = 0; mi < MI; ++mi) {
        #pragma unroll
        for (int ni = 0; ni < 4; ++ni) {
            int col = cbase + ni * 16;
            float bv = 0.f;
            if (EPI == 3) {
                int z = col >> 10, nn = col & 1023;
                bv = (z == 0 ? bias0 : z == 1 ? bias1 : bias2)[nn];
            } else if (EPI != 4) bv = bias0[col];
            #pragma unroll
            for (int r = 0; r < 4; ++r) {
                int row = rbase + mi * 16 + r;
                float v = acc[mi][ni][r] + bv;
                if (EPI == 0) {
                    C0[(size_t)row * N + col] = v;
                } else if (EPI == 1) {
                    C0[(size_t)row * N + col] = v + res[(size_t)row * N + col];
                } else if (EPI == 2) {
                    v = v > 0.f ? v : 0.01f * v;
                    Cbf[(size_t)row * N + col] = __float2bfloat16(v);
                } else if (EPI == 4) {
                    C0[zoff + (size_t)row * N + col] = v;
                } else {
                    int z = col >> 10;
                    int hh = (col >> 6) & 15, e = col & 63;
                    int b = row >> 10, t = row & (T - 1);
                    __hip_bfloat16* dst = (__hip_bfloat16*)(z == 0 ? C0 : (z == 1 ? C1 : C2));
                    dst[(((size_t)(b * H + hh)) * T + t) * HS + e] = __float2bfloat16(v);
                }
            }
        }
    }
}

// ---------------------------------------------------------------------------
// MFMA flash attention, bf16, KVBLK=128. grid (T/64, B*H), 4 waves.
// q,k: bf16 [B,H,T,HS]; vt: bf16 [B,H,HS,T]; out: bf16 concat [M][D].
// K rows (128B): 8-slot XOR swz; V^T/P rows (256B): 16-slot XOR swz.
// ---------------------------------------------------------------------------
template<int CAUSAL>
__global__ __launch_bounds__(256) void attn_mfma_kernel(
        const short* __restrict__ q, const short* __restrict__ k,
        const short* __restrict__ vt, __hip_bfloat16* __restrict__ att) {
    __shared__ __align__(16) short Ks[128 * 64];     // [s][hs]
    __shared__ __align__(16) short Vs[64 * 128];     // [hs][s]
    __shared__ __align__(16) short Ps[4][16 * 128];  // [w][q][s]
    int bh = blockIdx.y;
    int bI = bh >> 4, h = bh & 15;
    int tix = blockIdx.x;
    if (CAUSAL) tix = (tix & 1) ? (15 - (tix >> 1)) : (tix >> 1);
    int t0 = tix * 64;
    int tid = threadIdx.x;
    int lane = tid & 63, w = tid >> 6;
    int l15 = lane & 15, l16 = lane >> 4;

    const short* Qg = q + ((size_t)bh * T + t0 + w * 16 + l15) * HS + l16 * 8;
    bf16x8 qf0 = *(const bf16x8*)Qg;
    bf16x8 qf1 = *(const bf16x8*)(Qg + 32);

    const char* Kg = (const char*)(k + (size_t)bh * T * HS);   // row stride 128B
    const char* Vg = (const char*)(vt + (size_t)bh * HS * T);  // row stride 2048B

    float m_run[4] = {-1e30f, -1e30f, -1e30f, -1e30f};
    float l_run[4] = {0.f, 0.f, 0.f, 0.f};
    f32x4 acc_o[4] = {};
    char* Pw = (char*)Ps[w];
    int pswz = l15 << 4;       // reader-side P swizzle (row = l15)

    int n_tiles = CAUSAL ? (t0 / 128 + 1) : (T / 128);
    for (int it = 0; it < n_tiles; ++it) {
        int s0 = it * 128;
        __syncthreads();
        #pragma unroll
        for (int i = 0; i < 4; ++i) {      // K tile: 16 KB
            int o = i * 4096 + tid * 16;
            int row = o >> 7, bir = o & 127;
            gload16(Kg + (size_t)(s0 + row) * 128 + (bir ^ ((row & 7) << 4)),
                    (char*)Ks + o);
        }
        #pragma unroll
        for (int i = 0; i < 4; ++i) {      // V^T tile: 16 KB
            int o = i * 4096 + tid * 16;
            int row = o >> 8, bb = o & 255;
            gload16(Vg + (size_t)row * 2048 + s0 * 2 + (bb ^ ((row & 15) << 4)),
                    (char*)Vs + o);
        }
        __syncthreads();

        // S = Q @ K^T
        f32x4 acc_s[8] = {};
        __builtin_amdgcn_s_setprio(1);
        #pragma unroll
        for (int c = 0; c < 8; ++c) {
            int row = c * 16 + l15;
            const char* kb_ = (const char*)Ks + row * 128;
            int swz = (row & 7) << 4;
            bf16x8 kf0 = *(const bf16x8*)(kb_ + ((l16 * 16) ^ swz));
            bf16x8 kf1 = *(const bf16x8*)(kb_ + ((64 + l16 * 16) ^ swz));
            acc_s[c] = __builtin_amdgcn_mfma_f32_16x16x32_bf16(qf0, kf0, acc_s[c], 0, 0, 0);
            acc_s[c] = __builtin_amdgcn_mfma_f32_16x16x32_bf16(qf1, kf1, acc_s[c], 0, 0, 0);
        }
        __builtin_amdgcn_s_setprio(0);

        bool domask = CAUSAL && (it == n_tiles - 1);
        #pragma unroll
        for (int r = 0; r < 4; ++r) {
            float sc[8];
            #pragma unroll
            for (int c = 0; c < 8; ++c) {
                float s = acc_s[c][r];
                if (domask && (s0 + c * 16 + l15) > (t0 + w * 16 + l16 * 4 + r)) s = -1e30f;
                sc[c] = s;
            }
            float tm = fmaxf(fmaxf(fmaxf(sc[0], sc[1]), fmaxf(sc[2], sc[3])),
                             fmaxf(fmaxf(sc[4], sc[5]), fmaxf(sc[6], sc[7])));
            tm = fmaxf(tm, __shfl_xor(tm, 1, 16));
            tm = fmaxf(tm, __shfl_xor(tm, 2, 16));
            tm = fmaxf(tm, __shfl_xor(tm, 4, 16));
            tm = fmaxf(tm, __shfl_xor(tm, 8, 16));
            float mn = fmaxf(m_run[r], tm);
            int prow = l16 * 4 + r;
            int pswzr = prow << 4;
            float ls = 0.f;
            #pragma unroll
            for (int c = 0; c < 8; ++c) {
                float pv = __expf(0.125f * (sc[c] - mn));
                int pbyte = prow * 256 + (((c * 16 + l15) * 2) ^ pswzr);
                *(__hip_bfloat16*)(Pw + pbyte) = __float2bfloat16(pv);
                ls += pv;
            }
            ls += __shfl_xor(ls, 1, 16);
            ls += __shfl_xor(ls, 2, 16);
            ls += __shfl_xor(ls, 4, 16);
            ls += __shfl_xor(ls, 8, 16);
            float alpha = __expf(0.125f * (m_run[r] - mn));
            l_run[r] = l_run[r] * alpha + ls;
            m_run[r] = mn;
            acc_o[0][r] *= alpha; acc_o[1][r] *= alpha;
            acc_o[2][r] *= alpha; acc_o[3][r] *= alpha;
        }

        // O += P @ V : A=P [q][s], B^T = V^T [hs][s]
        const char* Pb = Pw + l15 * 256;
        bf16x8 pa[4];
        #pragma unroll
        for (int t = 0; t < 4; ++t)
            pa[t] = *(const bf16x8*)(Pb + ((t * 64 + l16 * 16) ^ pswz));
        __builtin_amdgcn_s_setprio(1);
        #pragma unroll
        for (int ni = 0; ni < 4; ++ni) {
            int row = ni * 16 + l15;
            const char* vb_ = (const char*)Vs + row * 256;
            int swz = (row & 15) << 4;
            #pragma unroll
            for (int t = 0; t < 4; ++t) {
                bf16x8 vf = *(const bf16x8*)(vb_ + ((t * 64 + l16 * 16) ^ swz));
                acc_o[ni] = __builtin_amdgcn_mfma_f32_16x16x32_bf16(pa[t], vf, acc_o[ni], 0, 0, 0);
            }
        }
        __builtin_amdgcn_s_setprio(0);
    }

    float inv[4];
    #pragma unroll
    for (int r = 0; r < 4; ++r) inv[r] = 1.0f / l_run[r];
    #pragma unroll
    for (int ni = 0; ni < 4; ++ni) {
        #pragma unroll
        for (int r = 0; r < 4; ++r) {
            size_t orow = ((size_t)(bI * T) + t0 + w * 16 + l16 * 4 + r) * D
                        + h * HS + ni * 16 + l15;
            att[orow] = __float2bfloat16(acc_o[ni][r] * inv[r]);
        }
    }
}

// ---------------------------------------------------------------------------
extern "C" void kernel_launch(void* const* d_in, const int* in_sizes, int n_in,
                              void* d_out, int out_size, void* d_ws, size_t ws_size,
                              hipStream_t stream) {
    const int*   idx     = (const int*)d_in[0];
    const float* tok_emb = (const float*)d_in[1];
    const float* pos_emb = (const float*)d_in[2];
    const float* Wq_u = (const float*)d_in[3],  *bq_u = (const float*)d_in[4];
    const float* Wk_u = (const float*)d_in[5],  *bk_u = (const float*)d_in[6];
    const float* Wv_u = (const float*)d_in[7],  *bv_u = (const float*)d_in[8];
    const float* Wp_u = (const float*)d_in[9],  *bp_u = (const float*)d_in[10];
    const float* Wq_m = (const float*)d_in[11], *bq_m = (const float*)d_in[12];
    const float* Wk_m = (const float*)d_in[13], *bk_m = (const float*)d_in[14];
    const float* Wv_m = (const float*)d_in[15], *bv_m = (const float*)d_in[16];
    const float* Wp_m = (const float*)d_in[17], *bp_m = (const float*)d_in[18];
    const float* W1   = (const float*)d_in[19], *b1   = (const float*)d_in[20];
    const float* W2   = (const float*)d_in[21], *b2   = (const float*)d_in[22];
    const float* lnf_g = (const float*)d_in[23], *lnf_b = (const float*)d_in[24];
    const float* n1_g  = (const float*)d_in[25], *n1_b  = (const float*)d_in[26];
    const float* n2_g  = (const float*)d_in[27], *n2_b  = (const float*)d_in[28];
    const float* nf_g  = (const float*)d_in[29], *nf_b  = (const float*)d_in[30];
    const float* Wfin  = (const float*)d_in[31], *bfin  = (const float*)d_in[32];
    float* out = (float*)d_out;

    char* p = (char*)d_ws;
    auto alloc = [&](size_t bytes) { char* r = p; p += (bytes + 255) & ~255ull; return r; };
    float* x    = (float*)alloc((size_t)M * D * 4);
    float* x2   = (float*)alloc((size_t)M * D * 4);
    float* w2p  = (float*)alloc((size_t)4 * M * D * 4);
    short* qbf  = (short*)alloc((size_t)M * D * 2);
    short* kbf  = (short*)alloc((size_t)M * D * 2);
    short* vbf  = (short*)alloc((size_t)M * D * 2);
    short* vtb  = (short*)alloc((size_t)M * D * 2);
    short* xnb  = (short*)alloc((size_t)M * D * 2);
    short* attb = (short*)alloc((size_t)M * D * 2);
    short* hb   = (short*)alloc((size_t)M * DFF * 2);
    short* WqkvT= (short*)alloc((size_t)3 * 1024 * 1024 * 2);
    short* WpT  = (short*)alloc((size_t)1024 * 1024 * 2);
    short* W1T  = (short*)alloc((size_t)D * DFF * 2);
    short* W2T  = (short*)alloc((size_t)DFF * D * 2);
    short* WfT  = (short*)alloc((size_t)D * V * 2);

    embed_kernel<<<M, 256, 0, stream>>>(idx, tok_emb, pos_emb, x);
    ln_bf16_w4_kernel<<<M / 4, 256, 0, stream>>>(x, n1_g, n1_b, (__hip_bfloat16*)xnb);
    transpose_bf16_kernel<<<dim3(V / 32, D / 32, 1), 256, 0, stream>>>(
        Wfin, (__hip_bfloat16*)WfT, D, V, 0, 0);

    for (int l = 0; l < LNUM; ++l) {
        const float *n1g = n1_g + l * D, *n1b = n1_b + l * D;
        const float *n2g = n2_g + l * D, *n2b = n2_b + l * D;
        const float *lfg = lnf_g + l * D, *lfb = lnf_b + l * D;
        const float *W1l = W1 + (size_t)l * D * DFF, *b1l = b1 + l * DFF;
        const float *W2l = W2 + (size_t)l * DFF * D, *b2l = b2 + l * D;
        transpose_bf16_kernel<<<dim3(DFF / 32, D / 32, 1), 256, 0, stream>>>(
            W1l, (__hip_bfloat16*)W1T, D, DFF, 0, 0);
        transpose_bf16_kernel<<<dim3(D / 32, DFF / 32, 1), 256, 0, stream>>>(
            W2l, (__hip_bfloat16*)W2T, DFF, D, 0, 0);
        for (int half = 0; half < 2; ++half) {
            const float *Wq_, *bq_, *Wk_, *bk_, *Wv_, *bv_, *Wp_, *bp_;
            if (half == 0) { Wq_ = Wq_u; bq_ = bq_u; Wk_ = Wk_u; bk_ = bk_u;
                             Wv_ = Wv_u; bv_ = bv_u; Wp_ = Wp_u; bp_ = bp_u; }
            else           { Wq_ = Wq_m; bq_ = bq_m; Wk_ = Wk_m; bk_ = bk_m;
                             Wv_ = Wv_m; bv_ = bv_m; Wp_ = Wp_m; bp_ = bp_m; }
            Wq_ += (size_t)l * H * D * HS;  bq_ += l * H * HS;
            Wk_ += (size_t)l * H * D * HS;  bk_ += l * H * HS;
            Wv_ += (size_t)l * H * D * HS;  bv_ += l * H * HS;
            Wp_ += (size_t)l * D * D;       bp_ += l * D;

            transpose_qkv_kernel<<<dim3(HS / 32, D / 32, 48), 256, 0, stream>>>(
                Wq_, Wk_, Wv_, WqkvT);
            transpose_bf16_kernel<<<dim3(D / 32, D / 32, 1), 256, 0, stream>>>(
                Wp_, (__hip_bfloat16*)WpT, D, D, 0, 0);

            // q,k,v = xn @ Wqkv -> bf16 [B,H,T,HS]
            mm_bf16_kernel<128, 3><<<dim3(M / 128, 3072 / 128), 256, 0, stream>>>(
                xnb, WqkvT, bq_, bk_, bv_, nullptr,
                (float*)qbf, (float*)kbf, (float*)vbf, nullptr, 3072, D, D);
            transpose_v_kernel<<<dim3(HS / 32, T / 32, BB * H), 256, 0, stream>>>(vbf, vtb);
            if (half == 0)
                attn_mfma_kernel<0><<<dim3(T / 64, BB * H), 256, 0, stream>>>(
                    qbf, kbf, vtb, (__hip_bfloat16*)attb);
            else
                attn_mfma_kernel<1><<<dim3(T / 64, BB * H), 256, 0, stream>>>(
                    qbf, kbf, vtb, (__hip_bfloat16*)attb);
            // x2 = x + att @ Wp + bp
            mm_bf16_kernel<64, 1><<<dim3(M / 64, D / 128), 256, 0, stream>>>(
                attb, WpT, bp_, nullptr, nullptr, x, x2, nullptr, nullptr, nullptr, D, D, D);
            // xn = ln(x2, n2) -> bf16
            ln_bf16_w4_kernel<<<M / 4, 256, 0, stream>>>(x2, n2g, n2b, (__hip_bfloat16*)xnb);
            // h = leaky(xn @ W1 + b1) -> bf16
            mm_bf16_kernel<128, 2><<<dim3(M / 128, DFF / 128), 256, 0, stream>>>(
                xnb, W1T, b1l, nullptr, nullptr, nullptr, nullptr, nullptr, nullptr,
                (__hip_bfloat16*)hb, DFF, D, D);
            // W2 split-K x4 -> partials
            mm_bf16_kernel<128, 4><<<dim3(M / 128, D / 128, 4), 256, 0, stream>>>(
                hb, W2T, nullptr, nullptr, nullptr, nullptr, w2p, nullptr, nullptr,
                nullptr, D, DFF / 4, DFF);
            const float* og = half ? n2g : n1g;
            const float* ob = half ? n2b : n1b;
            const float* gn; const float* bn;
            if (half == 0)      { gn = n1g; bn = n1b; }
            else if (l < LNUM-1){ gn = n1_g + (l+1)*D; bn = n1_b + (l+1)*D; }
            else                { gn = nf_g; bn = nf_b; }
            ffn_tail_kernel<4><<<M / 4, 256, 0, stream>>>(
                w2p, b2l, lfg, lfb, og, ob, x2, x, gn, bn, (__hip_bfloat16*)xnb);
        }
    }
    mm_bf16_kernel<128, 0><<<dim3(M / 128, V / 128), 256, 0, stream>>>(
        xnb, WfT, bfin, nullptr, nullptr, nullptr, out, nullptr, nullptr, nullptr, V, D, D);
}

// Round 6
// 1650.263 us; speedup vs baseline: 7.0751x; 1.0345x over previous
//
#include <hip/hip_runtime.h>
#include <hip/hip_bf16.h>
#include <math.h>

#define LNUM 4
#define H 16
#define D 1024
#define HS 64
#define DFF 5120
#define V 32000
#define BB 2
#define T 1024
#define M (BB*T)          // 2048 token rows
#define EPS 1e-5f

typedef __attribute__((ext_vector_type(8))) short bf16x8;
typedef __attribute__((ext_vector_type(4))) float f32x4;

// async global->LDS, 16B per lane (wave-uniform LDS base + lane*16)
__device__ __forceinline__ void gload16(const void* g, void* l) {
    __builtin_amdgcn_global_load_lds(
        (const __attribute__((address_space(1))) void*)g,
        (__attribute__((address_space(3))) void*)l, 16, 0, 0);
}

__device__ __forceinline__ float wred_sum(float v) {
    #pragma unroll
    for (int off = 32; off; off >>= 1) v += __shfl_xor(v, off, 64);
    return v;
}

// ---------------------------------------------------------------------------
// embed
// ---------------------------------------------------------------------------
__global__ __launch_bounds__(256) void embed_kernel(const int* __restrict__ idx,
        const float* __restrict__ tok, const float* __restrict__ pos,
        float* __restrict__ x) {
    int row = blockIdx.x;
    int t = row & (T - 1);
    int tok_id = idx[row];
    int c = threadIdx.x * 4;
    float4 a = *(const float4*)&tok[(size_t)tok_id * D + c];
    float4 p = *(const float4*)&pos[(size_t)t * D + c];
    a.x += p.x; a.y += p.y; a.z += p.z; a.w += p.w;
    *(float4*)&x[(size_t)row * D + c] = a;
}

// ---------------------------------------------------------------------------
// wave-per-row LN -> bf16 (4 rows per 256-thread block, no barriers)
// ---------------------------------------------------------------------------
__global__ __launch_bounds__(256) void ln_bf16_w4_kernel(const float* __restrict__ in,
        const float* __restrict__ g, const float* __restrict__ b,
        __hip_bfloat16* __restrict__ out) {
    int w = threadIdx.x >> 6, lane = threadIdx.x & 63;
    int row = blockIdx.x * 4 + w;
    const float* rp = in + (size_t)row * D;
    float4 xv[4];
    float s = 0.f;
    #pragma unroll
    for (int c = 0; c < 4; ++c) {
        xv[c] = *(const float4*)&rp[c * 256 + lane * 4];
        s += xv[c].x + xv[c].y + xv[c].z + xv[c].w;
    }
    float mu = wred_sum(s) * (1.0f / D);
    float vs = 0.f;
    #pragma unroll
    for (int c = 0; c < 4; ++c) {
        xv[c].x -= mu; xv[c].y -= mu; xv[c].z -= mu; xv[c].w -= mu;
        vs += xv[c].x*xv[c].x + xv[c].y*xv[c].y + xv[c].z*xv[c].z + xv[c].w*xv[c].w;
    }
    float rs = rsqrtf(wred_sum(vs) * (1.0f / D) + EPS);
    #pragma unroll
    for (int c = 0; c < 4; ++c) {
        int j = c * 256 + lane * 4;
        float4 gv = *(const float4*)&g[j];
        float4 bv = *(const float4*)&b[j];
        union { ushort4 u4; __hip_bfloat16 h[4]; } pk;
        pk.h[0] = __float2bfloat16(xv[c].x * rs * gv.x + bv.x);
        pk.h[1] = __float2bfloat16(xv[c].y * rs * gv.y + bv.y);
        pk.h[2] = __float2bfloat16(xv[c].z * rs * gv.z + bv.z);
        pk.h[3] = __float2bfloat16(xv[c].w * rs * gv.w + bv.w);
        *(ushort4*)&out[(size_t)row * D + j] = pk.u4;
    }
}

// ---------------------------------------------------------------------------
// FFN tail, fused:  f = sum(partials)+b2 ; x = res + ln(ln(f,g1,b1),g2,b2g)
// then xn = ln(x, gn, bn) -> bf16
// ---------------------------------------------------------------------------
template<int NP>
__global__ __launch_bounds__(256) void ffn_tail_kernel(
        const float* __restrict__ part, const float* __restrict__ b2,
        const float* __restrict__ g1, const float* __restrict__ b1,
        const float* __restrict__ g2, const float* __restrict__ b2g,
        const float* __restrict__ res, float* __restrict__ xout,
        const float* __restrict__ gn, const float* __restrict__ bn,
        __hip_bfloat16* __restrict__ xnout) {
    const size_t MD = (size_t)M * D;
    int w = threadIdx.x >> 6, lane = threadIdx.x & 63;
    int row = blockIdx.x * 4 + w;
    size_t ro = (size_t)row * D;
    float4 f[4];
    float s = 0.f;
    #pragma unroll
    for (int c = 0; c < 4; ++c) {
        int j = c * 256 + lane * 4;
        float4 acc = *(const float4*)&b2[j];
        #pragma unroll
        for (int pI = 0; pI < NP; ++pI) {
            float4 pv = *(const float4*)&part[pI * MD + ro + j];
            acc.x += pv.x; acc.y += pv.y; acc.z += pv.z; acc.w += pv.w;
        }
        f[c] = acc;
        s += acc.x + acc.y + acc.z + acc.w;
    }
    float mu = wred_sum(s) * (1.0f / D);
    float vs = 0.f;
    #pragma unroll
    for (int c = 0; c < 4; ++c) {
        f[c].x -= mu; f[c].y -= mu; f[c].z -= mu; f[c].w -= mu;
        vs += f[c].x*f[c].x + f[c].y*f[c].y + f[c].z*f[c].z + f[c].w*f[c].w;
    }
    float rs = rsqrtf(wred_sum(vs) * (1.0f / D) + EPS);
    float s2 = 0.f;
    #pragma unroll
    for (int c = 0; c < 4; ++c) {
        int j = c * 256 + lane * 4;
        float4 gv = *(const float4*)&g1[j];
        float4 bv = *(const float4*)&b1[j];
        f[c].x = f[c].x * rs * gv.x + bv.x;
        f[c].y = f[c].y * rs * gv.y + bv.y;
        f[c].z = f[c].z * rs * gv.z + bv.z;
        f[c].w = f[c].w * rs * gv.w + bv.w;
        s2 += f[c].x + f[c].y + f[c].z + f[c].w;
    }
    float mu2 = wred_sum(s2) * (1.0f / D);
    float vs2 = 0.f;
    #pragma unroll
    for (int c = 0; c < 4; ++c) {
        f[c].x -= mu2; f[c].y -= mu2; f[c].z -= mu2; f[c].w -= mu2;
        vs2 += f[c].x*f[c].x + f[c].y*f[c].y + f[c].z*f[c].z + f[c].w*f[c].w;
    }
    float rs2 = rsqrtf(wred_sum(vs2) * (1.0f / D) + EPS);
    float s3 = 0.f;
    #pragma unroll
    for (int c = 0; c < 4; ++c) {
        int j = c * 256 + lane * 4;
        float4 gv = *(const float4*)&g2[j];
        float4 bv = *(const float4*)&b2g[j];
        float4 rv = *(const float4*)&res[ro + j];
        f[c].x = rv.x + f[c].x * rs2 * gv.x + bv.x;
        f[c].y = rv.y + f[c].y * rs2 * gv.y + bv.y;
        f[c].z = rv.z + f[c].z * rs2 * gv.z + bv.z;
        f[c].w = rv.w + f[c].w * rs2 * gv.w + bv.w;
        *(float4*)&xout[ro + j] = f[c];
        s3 += f[c].x + f[c].y + f[c].z + f[c].w;
    }
    float mu3 = wred_sum(s3) * (1.0f / D);
    float vs3 = 0.f;
    #pragma unroll
    for (int c = 0; c < 4; ++c) {
        f[c].x -= mu3; f[c].y -= mu3; f[c].z -= mu3; f[c].w -= mu3;
        vs3 += f[c].x*f[c].x + f[c].y*f[c].y + f[c].z*f[c].z + f[c].w*f[c].w;
    }
    float rs3 = rsqrtf(wred_sum(vs3) * (1.0f / D) + EPS);
    #pragma unroll
    for (int c = 0; c < 4; ++c) {
        int j = c * 256 + lane * 4;
        float4 gv = *(const float4*)&gn[j];
        float4 bv = *(const float4*)&bn[j];
        union { ushort4 u4; __hip_bfloat16 h[4]; } pk;
        pk.h[0] = __float2bfloat16(f[c].x * rs3 * gv.x + bv.x);
        pk.h[1] = __float2bfloat16(f[c].y * rs3 * gv.y + bv.y);
        pk.h[2] = __float2bfloat16(f[c].z * rs3 * gv.z + bv.z);
        pk.h[3] = __float2bfloat16(f[c].w * rs3 * gv.w + bv.w);
        *(ushort4*)&xnout[ro + j] = pk.u4;
    }
}

// ---------------------------------------------------------------------------
// tiled transpose + fp32->bf16: in [R][C] f32 -> out [C][R] bf16
// ---------------------------------------------------------------------------
__global__ __launch_bounds__(256) void transpose_bf16_kernel(
        const float* __restrict__ in, __hip_bfloat16* __restrict__ out,
        int R, int C, size_t zin, size_t zout) {
    __shared__ float t[32][33];
    in += (size_t)blockIdx.z * zin; out += (size_t)blockIdx.z * zout;
    int tx = threadIdx.x & 31, ty = threadIdx.x >> 5;
    int c0 = blockIdx.x * 32, r0 = blockIdx.y * 32;
    #pragma unroll
    for (int i = 0; i < 4; ++i)
        t[ty + i * 8][tx] = in[(size_t)(r0 + ty + i * 8) * C + c0 + tx];
    __syncthreads();
    #pragma unroll
    for (int i = 0; i < 4; ++i)
        out[(size_t)(c0 + ty + i * 8) * R + r0 + tx] = __float2bfloat16(t[tx][ty + i * 8]);
}

// ---------------------------------------------------------------------------
// q/k/v weight transpose in ONE launch
// ---------------------------------------------------------------------------
__global__ __launch_bounds__(256) void transpose_qkv_kernel(
        const float* __restrict__ Wq, const float* __restrict__ Wk,
        const float* __restrict__ Wv, short* __restrict__ outT) {
    __shared__ float t[32][33];
    int z = blockIdx.z;
    int which = z >> 4, h = z & 15;
    const float* in = (which == 0 ? Wq : which == 1 ? Wk : Wv) + (size_t)h * D * HS;
    __hip_bfloat16* out = (__hip_bfloat16*)outT + ((size_t)which * H + h) * HS * D;
    int tx = threadIdx.x & 31, ty = threadIdx.x >> 5;
    int c0 = blockIdx.x * 32, r0 = blockIdx.y * 32;
    #pragma unroll
    for (int i = 0; i < 4; ++i)
        t[ty + i * 8][tx] = in[(size_t)(r0 + ty + i * 8) * HS + c0 + tx];
    __syncthreads();
    #pragma unroll
    for (int i = 0; i < 4; ++i)
        out[(size_t)(c0 + ty + i * 8) * D + r0 + tx] = __float2bfloat16(t[tx][ty + i * 8]);
}

// ---------------------------------------------------------------------------
// bf16->bf16 transpose for V: in [T][HS] per bh -> out [HS][T]
// ---------------------------------------------------------------------------
__global__ __launch_bounds__(256) void transpose_v_kernel(const short* __restrict__ in,
        short* __restrict__ out) {
    __shared__ short t[32][33];
    int z = blockIdx.z;
    in  += (size_t)z * T * HS;
    out += (size_t)z * HS * T;
    int tx = threadIdx.x & 31, ty = threadIdx.x >> 5;
    int c0 = blockIdx.x * 32, r0 = blockIdx.y * 32;
    #pragma unroll
    for (int i = 0; i < 4; ++i)
        t[ty + i * 8][tx] = in[(size_t)(r0 + ty + i * 8) * HS + c0 + tx];
    __syncthreads();
    #pragma unroll
    for (int i = 0; i < 4; ++i)
        out[(size_t)(c0 + ty + i * 8) * T + r0 + tx] = t[tx][ty + i * 8];
}

// ---------------------------------------------------------------------------
// bf16 MFMA GEMM, counted-vmcnt double-buffered pipeline.
// C = epi(A[M,Kl] @ BT[N,Kl]^T + bias).  BK=64, BN=128, 256 thr = 4 waves 2x2.
// LDS rows are 128B with per-row XOR swizzle (col ^ (row&7)<<4): applied to
// the pre-swizzled GLOBAL source (linear LDS dest, global_load_lds) and to
// the fragment ds_reads -> conflict-free b128 reads.
// Main loop: s_waitcnt vmcnt(NL) (2 tiles in flight, never drain) +
// raw s_barrier pairs + setprio around the MFMA cluster.
// EPI: 0 f32 C0 ; 1 +res f32 C0 ; 2 leaky bf16 Cbf ; 3 qkv scatter bf16 ;
//      4 raw partial f32 -> C0 + z*M*N
// ---------------------------------------------------------------------------
template<int BM, int EPI>
__global__ __launch_bounds__(256) void mm_bf16_kernel(
        const short* __restrict__ A, const short* __restrict__ BT,
        const float* __restrict__ bias0, const float* __restrict__ bias1,
        const float* __restrict__ bias2, const float* __restrict__ res,
        float* __restrict__ C0, float* __restrict__ C1, float* __restrict__ C2,
        __hip_bfloat16* __restrict__ Cbf, int N, int Kloop, int lda) {
    constexpr int BK = 64, BN = 128;
    constexpr int MI = BM / 32;
    __shared__ __align__(16) char As[2][BM * 128];
    __shared__ __align__(16) char Bs[2][BN * 128];
    int nwg = gridDim.x * gridDim.y;
    int bid = blockIdx.y * gridDim.x + blockIdx.x;
    int bx = blockIdx.x, by = blockIdx.y;
    if (!(nwg & 7)) {                       // bijective XCD swizzle
        int s = (bid & 7) * (nwg >> 3) + (bid >> 3);
        bx = s % gridDim.x; by = s / gridDim.x;
    }
    int tid = threadIdx.x;
    int lane = tid & 63, wid = tid >> 6;
    int wr = wid >> 1, wc = wid & 1;
    int l15 = lane & 15, l16 = lane >> 4;
    int m0 = bx * BM, n0 = by * BN;         // M-major tiles
    f32x4 acc[MI][4] = {};

    const size_t lda2 = (size_t)lda * 2;
    const char* Agc = (const char*)A + (size_t)m0 * lda2 + (size_t)blockIdx.z * Kloop * 2;
    const char* Bgc = (const char*)BT + (size_t)n0 * lda2 + (size_t)blockIdx.z * Kloop * 2;

    auto stage = [&](int buf, int kbyte) {
        #pragma unroll
        for (int i = 0; i < BM / 32; ++i) {
            int o = i * 4096 + tid * 16;
            int row = o >> 7, col = o & 127;
            gload16(Agc + (size_t)row * lda2 + kbyte + (col ^ ((row & 7) << 4)),
                    As[buf] + o);
        }
        #pragma unroll
        for (int i = 0; i < 4; ++i) {
            int o = i * 4096 + tid * 16;
            int row = o >> 7, col = o & 127;
            gload16(Bgc + (size_t)row * lda2 + kbyte + (col ^ ((row & 7) << 4)),
                    Bs[buf] + o);
        }
    };
    auto compute = [&](int buf) {
        #pragma unroll
        for (int kk = 0; kk < 2; ++kk) {
            bf16x8 af[MI], bfr[4];
            #pragma unroll
            for (int mi = 0; mi < MI; ++mi) {
                int row = wr * (BM / 2) + mi * 16 + l15;
                af[mi] = *(const bf16x8*)(As[buf] + row * 128 +
                          ((kk * 64 + l16 * 16) ^ ((row & 7) << 4)));
            }
            #pragma unroll
            for (int ni = 0; ni < 4; ++ni) {
                int row = wc * 64 + ni * 16 + l15;
                bfr[ni] = *(const bf16x8*)(Bs[buf] + row * 128 +
                          ((kk * 64 + l16 * 16) ^ ((row & 7) << 4)));
            }
            __builtin_amdgcn_s_setprio(1);
            #pragma unroll
            for (int mi = 0; mi < MI; ++mi)
                #pragma unroll
                for (int ni = 0; ni < 4; ++ni)
                    acc[mi][ni] = __builtin_amdgcn_mfma_f32_16x16x32_bf16(
                        af[mi], bfr[ni], acc[mi][ni], 0, 0, 0);
            __builtin_amdgcn_s_setprio(0);
        }
    };

    const int NT = Kloop / BK;
    stage(0, 0);
    stage(1, 128);
    for (int t = 0; t < NT; ++t) {
        if (t < NT - 1) {
            if constexpr (BM == 128) asm volatile("s_waitcnt vmcnt(8)" ::: "memory");
            else                     asm volatile("s_waitcnt vmcnt(6)" ::: "memory");
        } else {
            asm volatile("s_waitcnt vmcnt(0)" ::: "memory");
        }
        __builtin_amdgcn_sched_barrier(0);
        __builtin_amdgcn_s_barrier();        // tile t ready for all waves
        __builtin_amdgcn_sched_barrier(0);
        compute(t & 1);
        __builtin_amdgcn_s_barrier();        // all waves done reading buf
        __builtin_amdgcn_sched_barrier(0);
        if (t + 2 < NT) stage(t & 1, (t + 2) * 128);
    }

    int rbase = m0 + wr * (BM / 2) + l16 * 4;
    int cbase = n0 + wc * 64 + l15;
    size_t zoff = (EPI == 4) ? (size_t)blockIdx.z * M * N : 0;
    #pragma unroll
    for (int mi = 0; mi < MI; ++mi) {
        #pragma unroll
        for (int ni = 0; ni < 4; ++ni) {
            int col = cbase + ni * 16;
            float bv = 0.f;
            if (EPI == 3) {
                int z = col >> 10, nn = col & 1023;
                bv = (z == 0 ? bias0 : z == 1 ? bias1 : bias2)[nn];
            } else if (EPI != 4) bv = bias0[col];
            #pragma unroll
            for (int r = 0; r < 4; ++r) {
                int row = rbase + mi * 16 + r;
                float v = acc[mi][ni][r] + bv;
                if (EPI == 0) {
                    C0[(size_t)row * N + col] = v;
                } else if (EPI == 1) {
                    C0[(size_t)row * N + col] = v + res[(size_t)row * N + col];
                } else if (EPI == 2) {
                    v = v > 0.f ? v : 0.01f * v;
                    Cbf[(size_t)row * N + col] = __float2bfloat16(v);
                } else if (EPI == 4) {
                    C0[zoff + (size_t)row * N + col] = v;
                } else {
                    int z = col >> 10;
                    int hh = (col >> 6) & 15, e = col & 63;
                    int b = row >> 10, t = row & (T - 1);
                    __hip_bfloat16* dst = (__hip_bfloat16*)(z == 0 ? C0 : (z == 1 ? C1 : C2));
                    dst[(((size_t)(b * H + hh)) * T + t) * HS + e] = __float2bfloat16(v);
                }
            }
        }
    }
}

// ---------------------------------------------------------------------------
// MFMA flash attention, bf16, KVBLK=128. grid (T/64, B*H), 4 waves.
// ---------------------------------------------------------------------------
template<int CAUSAL>
__global__ __launch_bounds__(256) void attn_mfma_kernel(
        const short* __restrict__ q, const short* __restrict__ k,
        const short* __restrict__ vt, __hip_bfloat16* __restrict__ att) {
    __shared__ __align__(16) short Ks[128 * 64];     // [s][hs]
    __shared__ __align__(16) short Vs[64 * 128];     // [hs][s]
    __shared__ __align__(16) short Ps[4][16 * 128];  // [w][q][s]
    int bh = blockIdx.y;
    int bI = bh >> 4, h = bh & 15;
    int tix = blockIdx.x;
    if (CAUSAL) tix = (tix & 1) ? (15 - (tix >> 1)) : (tix >> 1);
    int t0 = tix * 64;
    int tid = threadIdx.x;
    int lane = tid & 63, w = tid >> 6;
    int l15 = lane & 15, l16 = lane >> 4;

    const short* Qg = q + ((size_t)bh * T + t0 + w * 16 + l15) * HS + l16 * 8;
    bf16x8 qf0 = *(const bf16x8*)Qg;
    bf16x8 qf1 = *(const bf16x8*)(Qg + 32);

    const char* Kg = (const char*)(k + (size_t)bh * T * HS);   // row stride 128B
    const char* Vg = (const char*)(vt + (size_t)bh * HS * T);  // row stride 2048B

    float m_run[4] = {-1e30f, -1e30f, -1e30f, -1e30f};
    float l_run[4] = {0.f, 0.f, 0.f, 0.f};
    f32x4 acc_o[4] = {};
    char* Pw = (char*)Ps[w];
    int pswz = l15 << 4;

    int n_tiles = CAUSAL ? (t0 / 128 + 1) : (T / 128);
    for (int it = 0; it < n_tiles; ++it) {
        int s0 = it * 128;
        __syncthreads();
        #pragma unroll
        for (int i = 0; i < 4; ++i) {      // K tile: 16 KB
            int o = i * 4096 + tid * 16;
            int row = o >> 7, bir = o & 127;
            gload16(Kg + (size_t)(s0 + row) * 128 + (bir ^ ((row & 7) << 4)),
                    (char*)Ks + o);
        }
        #pragma unroll
        for (int i = 0; i < 4; ++i) {      // V^T tile: 16 KB
            int o = i * 4096 + tid * 16;
            int row = o >> 8, bb = o & 255;
            gload16(Vg + (size_t)row * 2048 + s0 * 2 + (bb ^ ((row & 15) << 4)),
                    (char*)Vs + o);
        }
        __syncthreads();

        f32x4 acc_s[8] = {};
        __builtin_amdgcn_s_setprio(1);
        #pragma unroll
        for (int c = 0; c < 8; ++c) {
            int row = c * 16 + l15;
            const char* kb_ = (const char*)Ks + row * 128;
            int swz = (row & 7) << 4;
            bf16x8 kf0 = *(const bf16x8*)(kb_ + ((l16 * 16) ^ swz));
            bf16x8 kf1 = *(const bf16x8*)(kb_ + ((64 + l16 * 16) ^ swz));
            acc_s[c] = __builtin_amdgcn_mfma_f32_16x16x32_bf16(qf0, kf0, acc_s[c], 0, 0, 0);
            acc_s[c] = __builtin_amdgcn_mfma_f32_16x16x32_bf16(qf1, kf1, acc_s[c], 0, 0, 0);
        }
        __builtin_amdgcn_s_setprio(0);

        bool domask = CAUSAL && (it == n_tiles - 1);
        #pragma unroll
        for (int r = 0; r < 4; ++r) {
            float sc[8];
            #pragma unroll
            for (int c = 0; c < 8; ++c) {
                float s = acc_s[c][r];
                if (domask && (s0 + c * 16 + l15) > (t0 + w * 16 + l16 * 4 + r)) s = -1e30f;
                sc[c] = s;
            }
            float tm = fmaxf(fmaxf(fmaxf(sc[0], sc[1]), fmaxf(sc[2], sc[3])),
                             fmaxf(fmaxf(sc[4], sc[5]), fmaxf(sc[6], sc[7])));
            tm = fmaxf(tm, __shfl_xor(tm, 1, 16));
            tm = fmaxf(tm, __shfl_xor(tm, 2, 16));
            tm = fmaxf(tm, __shfl_xor(tm, 4, 16));
            tm = fmaxf(tm, __shfl_xor(tm, 8, 16));
            float mn = fmaxf(m_run[r], tm);
            int prow = l16 * 4 + r;
            int pswzr = prow << 4;
            float ls = 0.f;
            #pragma unroll
            for (int c = 0; c < 8; ++c) {
                float pv = __expf(0.125f * (sc[c] - mn));
                int pbyte = prow * 256 + (((c * 16 + l15) * 2) ^ pswzr);
                *(__hip_bfloat16*)(Pw + pbyte) = __float2bfloat16(pv);
                ls += pv;
            }
            ls += __shfl_xor(ls, 1, 16);
            ls += __shfl_xor(ls, 2, 16);
            ls += __shfl_xor(ls, 4, 16);
            ls += __shfl_xor(ls, 8, 16);
            float alpha = __expf(0.125f * (m_run[r] - mn));
            l_run[r] = l_run[r] * alpha + ls;
            m_run[r] = mn;
            acc_o[0][r] *= alpha; acc_o[1][r] *= alpha;
            acc_o[2][r] *= alpha; acc_o[3][r] *= alpha;
        }

        const char* Pb = Pw + l15 * 256;
        bf16x8 pa[4];
        #pragma unroll
        for (int t = 0; t < 4; ++t)
            pa[t] = *(const bf16x8*)(Pb + ((t * 64 + l16 * 16) ^ pswz));
        __builtin_amdgcn_s_setprio(1);
        #pragma unroll
        for (int ni = 0; ni < 4; ++ni) {
            int row = ni * 16 + l15;
            const char* vb_ = (const char*)Vs + row * 256;
            int swz = (row & 15) << 4;
            #pragma unroll
            for (int t = 0; t < 4; ++t) {
                bf16x8 vf = *(const bf16x8*)(vb_ + ((t * 64 + l16 * 16) ^ swz));
                acc_o[ni] = __builtin_amdgcn_mfma_f32_16x16x32_bf16(pa[t], vf, acc_o[ni], 0, 0, 0);
            }
        }
        __builtin_amdgcn_s_setprio(0);
    }

    float inv[4];
    #pragma unroll
    for (int r = 0; r < 4; ++r) inv[r] = 1.0f / l_run[r];
    #pragma unroll
    for (int ni = 0; ni < 4; ++ni) {
        #pragma unroll
        for (int r = 0; r < 4; ++r) {
            size_t orow = ((size_t)(bI * T) + t0 + w * 16 + l16 * 4 + r) * D
                        + h * HS + ni * 16 + l15;
            att[orow] = __float2bfloat16(acc_o[ni][r] * inv[r]);
        }
    }
}

// ---------------------------------------------------------------------------
extern "C" void kernel_launch(void* const* d_in, const int* in_sizes, int n_in,
                              void* d_out, int out_size, void* d_ws, size_t ws_size,
                              hipStream_t stream) {
    const int*   idx     = (const int*)d_in[0];
    const float* tok_emb = (const float*)d_in[1];
    const float* pos_emb = (const float*)d_in[2];
    const float* Wq_u = (const float*)d_in[3],  *bq_u = (const float*)d_in[4];
    const float* Wk_u = (const float*)d_in[5],  *bk_u = (const float*)d_in[6];
    const float* Wv_u = (const float*)d_in[7],  *bv_u = (const float*)d_in[8];
    const float* Wp_u = (const float*)d_in[9],  *bp_u = (const float*)d_in[10];
    const float* Wq_m = (const float*)d_in[11], *bq_m = (const float*)d_in[12];
    const float* Wk_m = (const float*)d_in[13], *bk_m = (const float*)d_in[14];
    const float* Wv_m = (const float*)d_in[15], *bv_m = (const float*)d_in[16];
    const float* Wp_m = (const float*)d_in[17], *bp_m = (const float*)d_in[18];
    const float* W1   = (const float*)d_in[19], *b1   = (const float*)d_in[20];
    const float* W2   = (const float*)d_in[21], *b2   = (const float*)d_in[22];
    const float* lnf_g = (const float*)d_in[23], *lnf_b = (const float*)d_in[24];
    const float* n1_g  = (const float*)d_in[25], *n1_b  = (const float*)d_in[26];
    const float* n2_g  = (const float*)d_in[27], *n2_b  = (const float*)d_in[28];
    const float* nf_g  = (const float*)d_in[29], *nf_b  = (const float*)d_in[30];
    const float* Wfin  = (const float*)d_in[31], *bfin  = (const float*)d_in[32];
    float* out = (float*)d_out;

    char* p = (char*)d_ws;
    auto alloc = [&](size_t bytes) { char* r = p; p += (bytes + 255) & ~255ull; return r; };
    float* x    = (float*)alloc((size_t)M * D * 4);
    float* x2   = (float*)alloc((size_t)M * D * 4);
    float* w2p  = (float*)alloc((size_t)4 * M * D * 4);
    short* qbf  = (short*)alloc((size_t)M * D * 2);
    short* kbf  = (short*)alloc((size_t)M * D * 2);
    short* vbf  = (short*)alloc((size_t)M * D * 2);
    short* vtb  = (short*)alloc((size_t)M * D * 2);
    short* xnb  = (short*)alloc((size_t)M * D * 2);
    short* attb = (short*)alloc((size_t)M * D * 2);
    short* hb   = (short*)alloc((size_t)M * DFF * 2);
    short* WqkvT= (short*)alloc((size_t)3 * 1024 * 1024 * 2);
    short* WpT  = (short*)alloc((size_t)1024 * 1024 * 2);
    short* W1T  = (short*)alloc((size_t)D * DFF * 2);
    short* W2T  = (short*)alloc((size_t)DFF * D * 2);
    short* WfT  = (short*)alloc((size_t)D * V * 2);

    embed_kernel<<<M, 256, 0, stream>>>(idx, tok_emb, pos_emb, x);
    ln_bf16_w4_kernel<<<M / 4, 256, 0, stream>>>(x, n1_g, n1_b, (__hip_bfloat16*)xnb);
    transpose_bf16_kernel<<<dim3(V / 32, D / 32, 1), 256, 0, stream>>>(
        Wfin, (__hip_bfloat16*)WfT, D, V, 0, 0);

    for (int l = 0; l < LNUM; ++l) {
        const float *n1g = n1_g + l * D, *n1b = n1_b + l * D;
        const float *n2g = n2_g + l * D, *n2b = n2_b + l * D;
        const float *lfg = lnf_g + l * D, *lfb = lnf_b + l * D;
        const float *W1l = W1 + (size_t)l * D * DFF, *b1l = b1 + l * DFF;
        const float *W2l = W2 + (size_t)l * DFF * D, *b2l = b2 + l * D;
        transpose_bf16_kernel<<<dim3(DFF / 32, D / 32, 1), 256, 0, stream>>>(
            W1l, (__hip_bfloat16*)W1T, D, DFF, 0, 0);
        transpose_bf16_kernel<<<dim3(D / 32, DFF / 32, 1), 256, 0, stream>>>(
            W2l, (__hip_bfloat16*)W2T, DFF, D, 0, 0);
        for (int half = 0; half < 2; ++half) {
            const float *Wq_, *bq_, *Wk_, *bk_, *Wv_, *bv_, *Wp_, *bp_;
            if (half == 0) { Wq_ = Wq_u; bq_ = bq_u; Wk_ = Wk_u; bk_ = bk_u;
                             Wv_ = Wv_u; bv_ = bv_u; Wp_ = Wp_u; bp_ = bp_u; }
            else           { Wq_ = Wq_m; bq_ = bq_m; Wk_ = Wk_m; bk_ = bk_m;
                             Wv_ = Wv_m; bv_ = bv_m; Wp_ = Wp_m; bp_ = bp_m; }
            Wq_ += (size_t)l * H * D * HS;  bq_ += l * H * HS;
            Wk_ += (size_t)l * H * D * HS;  bk_ += l * H * HS;
            Wv_ += (size_t)l * H * D * HS;  bv_ += l * H * HS;
            Wp_ += (size_t)l * D * D;       bp_ += l * D;

            transpose_qkv_kernel<<<dim3(HS / 32, D / 32, 48), 256, 0, stream>>>(
                Wq_, Wk_, Wv_, WqkvT);
            transpose_bf16_kernel<<<dim3(D / 32, D / 32, 1), 256, 0, stream>>>(
                Wp_, (__hip_bfloat16*)WpT, D, D, 0, 0);

            // q,k,v = xn @ Wqkv -> bf16 [B,H,T,HS]
            mm_bf16_kernel<128, 3><<<dim3(M / 128, 3072 / 128), 256, 0, stream>>>(
                xnb, WqkvT, bq_, bk_, bv_, nullptr,
                (float*)qbf, (float*)kbf, (float*)vbf, nullptr, 3072, D, D);
            transpose_v_kernel<<<dim3(HS / 32, T / 32, BB * H), 256, 0, stream>>>(vbf, vtb);
            if (half == 0)
                attn_mfma_kernel<0><<<dim3(T / 64, BB * H), 256, 0, stream>>>(
                    qbf, kbf, vtb, (__hip_bfloat16*)attb);
            else
                attn_mfma_kernel<1><<<dim3(T / 64, BB * H), 256, 0, stream>>>(
                    qbf, kbf, vtb, (__hip_bfloat16*)attb);
            // x2 = x + att @ Wp + bp
            mm_bf16_kernel<64, 1><<<dim3(M / 64, D / 128), 256, 0, stream>>>(
                attb, WpT, bp_, nullptr, nullptr, x, x2, nullptr, nullptr, nullptr, D, D, D);
            // xn = ln(x2, n2) -> bf16
            ln_bf16_w4_kernel<<<M / 4, 256, 0, stream>>>(x2, n2g, n2b, (__hip_bfloat16*)xnb);
            // h = leaky(xn @ W1 + b1) -> bf16
            mm_bf16_kernel<128, 2><<<dim3(M / 128, DFF / 128), 256, 0, stream>>>(
                xnb, W1T, b1l, nullptr, nullptr, nullptr, nullptr, nullptr, nullptr,
                (__hip_bfloat16*)hb, DFF, D, D);
            // W2 split-K x4 -> partials
            mm_bf16_kernel<128, 4><<<dim3(M / 128, D / 128, 4), 256, 0, stream>>>(
                hb, W2T, nullptr, nullptr, nullptr, nullptr, w2p, nullptr, nullptr,
                nullptr, D, DFF / 4, DFF);
            const float* og = half ? n2g : n1g;
            const float* ob = half ? n2b : n1b;
            const float* gn; const float* bn;
            if (half == 0)      { gn = n1g; bn = n1b; }
            else if (l < LNUM-1){ gn = n1_g + (l+1)*D; bn = n1_b + (l+1)*D; }
            else                { gn = nf_g; bn = nf_b; }
            ffn_tail_kernel<4><<<M / 4, 256, 0, stream>>>(
                w2p, b2l, lfg, lfb, og, ob, x2, x, gn, bn, (__hip_bfloat16*)xnb);
        }
    }
    mm_bf16_kernel<128, 0><<<dim3(M / 128, V / 128), 256, 0, stream>>>(
        xnb, WfT, bfin, nullptr, nullptr, nullptr, out, nullptr, nullptr, nullptr, V, D, D);
}

// Round 8
// 1588.506 us; speedup vs baseline: 7.3501x; 1.0389x over previous
//
#include <hip/hip_runtime.h>
#include <hip/hip_bf16.h>
#include <math.h>

#define LNUM 4
#define H 16
#define D 1024
#define HS 64
#define DFF 5120
#define V 32000
#define BB 2
#define T 1024
#define M (BB*T)          // 2048 token rows
#define EPS 1e-5f

typedef __attribute__((ext_vector_type(8))) short bf16x8;
typedef __attribute__((ext_vector_type(4))) float f32x4;

// async global->LDS, 16B per lane (wave-uniform LDS base + lane*16)
__device__ __forceinline__ void gload16(const void* g, void* l) {
    __builtin_amdgcn_global_load_lds(
        (const __attribute__((address_space(1))) void*)g,
        (__attribute__((address_space(3))) void*)l, 16, 0, 0);
}

__device__ __forceinline__ float wred_sum(float v) {
    #pragma unroll
    for (int off = 32; off; off >>= 1) v += __shfl_xor(v, off, 64);
    return v;
}

// ---------------------------------------------------------------------------
// embed
// ---------------------------------------------------------------------------
__global__ __launch_bounds__(256) void embed_kernel(const int* __restrict__ idx,
        const float* __restrict__ tok, const float* __restrict__ pos,
        float* __restrict__ x) {
    int row = blockIdx.x;
    int t = row & (T - 1);
    int tok_id = idx[row];
    int c = threadIdx.x * 4;
    float4 a = *(const float4*)&tok[(size_t)tok_id * D + c];
    float4 p = *(const float4*)&pos[(size_t)t * D + c];
    a.x += p.x; a.y += p.y; a.z += p.z; a.w += p.w;
    *(float4*)&x[(size_t)row * D + c] = a;
}

// ---------------------------------------------------------------------------
// wave-per-row LN -> bf16 (4 rows per 256-thread block, no barriers)
// ---------------------------------------------------------------------------
__global__ __launch_bounds__(256) void ln_bf16_w4_kernel(const float* __restrict__ in,
        const float* __restrict__ g, const float* __restrict__ b,
        __hip_bfloat16* __restrict__ out) {
    int w = threadIdx.x >> 6, lane = threadIdx.x & 63;
    int row = blockIdx.x * 4 + w;
    const float* rp = in + (size_t)row * D;
    float4 xv[4];
    float s = 0.f;
    #pragma unroll
    for (int c = 0; c < 4; ++c) {
        xv[c] = *(const float4*)&rp[c * 256 + lane * 4];
        s += xv[c].x + xv[c].y + xv[c].z + xv[c].w;
    }
    float mu = wred_sum(s) * (1.0f / D);
    float vs = 0.f;
    #pragma unroll
    for (int c = 0; c < 4; ++c) {
        xv[c].x -= mu; xv[c].y -= mu; xv[c].z -= mu; xv[c].w -= mu;
        vs += xv[c].x*xv[c].x + xv[c].y*xv[c].y + xv[c].z*xv[c].z + xv[c].w*xv[c].w;
    }
    float rs = rsqrtf(wred_sum(vs) * (1.0f / D) + EPS);
    #pragma unroll
    for (int c = 0; c < 4; ++c) {
        int j = c * 256 + lane * 4;
        float4 gv = *(const float4*)&g[j];
        float4 bv = *(const float4*)&b[j];
        union { ushort4 u4; __hip_bfloat16 h[4]; } pk;
        pk.h[0] = __float2bfloat16(xv[c].x * rs * gv.x + bv.x);
        pk.h[1] = __float2bfloat16(xv[c].y * rs * gv.y + bv.y);
        pk.h[2] = __float2bfloat16(xv[c].z * rs * gv.z + bv.z);
        pk.h[3] = __float2bfloat16(xv[c].w * rs * gv.w + bv.w);
        *(ushort4*)&out[(size_t)row * D + j] = pk.u4;
    }
}

// ---------------------------------------------------------------------------
// FFN tail, fused:  f = sum(partials)+b2 ; x = res + ln(ln(f,g1,b1),g2,b2g)
// then xn = ln(x, gn, bn) -> bf16
// ---------------------------------------------------------------------------
template<int NP>
__global__ __launch_bounds__(256) void ffn_tail_kernel(
        const float* __restrict__ part, const float* __restrict__ b2,
        const float* __restrict__ g1, const float* __restrict__ b1,
        const float* __restrict__ g2, const float* __restrict__ b2g,
        const float* __restrict__ res, float* __restrict__ xout,
        const float* __restrict__ gn, const float* __restrict__ bn,
        __hip_bfloat16* __restrict__ xnout) {
    const size_t MD = (size_t)M * D;
    int w = threadIdx.x >> 6, lane = threadIdx.x & 63;
    int row = blockIdx.x * 4 + w;
    size_t ro = (size_t)row * D;
    float4 f[4];
    float s = 0.f;
    #pragma unroll
    for (int c = 0; c < 4; ++c) {
        int j = c * 256 + lane * 4;
        float4 acc = *(const float4*)&b2[j];
        #pragma unroll
        for (int pI = 0; pI < NP; ++pI) {
            float4 pv = *(const float4*)&part[pI * MD + ro + j];
            acc.x += pv.x; acc.y += pv.y; acc.z += pv.z; acc.w += pv.w;
        }
        f[c] = acc;
        s += acc.x + acc.y + acc.z + acc.w;
    }
    float mu = wred_sum(s) * (1.0f / D);
    float vs = 0.f;
    #pragma unroll
    for (int c = 0; c < 4; ++c) {
        f[c].x -= mu; f[c].y -= mu; f[c].z -= mu; f[c].w -= mu;
        vs += f[c].x*f[c].x + f[c].y*f[c].y + f[c].z*f[c].z + f[c].w*f[c].w;
    }
    float rs = rsqrtf(wred_sum(vs) * (1.0f / D) + EPS);
    float s2 = 0.f;
    #pragma unroll
    for (int c = 0; c < 4; ++c) {
        int j = c * 256 + lane * 4;
        float4 gv = *(const float4*)&g1[j];
        float4 bv = *(const float4*)&b1[j];
        f[c].x = f[c].x * rs * gv.x + bv.x;
        f[c].y = f[c].y * rs * gv.y + bv.y;
        f[c].z = f[c].z * rs * gv.z + bv.z;
        f[c].w = f[c].w * rs * gv.w + bv.w;
        s2 += f[c].x + f[c].y + f[c].z + f[c].w;
    }
    float mu2 = wred_sum(s2) * (1.0f / D);
    float vs2 = 0.f;
    #pragma unroll
    for (int c = 0; c < 4; ++c) {
        f[c].x -= mu2; f[c].y -= mu2; f[c].z -= mu2; f[c].w -= mu2;
        vs2 += f[c].x*f[c].x + f[c].y*f[c].y + f[c].z*f[c].z + f[c].w*f[c].w;
    }
    float rs2 = rsqrtf(wred_sum(vs2) * (1.0f / D) + EPS);
    float s3 = 0.f;
    #pragma unroll
    for (int c = 0; c < 4; ++c) {
        int j = c * 256 + lane * 4;
        float4 gv = *(const float4*)&g2[j];
        float4 bv = *(const float4*)&b2g[j];
        float4 rv = *(const float4*)&res[ro + j];
        f[c].x = rv.x + f[c].x * rs2 * gv.x + bv.x;
        f[c].y = rv.y + f[c].y * rs2 * gv.y + bv.y;
        f[c].z = rv.z + f[c].z * rs2 * gv.z + bv.z;
        f[c].w = rv.w + f[c].w * rs2 * gv.w + bv.w;
        *(float4*)&xout[ro + j] = f[c];
        s3 += f[c].x + f[c].y + f[c].z + f[c].w;
    }
    float mu3 = wred_sum(s3) * (1.0f / D);
    float vs3 = 0.f;
    #pragma unroll
    for (int c = 0; c < 4; ++c) {
        f[c].x -= mu3; f[c].y -= mu3; f[c].z -= mu3; f[c].w -= mu3;
        vs3 += f[c].x*f[c].x + f[c].y*f[c].y + f[c].z*f[c].z + f[c].w*f[c].w;
    }
    float rs3 = rsqrtf(wred_sum(vs3) * (1.0f / D) + EPS);
    #pragma unroll
    for (int c = 0; c < 4; ++c) {
        int j = c * 256 + lane * 4;
        float4 gv = *(const float4*)&gn[j];
        float4 bv = *(const float4*)&bn[j];
        union { ushort4 u4; __hip_bfloat16 h[4]; } pk;
        pk.h[0] = __float2bfloat16(f[c].x * rs3 * gv.x + bv.x);
        pk.h[1] = __float2bfloat16(f[c].y * rs3 * gv.y + bv.y);
        pk.h[2] = __float2bfloat16(f[c].z * rs3 * gv.z + bv.z);
        pk.h[3] = __float2bfloat16(f[c].w * rs3 * gv.w + bv.w);
        *(ushort4*)&xnout[ro + j] = pk.u4;
    }
}

// ---------------------------------------------------------------------------
// tiled transpose + fp32->bf16: in [R][C] f32 -> out [C][R] bf16
// ---------------------------------------------------------------------------
__global__ __launch_bounds__(256) void transpose_bf16_kernel(
        const float* __restrict__ in, __hip_bfloat16* __restrict__ out,
        int R, int C, size_t zin, size_t zout) {
    __shared__ float t[32][33];
    in += (size_t)blockIdx.z * zin; out += (size_t)blockIdx.z * zout;
    int tx = threadIdx.x & 31, ty = threadIdx.x >> 5;
    int c0 = blockIdx.x * 32, r0 = blockIdx.y * 32;
    #pragma unroll
    for (int i = 0; i < 4; ++i)
        t[ty + i * 8][tx] = in[(size_t)(r0 + ty + i * 8) * C + c0 + tx];
    __syncthreads();
    #pragma unroll
    for (int i = 0; i < 4; ++i)
        out[(size_t)(c0 + ty + i * 8) * R + r0 + tx] = __float2bfloat16(t[tx][ty + i * 8]);
}

// ---------------------------------------------------------------------------
// q/k/v weight transpose in ONE launch
// ---------------------------------------------------------------------------
__global__ __launch_bounds__(256) void transpose_qkv_kernel(
        const float* __restrict__ Wq, const float* __restrict__ Wk,
        const float* __restrict__ Wv, short* __restrict__ outT) {
    __shared__ float t[32][33];
    int z = blockIdx.z;
    int which = z >> 4, h = z & 15;
    const float* in = (which == 0 ? Wq : which == 1 ? Wk : Wv) + (size_t)h * D * HS;
    __hip_bfloat16* out = (__hip_bfloat16*)outT + ((size_t)which * H + h) * HS * D;
    int tx = threadIdx.x & 31, ty = threadIdx.x >> 5;
    int c0 = blockIdx.x * 32, r0 = blockIdx.y * 32;
    #pragma unroll
    for (int i = 0; i < 4; ++i)
        t[ty + i * 8][tx] = in[(size_t)(r0 + ty + i * 8) * HS + c0 + tx];
    __syncthreads();
    #pragma unroll
    for (int i = 0; i < 4; ++i)
        out[(size_t)(c0 + ty + i * 8) * D + r0 + tx] = __float2bfloat16(t[tx][ty + i * 8]);
}

// ---------------------------------------------------------------------------
// bf16->bf16 transpose for V: in [T][HS] per bh -> out [HS][T]
// ---------------------------------------------------------------------------
__global__ __launch_bounds__(256) void transpose_v_kernel(const short* __restrict__ in,
        short* __restrict__ out) {
    __shared__ short t[32][33];
    int z = blockIdx.z;
    in  += (size_t)z * T * HS;
    out += (size_t)z * HS * T;
    int tx = threadIdx.x & 31, ty = threadIdx.x >> 5;
    int c0 = blockIdx.x * 32, r0 = blockIdx.y * 32;
    #pragma unroll
    for (int i = 0; i < 4; ++i)
        t[ty + i * 8][tx] = in[(size_t)(r0 + ty + i * 8) * HS + c0 + tx];
    __syncthreads();
    #pragma unroll
    for (int i = 0; i < 4; ++i)
        out[(size_t)(c0 + ty + i * 8) * T + r0 + tx] = t[tx][ty + i * 8];
}

// ---------------------------------------------------------------------------
// 8-phase 256x256 bf16 MFMA GEMM (m201-style).  C = epi(A @ BT^T + bias).
// 512 thr = 8 waves (2M x 4N); per-wave C = 128x64; BK=64 split into 2 khalves.
// LDS: [buf][kh][256 rows][32 k] for A and B (4 x 16KB each side = 128 KB).
// One stage unit per phase; counted vmcnt(4) gate once per K-tile, followed
// by an s_barrier BEFORE phase-0 ds_reads (vmcnt is per-wave; without the
// barrier a fast wave reads rows staged by a slow wave's in-flight loads —
// the R7 race).  Row swizzle: 64B rows, col16 ^= ((row>>1)&3)<<4 (2-way=free).
// EPI: 0 f32+bias -> C0 ; 2 leaky -> bf16 Cbf.  M fixed = 2048 (8 M-tiles).
// ---------------------------------------------------------------------------
template<int EPI>
__global__ __launch_bounds__(512, 2) void mm256_kernel(
        const short* __restrict__ A, const short* __restrict__ BT,
        const float* __restrict__ bias0, float* __restrict__ C0,
        __hip_bfloat16* __restrict__ Cbf, int N, int Kloop, int lda) {
    __shared__ __align__(16) char LA[2][2][256 * 64];
    __shared__ __align__(16) char LB[2][2][256 * 64];
    int tid = threadIdx.x;
    int lane = tid & 63, wid = tid >> 6;
    int wr = wid >> 2, wc = wid & 3;
    int l15 = lane & 15, l16 = lane >> 4;

    // bijective XCD swizzle (m204), M-major tile order (Mtiles = 8)
    int nwg = gridDim.x;
    int bid = blockIdx.x;
    int q = nwg >> 3, r = nwg & 7;
    int xcd = bid & 7, loc = bid >> 3;
    int wg = (xcd < r ? xcd * (q + 1) : r * (q + 1) + (xcd - r) * q) + loc;
    int m0 = (wg & 7) * 256;
    int n0 = (wg >> 3) * 256;

    const size_t lda2 = (size_t)lda * 2;
    const char* Agc = (const char*)A + (size_t)m0 * lda2;
    const char* Bgc = (const char*)BT + (size_t)n0 * lda2;

    f32x4 acc[8][4] = {};
    bf16x8 af[8], bfr[2];

    auto stA = [&](int buf, int kh, int kt) {
        #pragma unroll
        for (int i = 0; i < 2; ++i) {
            int o = i * 8192 + tid * 16;
            int row = o >> 6, col = o & 63;
            gload16(Agc + (size_t)row * lda2 + kt * 128 + kh * 64 +
                    (col ^ (((row >> 1) & 3) << 4)), LA[buf][kh] + o);
        }
    };
    auto stB = [&](int buf, int kh, int kt) {
        #pragma unroll
        for (int i = 0; i < 2; ++i) {
            int o = i * 8192 + tid * 16;
            int row = o >> 6, col = o & 63;
            gload16(Bgc + (size_t)row * lda2 + kt * 128 + kh * 64 +
                    (col ^ (((row >> 1) & 3) << 4)), LB[buf][kh] + o);
        }
    };
    auto rdA = [&](int buf, int kk) {
        #pragma unroll
        for (int mf = 0; mf < 8; ++mf) {
            int row = wr * 128 + mf * 16 + l15;
            af[mf] = *(const bf16x8*)(LA[buf][kk] + row * 64 +
                      ((l16 * 16) ^ (((row >> 1) & 3) << 4)));
        }
    };
    auto rdB = [&](int buf, int kk, int nh) {
        #pragma unroll
        for (int nf = 0; nf < 2; ++nf) {
            int row = wc * 64 + nh * 32 + nf * 16 + l15;
            bfr[nf] = *(const bf16x8*)(LB[buf][kk] + row * 64 +
                       ((l16 * 16) ^ (((row >> 1) & 3) << 4)));
        }
    };
    auto mfma16 = [&](int nh) {
        __builtin_amdgcn_s_setprio(1);
        #pragma unroll
        for (int mf = 0; mf < 8; ++mf) {
            acc[mf][nh * 2 + 0] = __builtin_amdgcn_mfma_f32_16x16x32_bf16(
                af[mf], bfr[0], acc[mf][nh * 2 + 0], 0, 0, 0);
            acc[mf][nh * 2 + 1] = __builtin_amdgcn_mfma_f32_16x16x32_bf16(
                af[mf], bfr[1], acc[mf][nh * 2 + 1], 0, 0, 0);
        }
        __builtin_amdgcn_s_setprio(0);
        __builtin_amdgcn_s_barrier();
    };

    const int NT = Kloop / 64;
    // prologue: tile0 fully + A0,B0 of tile1
    stA(0, 0, 0); stB(0, 0, 0); stA(0, 1, 0); stB(0, 1, 0);
    stA(1, 0, 1); stB(1, 0, 1);

    for (int t = 0; t < NT; ++t) {
        int buf = t & 1;
        if (t + 1 < NT) { asm volatile("s_waitcnt vmcnt(4)" ::: "memory"); }
        else            { asm volatile("s_waitcnt vmcnt(0)" ::: "memory"); }
        __builtin_amdgcn_sched_barrier(0);
        __builtin_amdgcn_s_barrier();        // ALL waves passed the vmcnt gate
        __builtin_amdgcn_sched_barrier(0);
        // phase 0: kk=0, nh=0 ; stage A-kh1 of t+1
        rdA(buf, 0); rdB(buf, 0, 0);
        if (t + 1 < NT) stA(buf ^ 1, 1, t + 1);
        __builtin_amdgcn_s_barrier();
        asm volatile("s_waitcnt lgkmcnt(0)" ::: "memory");
        __builtin_amdgcn_sched_barrier(0);
        mfma16(0);
        // phase 1: kk=0, nh=1 ; stage B-kh1 of t+1
        rdB(buf, 0, 1);
        if (t + 1 < NT) stB(buf ^ 1, 1, t + 1);
        __builtin_amdgcn_s_barrier();
        asm volatile("s_waitcnt lgkmcnt(0)" ::: "memory");
        __builtin_amdgcn_sched_barrier(0);
        mfma16(1);
        // phase 2: kk=1, nh=0 ; stage A-kh0 of t+2
        rdA(buf, 1); rdB(buf, 1, 0);
        if (t + 2 < NT) stA(buf, 0, t + 2);
        __builtin_amdgcn_s_barrier();
        asm volatile("s_waitcnt lgkmcnt(0)" ::: "memory");
        __builtin_amdgcn_sched_barrier(0);
        mfma16(0);
        // phase 3: kk=1, nh=1 ; stage B-kh0 of t+2
        rdB(buf, 1, 1);
        if (t + 2 < NT) stB(buf, 0, t + 2);
        __builtin_amdgcn_s_barrier();
        asm volatile("s_waitcnt lgkmcnt(0)" ::: "memory");
        __builtin_amdgcn_sched_barrier(0);
        mfma16(1);
    }

    // epilogue
    #pragma unroll
    for (int mf = 0; mf < 8; ++mf) {
        #pragma unroll
        for (int nf = 0; nf < 4; ++nf) {
            int col = n0 + wc * 64 + nf * 16 + l15;
            float bv = bias0[col];
            #pragma unroll
            for (int rr = 0; rr < 4; ++rr) {
                int row = m0 + wr * 128 + mf * 16 + l16 * 4 + rr;
                float v = acc[mf][nf][rr] + bv;
                if (EPI == 0) {
                    C0[(size_t)row * N + col] = v;
                } else {
                    v = v > 0.f ? v : 0.01f * v;
                    Cbf[(size_t)row * N + col] = __float2bfloat16(v);
                }
            }
        }
    }
}

// ---------------------------------------------------------------------------
// bf16 MFMA GEMM (128-tile, double-buffered counted-vmcnt) — qkv/proj/W2.
// EPI: 0 f32 C0 ; 1 +res f32 C0 ; 2 leaky bf16 Cbf ; 3 qkv scatter bf16 ;
//      4 raw partial f32 -> C0 + z*M*N
// ---------------------------------------------------------------------------
template<int BM, int EPI>
__global__ __launch_bounds__(256) void mm_bf16_kernel(
        const short* __restrict__ A, const short* __restrict__ BT,
        const float* __restrict__ bias0, const float* __restrict__ bias1,
        const float* __restrict__ bias2, const float* __restrict__ res,
        float* __restrict__ C0, float* __restrict__ C1, float* __restrict__ C2,
        __hip_bfloat16* __restrict__ Cbf, int N, int Kloop, int lda) {
    constexpr int MI = BM / 32;
    __shared__ __align__(16) char As[2][BM * 128];
    __shared__ __align__(16) char Bs[2][128 * 128];
    int nwg = gridDim.x * gridDim.y;
    int bid = blockIdx.y * gridDim.x + blockIdx.x;
    int bx = blockIdx.x, by = blockIdx.y;
    if (!(nwg & 7)) {
        int s = (bid & 7) * (nwg >> 3) + (bid >> 3);
        bx = s % gridDim.x; by = s / gridDim.x;
    }
    int tid = threadIdx.x;
    int lane = tid & 63, wid = tid >> 6;
    int wr = wid >> 1, wc = wid & 1;
    int l15 = lane & 15, l16 = lane >> 4;
    int m0 = bx * BM, n0 = by * 128;
    f32x4 acc[MI][4] = {};

    const size_t lda2 = (size_t)lda * 2;
    const char* Agc = (const char*)A + (size_t)m0 * lda2 + (size_t)blockIdx.z * Kloop * 2;
    const char* Bgc = (const char*)BT + (size_t)n0 * lda2 + (size_t)blockIdx.z * Kloop * 2;

    auto stage = [&](int buf, int kbyte) {
        #pragma unroll
        for (int i = 0; i < BM / 32; ++i) {
            int o = i * 4096 + tid * 16;
            int row = o >> 7, col = o & 127;
            gload16(Agc + (size_t)row * lda2 + kbyte + (col ^ ((row & 7) << 4)),
                    As[buf] + o);
        }
        #pragma unroll
        for (int i = 0; i < 4; ++i) {
            int o = i * 4096 + tid * 16;
            int row = o >> 7, col = o & 127;
            gload16(Bgc + (size_t)row * lda2 + kbyte + (col ^ ((row & 7) << 4)),
                    Bs[buf] + o);
        }
    };
    auto compute = [&](int buf) {
        #pragma unroll
        for (int kk = 0; kk < 2; ++kk) {
            bf16x8 af[MI], bfr[4];
            #pragma unroll
            for (int mi = 0; mi < MI; ++mi) {
                int row = wr * (BM / 2) + mi * 16 + l15;
                af[mi] = *(const bf16x8*)(As[buf] + row * 128 +
                          ((kk * 64 + l16 * 16) ^ ((row & 7) << 4)));
            }
            #pragma unroll
            for (int ni = 0; ni < 4; ++ni) {
                int row = wc * 64 + ni * 16 + l15;
                bfr[ni] = *(const bf16x8*)(Bs[buf] + row * 128 +
                          ((kk * 64 + l16 * 16) ^ ((row & 7) << 4)));
            }
            __builtin_amdgcn_s_setprio(1);
            #pragma unroll
            for (int mi = 0; mi < MI; ++mi)
                #pragma unroll
                for (int ni = 0; ni < 4; ++ni)
                    acc[mi][ni] = __builtin_amdgcn_mfma_f32_16x16x32_bf16(
                        af[mi], bfr[ni], acc[mi][ni], 0, 0, 0);
            __builtin_amdgcn_s_setprio(0);
        }
    };

    const int NT = Kloop / 64;
    stage(0, 0);
    stage(1, 128);
    for (int t = 0; t < NT; ++t) {
        if (t < NT - 1) {
            if constexpr (BM == 128) asm volatile("s_waitcnt vmcnt(8)" ::: "memory");
            else                     asm volatile("s_waitcnt vmcnt(6)" ::: "memory");
        } else {
            asm volatile("s_waitcnt vmcnt(0)" ::: "memory");
        }
        __builtin_amdgcn_sched_barrier(0);
        __builtin_amdgcn_s_barrier();
        __builtin_amdgcn_sched_barrier(0);
        compute(t & 1);
        __builtin_amdgcn_s_barrier();
        __builtin_amdgcn_sched_barrier(0);
        if (t + 2 < NT) stage(t & 1, (t + 2) * 128);
    }

    int rbase = m0 + wr * (BM / 2) + l16 * 4;
    int cbase = n0 + wc * 64 + l15;
    size_t zoff = (EPI == 4) ? (size_t)blockIdx.z * M * N : 0;
    #pragma unroll
    for (int mi = 0; mi < MI; ++mi) {
        #pragma unroll
        for (int ni = 0; ni < 4; ++ni) {
            int col = cbase + ni * 16;
            float bv = 0.f;
            if (EPI == 3) {
                int z = col >> 10, nn = col & 1023;
                bv = (z == 0 ? bias0 : z == 1 ? bias1 : bias2)[nn];
            } else if (EPI != 4) bv = bias0[col];
            #pragma unroll
            for (int r = 0; r < 4; ++r) {
                int row = rbase + mi * 16 + r;
                float v = acc[mi][ni][r] + bv;
                if (EPI == 0) {
                    C0[(size_t)row * N + col] = v;
                } else if (EPI == 1) {
                    C0[(size_t)row * N + col] = v + res[(size_t)row * N + col];
                } else if (EPI == 2) {
                    v = v > 0.f ? v : 0.01f * v;
                    Cbf[(size_t)row * N + col] = __float2bfloat16(v);
                } else if (EPI == 4) {
                    C0[zoff + (size_t)row * N + col] = v;
                } else {
                    int z = col >> 10;
                    int hh = (col >> 6) & 15, e = col & 63;
                    int b = row >> 10, t2 = row & (T - 1);
                    __hip_bfloat16* dst = (__hip_bfloat16*)(z == 0 ? C0 : (z == 1 ? C1 : C2));
                    dst[(((size_t)(b * H + hh)) * T + t2) * HS + e] = __float2bfloat16(v);
                }
            }
        }
    }
}

// ---------------------------------------------------------------------------
// MFMA flash attention, bf16, KVBLK=128. grid (T/64, B*H), 4 waves.
// ---------------------------------------------------------------------------
template<int CAUSAL>
__global__ __launch_bounds__(256) void attn_mfma_kernel(
        const short* __restrict__ q, const short* __restrict__ k,
        const short* __restrict__ vt, __hip_bfloat16* __restrict__ att) {
    __shared__ __align__(16) short Ks[128 * 64];
    __shared__ __align__(16) short Vs[64 * 128];
    __shared__ __align__(16) short Ps[4][16 * 128];
    int bh = blockIdx.y;
    int bI = bh >> 4, h = bh & 15;
    int tix = blockIdx.x;
    if (CAUSAL) tix = (tix & 1) ? (15 - (tix >> 1)) : (tix >> 1);
    int t0 = tix * 64;
    int tid = threadIdx.x;
    int lane = tid & 63, w = tid >> 6;
    int l15 = lane & 15, l16 = lane >> 4;

    const short* Qg = q + ((size_t)bh * T + t0 + w * 16 + l15) * HS + l16 * 8;
    bf16x8 qf0 = *(const bf16x8*)Qg;
    bf16x8 qf1 = *(const bf16x8*)(Qg + 32);

    const char* Kg = (const char*)(k + (size_t)bh * T * HS);
    const char* Vg = (const char*)(vt + (size_t)bh * HS * T);

    float m_run[4] = {-1e30f, -1e30f, -1e30f, -1e30f};
    float l_run[4] = {0.f, 0.f, 0.f, 0.f};
    f32x4 acc_o[4] = {};
    char* Pw = (char*)Ps[w];
    int pswz = l15 << 4;

    int n_tiles = CAUSAL ? (t0 / 128 + 1) : (T / 128);
    for (int it = 0; it < n_tiles; ++it) {
        int s0 = it * 128;
        __syncthreads();
        #pragma unroll
        for (int i = 0; i < 4; ++i) {
            int o = i * 4096 + tid * 16;
            int row = o >> 7, bir = o & 127;
            gload16(Kg + (size_t)(s0 + row) * 128 + (bir ^ ((row & 7) << 4)),
                    (char*)Ks + o);
        }
        #pragma unroll
        for (int i = 0; i < 4; ++i) {
            int o = i * 4096 + tid * 16;
            int row = o >> 8, bb = o & 255;
            gload16(Vg + (size_t)row * 2048 + s0 * 2 + (bb ^ ((row & 15) << 4)),
                    (char*)Vs + o);
        }
        __syncthreads();

        f32x4 acc_s[8] = {};
        __builtin_amdgcn_s_setprio(1);
        #pragma unroll
        for (int c = 0; c < 8; ++c) {
            int row = c * 16 + l15;
            const char* kb_ = (const char*)Ks + row * 128;
            int swz = (row & 7) << 4;
            bf16x8 kf0 = *(const bf16x8*)(kb_ + ((l16 * 16) ^ swz));
            bf16x8 kf1 = *(const bf16x8*)(kb_ + ((64 + l16 * 16) ^ swz));
            acc_s[c] = __builtin_amdgcn_mfma_f32_16x16x32_bf16(qf0, kf0, acc_s[c], 0, 0, 0);
            acc_s[c] = __builtin_amdgcn_mfma_f32_16x16x32_bf16(qf1, kf1, acc_s[c], 0, 0, 0);
        }
        __builtin_amdgcn_s_setprio(0);

        bool domask = CAUSAL && (it == n_tiles - 1);
        #pragma unroll
        for (int r = 0; r < 4; ++r) {
            float sc[8];
            #pragma unroll
            for (int c = 0; c < 8; ++c) {
                float s = acc_s[c][r];
                if (domask && (s0 + c * 16 + l15) > (t0 + w * 16 + l16 * 4 + r)) s = -1e30f;
                sc[c] = s;
            }
            float tm = fmaxf(fmaxf(fmaxf(sc[0], sc[1]), fmaxf(sc[2], sc[3])),
                             fmaxf(fmaxf(sc[4], sc[5]), fmaxf(sc[6], sc[7])));
            tm = fmaxf(tm, __shfl_xor(tm, 1, 16));
            tm = fmaxf(tm, __shfl_xor(tm, 2, 16));
            tm = fmaxf(tm, __shfl_xor(tm, 4, 16));
            tm = fmaxf(tm, __shfl_xor(tm, 8, 16));
            float mn = fmaxf(m_run[r], tm);
            int prow = l16 * 4 + r;
            int pswzr = prow << 4;
            float ls = 0.f;
            #pragma unroll
            for (int c = 0; c < 8; ++c) {
                float pv = __expf(0.125f * (sc[c] - mn));
                int pbyte = prow * 256 + (((c * 16 + l15) * 2) ^ pswzr);
                *(__hip_bfloat16*)(Pw + pbyte) = __float2bfloat16(pv);
                ls += pv;
            }
            ls += __shfl_xor(ls, 1, 16);
            ls += __shfl_xor(ls, 2, 16);
            ls += __shfl_xor(ls, 4, 16);
            ls += __shfl_xor(ls, 8, 16);
            float alpha = __expf(0.125f * (m_run[r] - mn));
            l_run[r] = l_run[r] * alpha + ls;
            m_run[r] = mn;
            acc_o[0][r] *= alpha; acc_o[1][r] *= alpha;
            acc_o[2][r] *= alpha; acc_o[3][r] *= alpha;
        }

        const char* Pb = Pw + l15 * 256;
        bf16x8 pa[4];
        #pragma unroll
        for (int t = 0; t < 4; ++t)
            pa[t] = *(const bf16x8*)(Pb + ((t * 64 + l16 * 16) ^ pswz));
        __builtin_amdgcn_s_setprio(1);
        #pragma unroll
        for (int ni = 0; ni < 4; ++ni) {
            int row = ni * 16 + l15;
            const char* vb_ = (const char*)Vs + row * 256;
            int swz = (row & 15) << 4;
            #pragma unroll
            for (int t = 0; t < 4; ++t) {
                bf16x8 vf = *(const bf16x8*)(vb_ + ((t * 64 + l16 * 16) ^ swz));
                acc_o[ni] = __builtin_amdgcn_mfma_f32_16x16x32_bf16(pa[t], vf, acc_o[ni], 0, 0, 0);
            }
        }
        __builtin_amdgcn_s_setprio(0);
    }

    float inv[4];
    #pragma unroll
    for (int r = 0; r < 4; ++r) inv[r] = 1.0f / l_run[r];
    #pragma unroll
    for (int ni = 0; ni < 4; ++ni) {
        #pragma unroll
        for (int r = 0; r < 4; ++r) {
            size_t orow = ((size_t)(bI * T) + t0 + w * 16 + l16 * 4 + r) * D
                        + h * HS + ni * 16 + l15;
            att[orow] = __float2bfloat16(acc_o[ni][r] * inv[r]);
        }
    }
}

// ---------------------------------------------------------------------------
extern "C" void kernel_launch(void* const* d_in, const int* in_sizes, int n_in,
                              void* d_out, int out_size, void* d_ws, size_t ws_size,
                              hipStream_t stream) {
    const int*   idx     = (const int*)d_in[0];
    const float* tok_emb = (const float*)d_in[1];
    const float* pos_emb = (const float*)d_in[2];
    const float* Wq_u = (const float*)d_in[3],  *bq_u = (const float*)d_in[4];
    const float* Wk_u = (const float*)d_in[5],  *bk_u = (const float*)d_in[6];
    const float* Wv_u = (const float*)d_in[7],  *bv_u = (const float*)d_in[8];
    const float* Wp_u = (const float*)d_in[9],  *bp_u = (const float*)d_in[10];
    const float* Wq_m = (const float*)d_in[11], *bq_m = (const float*)d_in[12];
    const float* Wk_m = (const float*)d_in[13], *bk_m = (const float*)d_in[14];
    const float* Wv_m = (const float*)d_in[15], *bv_m = (const float*)d_in[16];
    const float* Wp_m = (const float*)d_in[17], *bp_m = (const float*)d_in[18];
    const float* W1   = (const float*)d_in[19], *b1   = (const float*)d_in[20];
    const float* W2   = (const float*)d_in[21], *b2   = (const float*)d_in[22];
    const float* lnf_g = (const float*)d_in[23], *lnf_b = (const float*)d_in[24];
    const float* n1_g  = (const float*)d_in[25], *n1_b  = (const float*)d_in[26];
    const float* n2_g  = (const float*)d_in[27], *n2_b  = (const float*)d_in[28];
    const float* nf_g  = (const float*)d_in[29], *nf_b  = (const float*)d_in[30];
    const float* Wfin  = (const float*)d_in[31], *bfin  = (const float*)d_in[32];
    float* out = (float*)d_out;

    char* p = (char*)d_ws;
    auto alloc = [&](size_t bytes) { char* r = p; p += (bytes + 255) & ~255ull; return r; };
    float* x    = (float*)alloc((size_t)M * D * 4);
    float* x2   = (float*)alloc((size_t)M * D * 4);
    float* w2p  = (float*)alloc((size_t)4 * M * D * 4);
    short* qbf  = (short*)alloc((size_t)M * D * 2);
    short* kbf  = (short*)alloc((size_t)M * D * 2);
    short* vbf  = (short*)alloc((size_t)M * D * 2);
    short* vtb  = (short*)alloc((size_t)M * D * 2);
    short* xnb  = (short*)alloc((size_t)M * D * 2);
    short* attb = (short*)alloc((size_t)M * D * 2);
    short* hb   = (short*)alloc((size_t)M * DFF * 2);
    short* WqkvT= (short*)alloc((size_t)3 * 1024 * 1024 * 2);
    short* WpT  = (short*)alloc((size_t)1024 * 1024 * 2);
    short* W1T  = (short*)alloc((size_t)D * DFF * 2);
    short* W2T  = (short*)alloc((size_t)DFF * D * 2);
    short* WfT  = (short*)alloc((size_t)D * V * 2);

    embed_kernel<<<M, 256, 0, stream>>>(idx, tok_emb, pos_emb, x);
    ln_bf16_w4_kernel<<<M / 4, 256, 0, stream>>>(x, n1_g, n1_b, (__hip_bfloat16*)xnb);
    transpose_bf16_kernel<<<dim3(V / 32, D / 32, 1), 256, 0, stream>>>(
        Wfin, (__hip_bfloat16*)WfT, D, V, 0, 0);

    for (int l = 0; l < LNUM; ++l) {
        const float *n1g = n1_g + l * D, *n1b = n1_b + l * D;
        const float *n2g = n2_g + l * D, *n2b = n2_b + l * D;
        const float *lfg = lnf_g + l * D, *lfb = lnf_b + l * D;
        const float *W1l = W1 + (size_t)l * D * DFF, *b1l = b1 + l * DFF;
        const float *W2l = W2 + (size_t)l * DFF * D, *b2l = b2 + l * D;
        transpose_bf16_kernel<<<dim3(DFF / 32, D / 32, 1), 256, 0, stream>>>(
            W1l, (__hip_bfloat16*)W1T, D, DFF, 0, 0);
        transpose_bf16_kernel<<<dim3(D / 32, DFF / 32, 1), 256, 0, stream>>>(
            W2l, (__hip_bfloat16*)W2T, DFF, D, 0, 0);
        for (int half = 0; half < 2; ++half) {
            const float *Wq_, *bq_, *Wk_, *bk_, *Wv_, *bv_, *Wp_, *bp_;
            if (half == 0) { Wq_ = Wq_u; bq_ = bq_u; Wk_ = Wk_u; bk_ = bk_u;
                             Wv_ = Wv_u; bv_ = bv_u; Wp_ = Wp_u; bp_ = bp_u; }
            else           { Wq_ = Wq_m; bq_ = bq_m; Wk_ = Wk_m; bk_ = bk_m;
                             Wv_ = Wv_m; bv_ = bv_m; Wp_ = Wp_m; bp_ = bp_m; }
            Wq_ += (size_t)l * H * D * HS;  bq_ += l * H * HS;
            Wk_ += (size_t)l * H * D * HS;  bk_ += l * H * HS;
            Wv_ += (size_t)l * H * D * HS;  bv_ += l * H * HS;
            Wp_ += (size_t)l * D * D;       bp_ += l * D;

            transpose_qkv_kernel<<<dim3(HS / 32, D / 32, 48), 256, 0, stream>>>(
                Wq_, Wk_, Wv_, WqkvT);
            transpose_bf16_kernel<<<dim3(D / 32, D / 32, 1), 256, 0, stream>>>(
                Wp_, (__hip_bfloat16*)WpT, D, D, 0, 0);

            // q,k,v = xn @ Wqkv -> bf16 [B,H,T,HS]
            mm_bf16_kernel<128, 3><<<dim3(M / 128, 3072 / 128), 256, 0, stream>>>(
                xnb, WqkvT, bq_, bk_, bv_, nullptr,
                (float*)qbf, (float*)kbf, (float*)vbf, nullptr, 3072, D, D);
            transpose_v_kernel<<<dim3(HS / 32, T / 32, BB * H), 256, 0, stream>>>(vbf, vtb);
            if (half == 0)
                attn_mfma_kernel<0><<<dim3(T / 64, BB * H), 256, 0, stream>>>(
                    qbf, kbf, vtb, (__hip_bfloat16*)attb);
            else
                attn_mfma_kernel<1><<<dim3(T / 64, BB * H), 256, 0, stream>>>(
                    qbf, kbf, vtb, (__hip_bfloat16*)attb);
            // x2 = x + att @ Wp + bp
            mm_bf16_kernel<64, 1><<<dim3(M / 64, D / 128), 256, 0, stream>>>(
                attb, WpT, bp_, nullptr, nullptr, x, x2, nullptr, nullptr, nullptr, D, D, D);
            // xn = ln(x2, n2) -> bf16
            ln_bf16_w4_kernel<<<M / 4, 256, 0, stream>>>(x2, n2g, n2b, (__hip_bfloat16*)xnb);
            // h = leaky(xn @ W1 + b1) -> bf16  (8-phase 256^2)
            mm256_kernel<2><<<(M / 256) * (DFF / 256), 512, 0, stream>>>(
                xnb, W1T, b1l, nullptr, (__hip_bfloat16*)hb, DFF, D, D);
            // W2 split-K x4 -> partials
            mm_bf16_kernel<128, 4><<<dim3(M / 128, D / 128, 4), 256, 0, stream>>>(
                hb, W2T, nullptr, nullptr, nullptr, nullptr, w2p, nullptr, nullptr,
                nullptr, D, DFF / 4, DFF);
            const float* og = half ? n2g : n1g;
            const float* ob = half ? n2b : n1b;
            const float* gn; const float* bn;
            if (half == 0)      { gn = n1g; bn = n1b; }
            else if (l < LNUM-1){ gn = n1_g + (l+1)*D; bn = n1_b + (l+1)*D; }
            else                { gn = nf_g; bn = nf_b; }
            ffn_tail_kernel<4><<<M / 4, 256, 0, stream>>>(
                w2p, b2l, lfg, lfb, og, ob, x2, x, gn, bn, (__hip_bfloat16*)xnb);
        }
    }
    // vocab head: 8-phase 256^2
    mm256_kernel<0><<<(M / 256) * (V / 256), 512, 0, stream>>>(
        xnb, WfT, bfin, out, nullptr, V, D, D);
}

// Round 9
// 1518.844 us; speedup vs baseline: 7.6872x; 1.0459x over previous
//
#include <hip/hip_runtime.h>
#include <hip/hip_bf16.h>
#include <math.h>

#define LNUM 4
#define H 16
#define D 1024
#define HS 64
#define DFF 5120
#define V 32000
#define BB 2
#define T 1024
#define M (BB*T)          // 2048 token rows
#define EPS 1e-5f

typedef __attribute__((ext_vector_type(8))) short bf16x8;
typedef __attribute__((ext_vector_type(4))) float f32x4;

// async global->LDS, 16B per lane (wave-uniform LDS base + lane*16)
__device__ __forceinline__ void gload16(const void* g, void* l) {
    __builtin_amdgcn_global_load_lds(
        (const __attribute__((address_space(1))) void*)g,
        (__attribute__((address_space(3))) void*)l, 16, 0, 0);
}

__device__ __forceinline__ float wred_sum(float v) {
    #pragma unroll
    for (int off = 32; off; off >>= 1) v += __shfl_xor(v, off, 64);
    return v;
}

// ---------------------------------------------------------------------------
// embed + first pre-attn LN fused (wave-per-row, 4 rows/block)
// writes x (f32, residual stream) and xn (bf16, LN'd with layer-0 n1)
// ---------------------------------------------------------------------------
__global__ __launch_bounds__(256) void embed_ln_kernel(const int* __restrict__ idx,
        const float* __restrict__ tok, const float* __restrict__ pos,
        const float* __restrict__ g, const float* __restrict__ b,
        float* __restrict__ x, __hip_bfloat16* __restrict__ xn) {
    int w = threadIdx.x >> 6, lane = threadIdx.x & 63;
    int row = blockIdx.x * 4 + w;
    int t = row & (T - 1);
    int tok_id = idx[row];
    const float* tp = tok + (size_t)tok_id * D;
    const float* pp = pos + (size_t)t * D;
    float4 xv[4];
    float s = 0.f;
    #pragma unroll
    for (int c = 0; c < 4; ++c) {
        int j = c * 256 + lane * 4;
        float4 a = *(const float4*)&tp[j];
        float4 p = *(const float4*)&pp[j];
        a.x += p.x; a.y += p.y; a.z += p.z; a.w += p.w;
        *(float4*)&x[(size_t)row * D + j] = a;
        xv[c] = a;
        s += a.x + a.y + a.z + a.w;
    }
    float mu = wred_sum(s) * (1.0f / D);
    float vs = 0.f;
    #pragma unroll
    for (int c = 0; c < 4; ++c) {
        xv[c].x -= mu; xv[c].y -= mu; xv[c].z -= mu; xv[c].w -= mu;
        vs += xv[c].x*xv[c].x + xv[c].y*xv[c].y + xv[c].z*xv[c].z + xv[c].w*xv[c].w;
    }
    float rs = rsqrtf(wred_sum(vs) * (1.0f / D) + EPS);
    #pragma unroll
    for (int c = 0; c < 4; ++c) {
        int j = c * 256 + lane * 4;
        float4 gv = *(const float4*)&g[j];
        float4 bv = *(const float4*)&b[j];
        union { ushort4 u4; __hip_bfloat16 h[4]; } pk;
        pk.h[0] = __float2bfloat16(xv[c].x * rs * gv.x + bv.x);
        pk.h[1] = __float2bfloat16(xv[c].y * rs * gv.y + bv.y);
        pk.h[2] = __float2bfloat16(xv[c].z * rs * gv.z + bv.z);
        pk.h[3] = __float2bfloat16(xv[c].w * rs * gv.w + bv.w);
        *(ushort4*)&xn[(size_t)row * D + j] = pk.u4;
    }
}

// ---------------------------------------------------------------------------
// wave-per-row LN -> bf16 (4 rows per 256-thread block, no barriers)
// ---------------------------------------------------------------------------
__global__ __launch_bounds__(256) void ln_bf16_w4_kernel(const float* __restrict__ in,
        const float* __restrict__ g, const float* __restrict__ b,
        __hip_bfloat16* __restrict__ out) {
    int w = threadIdx.x >> 6, lane = threadIdx.x & 63;
    int row = blockIdx.x * 4 + w;
    const float* rp = in + (size_t)row * D;
    float4 xv[4];
    float s = 0.f;
    #pragma unroll
    for (int c = 0; c < 4; ++c) {
        xv[c] = *(const float4*)&rp[c * 256 + lane * 4];
        s += xv[c].x + xv[c].y + xv[c].z + xv[c].w;
    }
    float mu = wred_sum(s) * (1.0f / D);
    float vs = 0.f;
    #pragma unroll
    for (int c = 0; c < 4; ++c) {
        xv[c].x -= mu; xv[c].y -= mu; xv[c].z -= mu; xv[c].w -= mu;
        vs += xv[c].x*xv[c].x + xv[c].y*xv[c].y + xv[c].z*xv[c].z + xv[c].w*xv[c].w;
    }
    float rs = rsqrtf(wred_sum(vs) * (1.0f / D) + EPS);
    #pragma unroll
    for (int c = 0; c < 4; ++c) {
        int j = c * 256 + lane * 4;
        float4 gv = *(const float4*)&g[j];
        float4 bv = *(const float4*)&b[j];
        union { ushort4 u4; __hip_bfloat16 h[4]; } pk;
        pk.h[0] = __float2bfloat16(xv[c].x * rs * gv.x + bv.x);
        pk.h[1] = __float2bfloat16(xv[c].y * rs * gv.y + bv.y);
        pk.h[2] = __float2bfloat16(xv[c].z * rs * gv.z + bv.z);
        pk.h[3] = __float2bfloat16(xv[c].w * rs * gv.w + bv.w);
        *(ushort4*)&out[(size_t)row * D + j] = pk.u4;
    }
}

// ---------------------------------------------------------------------------
// FFN tail, fused:  f = sum(partials)+b2 ; x = res + ln(ln(f,g1,b1),g2,b2g)
// then xn = ln(x, gn, bn) -> bf16
// ---------------------------------------------------------------------------
template<int NP>
__global__ __launch_bounds__(256) void ffn_tail_kernel(
        const float* __restrict__ part, const float* __restrict__ b2,
        const float* __restrict__ g1, const float* __restrict__ b1,
        const float* __restrict__ g2, const float* __restrict__ b2g,
        const float* __restrict__ res, float* __restrict__ xout,
        const float* __restrict__ gn, const float* __restrict__ bn,
        __hip_bfloat16* __restrict__ xnout) {
    const size_t MD = (size_t)M * D;
    int w = threadIdx.x >> 6, lane = threadIdx.x & 63;
    int row = blockIdx.x * 4 + w;
    size_t ro = (size_t)row * D;
    float4 f[4];
    float s = 0.f;
    #pragma unroll
    for (int c = 0; c < 4; ++c) {
        int j = c * 256 + lane * 4;
        float4 acc = *(const float4*)&b2[j];
        #pragma unroll
        for (int pI = 0; pI < NP; ++pI) {
            float4 pv = *(const float4*)&part[pI * MD + ro + j];
            acc.x += pv.x; acc.y += pv.y; acc.z += pv.z; acc.w += pv.w;
        }
        f[c] = acc;
        s += acc.x + acc.y + acc.z + acc.w;
    }
    float mu = wred_sum(s) * (1.0f / D);
    float vs = 0.f;
    #pragma unroll
    for (int c = 0; c < 4; ++c) {
        f[c].x -= mu; f[c].y -= mu; f[c].z -= mu; f[c].w -= mu;
        vs += f[c].x*f[c].x + f[c].y*f[c].y + f[c].z*f[c].z + f[c].w*f[c].w;
    }
    float rs = rsqrtf(wred_sum(vs) * (1.0f / D) + EPS);
    float s2 = 0.f;
    #pragma unroll
    for (int c = 0; c < 4; ++c) {
        int j = c * 256 + lane * 4;
        float4 gv = *(const float4*)&g1[j];
        float4 bv = *(const float4*)&b1[j];
        f[c].x = f[c].x * rs * gv.x + bv.x;
        f[c].y = f[c].y * rs * gv.y + bv.y;
        f[c].z = f[c].z * rs * gv.z + bv.z;
        f[c].w = f[c].w * rs * gv.w + bv.w;
        s2 += f[c].x + f[c].y + f[c].z + f[c].w;
    }
    float mu2 = wred_sum(s2) * (1.0f / D);
    float vs2 = 0.f;
    #pragma unroll
    for (int c = 0; c < 4; ++c) {
        f[c].x -= mu2; f[c].y -= mu2; f[c].z -= mu2; f[c].w -= mu2;
        vs2 += f[c].x*f[c].x + f[c].y*f[c].y + f[c].z*f[c].z + f[c].w*f[c].w;
    }
    float rs2 = rsqrtf(wred_sum(vs2) * (1.0f / D) + EPS);
    float s3 = 0.f;
    #pragma unroll
    for (int c = 0; c < 4; ++c) {
        int j = c * 256 + lane * 4;
        float4 gv = *(const float4*)&g2[j];
        float4 bv = *(const float4*)&b2g[j];
        float4 rv = *(const float4*)&res[ro + j];
        f[c].x = rv.x + f[c].x * rs2 * gv.x + bv.x;
        f[c].y = rv.y + f[c].y * rs2 * gv.y + bv.y;
        f[c].z = rv.z + f[c].z * rs2 * gv.z + bv.z;
        f[c].w = rv.w + f[c].w * rs2 * gv.w + bv.w;
        *(float4*)&xout[ro + j] = f[c];
        s3 += f[c].x + f[c].y + f[c].z + f[c].w;
    }
    float mu3 = wred_sum(s3) * (1.0f / D);
    float vs3 = 0.f;
    #pragma unroll
    for (int c = 0; c < 4; ++c) {
        f[c].x -= mu3; f[c].y -= mu3; f[c].z -= mu3; f[c].w -= mu3;
        vs3 += f[c].x*f[c].x + f[c].y*f[c].y + f[c].z*f[c].z + f[c].w*f[c].w;
    }
    float rs3 = rsqrtf(wred_sum(vs3) * (1.0f / D) + EPS);
    #pragma unroll
    for (int c = 0; c < 4; ++c) {
        int j = c * 256 + lane * 4;
        float4 gv = *(const float4*)&gn[j];
        float4 bv = *(const float4*)&bn[j];
        union { ushort4 u4; __hip_bfloat16 h[4]; } pk;
        pk.h[0] = __float2bfloat16(f[c].x * rs3 * gv.x + bv.x);
        pk.h[1] = __float2bfloat16(f[c].y * rs3 * gv.y + bv.y);
        pk.h[2] = __float2bfloat16(f[c].z * rs3 * gv.z + bv.z);
        pk.h[3] = __float2bfloat16(f[c].w * rs3 * gv.w + bv.w);
        *(ushort4*)&xnout[ro + j] = pk.u4;
    }
}

// ---------------------------------------------------------------------------
// tiled transpose + fp32->bf16: in [R][C] f32 -> out [C][R] bf16 (Wfin)
// ---------------------------------------------------------------------------
__global__ __launch_bounds__(256) void transpose_bf16_kernel(
        const float* __restrict__ in, __hip_bfloat16* __restrict__ out,
        int R, int C) {
    __shared__ float t[32][33];
    int tx = threadIdx.x & 31, ty = threadIdx.x >> 5;
    int c0 = blockIdx.x * 32, r0 = blockIdx.y * 32;
    #pragma unroll
    for (int i = 0; i < 4; ++i)
        t[ty + i * 8][tx] = in[(size_t)(r0 + ty + i * 8) * C + c0 + tx];
    __syncthreads();
    #pragma unroll
    for (int i = 0; i < 4; ++i)
        out[(size_t)(c0 + ty + i * 8) * R + r0 + tx] = __float2bfloat16(t[tx][ty + i * 8]);
}

// ---------------------------------------------------------------------------
// per-half weight prep in ONE launch: grid (32, 32, 4)
// z<3: qkv which=z: in [H][D][HS] f32 -> WqkvT [3*H][HS][D] bf16
// z=3: Wp [D][D] -> WpT [D][D]^T bf16
// ---------------------------------------------------------------------------
__global__ __launch_bounds__(256) void trans_qkvp_kernel(
        const float* __restrict__ Wq, const float* __restrict__ Wk,
        const float* __restrict__ Wv, const float* __restrict__ Wp,
        short* __restrict__ qkvT, short* __restrict__ WpT) {
    __shared__ float t[32][33];
    int tx = threadIdx.x & 31, ty = threadIdx.x >> 5;
    int z = blockIdx.z;
    const float* in;
    __hip_bfloat16* out;
    int inC, outC;
    int r0 = blockIdx.y * 32, c0;
    if (z < 3) {
        int c0g = blockIdx.x * 32;
        int h = c0g >> 6;
        c0 = c0g & 63;
        in = (z == 0 ? Wq : z == 1 ? Wk : Wv) + (size_t)h * D * HS;
        out = (__hip_bfloat16*)qkvT + ((size_t)z * H + h) * HS * D;
        inC = HS; outC = D;
    } else {
        c0 = blockIdx.x * 32;
        in = Wp; out = (__hip_bfloat16*)WpT;
        inC = D; outC = D;
    }
    #pragma unroll
    for (int i = 0; i < 4; ++i)
        t[ty + i * 8][tx] = in[(size_t)(r0 + ty + i * 8) * inC + c0 + tx];
    __syncthreads();
    #pragma unroll
    for (int i = 0; i < 4; ++i)
        out[(size_t)(c0 + ty + i * 8) * outC + r0 + tx] = __float2bfloat16(t[tx][ty + i * 8]);
}

// ---------------------------------------------------------------------------
// per-layer W1+W2 transpose in ONE launch: grid (160, 32, 2)
// z=0: W1 [D][DFF] -> W1T [DFF][D] ; z=1: W2 [DFF][D] -> W2T [D][DFF]
// ---------------------------------------------------------------------------
__global__ __launch_bounds__(256) void trans_w12_kernel(
        const float* __restrict__ W1, const float* __restrict__ W2,
        short* __restrict__ W1T, short* __restrict__ W2T) {
    __shared__ float t[32][33];
    int tx = threadIdx.x & 31, ty = threadIdx.x >> 5;
    int z = blockIdx.z;
    const float* in; __hip_bfloat16* out;
    int inC, outC, r0, c0;
    if (z == 0) { in = W1; out = (__hip_bfloat16*)W1T; inC = DFF; outC = D;
                  r0 = blockIdx.y * 32; c0 = blockIdx.x * 32; }
    else        { in = W2; out = (__hip_bfloat16*)W2T; inC = D; outC = DFF;
                  r0 = blockIdx.x * 32; c0 = blockIdx.y * 32; }
    #pragma unroll
    for (int i = 0; i < 4; ++i)
        t[ty + i * 8][tx] = in[(size_t)(r0 + ty + i * 8) * inC + c0 + tx];
    __syncthreads();
    #pragma unroll
    for (int i = 0; i < 4; ++i)
        out[(size_t)(c0 + ty + i * 8) * outC + r0 + tx] = __float2bfloat16(t[tx][ty + i * 8]);
}

// ---------------------------------------------------------------------------
// bf16->bf16 transpose for V: in [T][HS] per bh -> out [HS][T]
// ---------------------------------------------------------------------------
__global__ __launch_bounds__(256) void transpose_v_kernel(const short* __restrict__ in,
        short* __restrict__ out) {
    __shared__ short t[32][33];
    int z = blockIdx.z;
    in  += (size_t)z * T * HS;
    out += (size_t)z * HS * T;
    int tx = threadIdx.x & 31, ty = threadIdx.x >> 5;
    int c0 = blockIdx.x * 32, r0 = blockIdx.y * 32;
    #pragma unroll
    for (int i = 0; i < 4; ++i)
        t[ty + i * 8][tx] = in[(size_t)(r0 + ty + i * 8) * HS + c0 + tx];
    __syncthreads();
    #pragma unroll
    for (int i = 0; i < 4; ++i)
        out[(size_t)(c0 + ty + i * 8) * T + r0 + tx] = t[tx][ty + i * 8];
}

// ---------------------------------------------------------------------------
// 256x256 bf16 MFMA GEMM, 2 phases per K-tile (BK=64, one phase per k-half).
// 512 thr = 8 waves (2M x 4N); per-wave C = 128x64.
// LDS: [buf][kh][256][32] A and B (128 KB). Per phase: 12 ds_read_b128 +
// 4 gload16 stage + 32-MFMA cluster + 1 barrier. Counted vmcnt(4) once per
// K-tile, placed before phase-B's existing barrier (drains tile t+1 fully,
// keeps t+2-kh0 in flight). Compiler auto-inserts lgkmcnt for ds_read->MFMA.
// Row swizzle: 64B rows, col ^= ((row>>1)&3)<<4 on both stage-src and reads.
// EPI: 0 f32+bias -> C0 ; 2 leaky -> bf16 Cbf.  M fixed = 2048 (8 M-tiles).
// ---------------------------------------------------------------------------
template<int EPI>
__global__ __launch_bounds__(512, 2) void mm256_kernel(
        const short* __restrict__ A, const short* __restrict__ BT,
        const float* __restrict__ bias0, float* __restrict__ C0,
        __hip_bfloat16* __restrict__ Cbf, int N, int Kloop, int lda) {
    __shared__ __align__(16) char LA[2][2][256 * 64];
    __shared__ __align__(16) char LB[2][2][256 * 64];
    int tid = threadIdx.x;
    int lane = tid & 63, wid = tid >> 6;
    int wr = wid >> 2, wc = wid & 3;
    int l15 = lane & 15, l16 = lane >> 4;

    // bijective XCD swizzle (m204), M-major tile order (Mtiles = 8)
    int nwg = gridDim.x;
    int bid = blockIdx.x;
    int q = nwg >> 3, r = nwg & 7;
    int xcd = bid & 7, loc = bid >> 3;
    int wg = (xcd < r ? xcd * (q + 1) : r * (q + 1) + (xcd - r) * q) + loc;
    int m0 = (wg & 7) * 256;
    int n0 = (wg >> 3) * 256;

    const size_t lda2 = (size_t)lda * 2;
    const char* Agc = (const char*)A + (size_t)m0 * lda2;
    const char* Bgc = (const char*)BT + (size_t)n0 * lda2;

    f32x4 acc[8][4] = {};
    bf16x8 af[8], bfr[4];

    auto stA = [&](int buf, int kh, int kt) {
        #pragma unroll
        for (int i = 0; i < 2; ++i) {
            int o = i * 8192 + tid * 16;
            int row = o >> 6, col = o & 63;
            gload16(Agc + (size_t)row * lda2 + kt * 128 + kh * 64 +
                    (col ^ (((row >> 1) & 3) << 4)), LA[buf][kh] + o);
        }
    };
    auto stB = [&](int buf, int kh, int kt) {
        #pragma unroll
        for (int i = 0; i < 2; ++i) {
            int o = i * 8192 + tid * 16;
            int row = o >> 6, col = o & 63;
            gload16(Bgc + (size_t)row * lda2 + kt * 128 + kh * 64 +
                    (col ^ (((row >> 1) & 3) << 4)), LB[buf][kh] + o);
        }
    };
    auto rdA = [&](int buf, int kk) {
        #pragma unroll
        for (int mf = 0; mf < 8; ++mf) {
            int row = wr * 128 + mf * 16 + l15;
            af[mf] = *(const bf16x8*)(LA[buf][kk] + row * 64 +
                      ((l16 * 16) ^ (((row >> 1) & 3) << 4)));
        }
    };
    auto rdB4 = [&](int buf, int kk) {
        #pragma unroll
        for (int nf = 0; nf < 4; ++nf) {
            int row = wc * 64 + nf * 16 + l15;
            bfr[nf] = *(const bf16x8*)(LB[buf][kk] + row * 64 +
                       ((l16 * 16) ^ (((row >> 1) & 3) << 4)));
        }
    };
    auto mfma32 = [&]() {
        __builtin_amdgcn_s_setprio(1);
        #pragma unroll
        for (int mf = 0; mf < 8; ++mf)
            #pragma unroll
            for (int nf = 0; nf < 4; ++nf)
                acc[mf][nf] = __builtin_amdgcn_mfma_f32_16x16x32_bf16(
                    af[mf], bfr[nf], acc[mf][nf], 0, 0, 0);
        __builtin_amdgcn_s_setprio(0);
    };

    const int NT = Kloop / 64;
    // prologue: tile0 both halves + tile1 kh0  (12 gloads/thread)
    stA(0, 0, 0); stB(0, 0, 0); stA(0, 1, 0); stB(0, 1, 0);
    stA(1, 0, 1); stB(1, 0, 1);
    asm volatile("s_waitcnt vmcnt(4)" ::: "memory");   // tile0 landed
    __builtin_amdgcn_sched_barrier(0);
    __builtin_amdgcn_s_barrier();
    __builtin_amdgcn_sched_barrier(0);

    for (int t = 0; t < NT; ++t) {
        int buf = t & 1;
        // phase A (kk=0): reads kh0; stage t+1 kh1 into buf^1
        rdA(buf, 0); rdB4(buf, 0);
        if (t + 1 < NT) { stA(buf ^ 1, 1, t + 1); stB(buf ^ 1, 1, t + 1); }
        mfma32();
        __builtin_amdgcn_sched_barrier(0);
        __builtin_amdgcn_s_barrier();      // kh0 reads done -> kh0 region free
        __builtin_amdgcn_sched_barrier(0);
        // phase B (kk=1): reads kh1; stage t+2 kh0 into buf (kh0 now free)
        rdA(buf, 1); rdB4(buf, 1);
        if (t + 2 < NT) { stA(buf, 0, t + 2); stB(buf, 0, t + 2); }
        mfma32();
        if (t + 2 < NT) { asm volatile("s_waitcnt vmcnt(4)" ::: "memory"); }
        else            { asm volatile("s_waitcnt vmcnt(0)" ::: "memory"); }
        __builtin_amdgcn_sched_barrier(0);
        __builtin_amdgcn_s_barrier();      // next tile fully landed for all
        __builtin_amdgcn_sched_barrier(0);
    }

    // epilogue
    #pragma unroll
    for (int mf = 0; mf < 8; ++mf) {
        #pragma unroll
        for (int nf = 0; nf < 4; ++nf) {
            int col = n0 + wc * 64 + nf * 16 + l15;
            float bv = bias0[col];
            #pragma unroll
            for (int rr = 0; rr < 4; ++rr) {
                int row = m0 + wr * 128 + mf * 16 + l16 * 4 + rr;
                float v = acc[mf][nf][rr] + bv;
                if (EPI == 0) {
                    C0[(size_t)row * N + col] = v;
                } else {
                    v = v > 0.f ? v : 0.01f * v;
                    Cbf[(size_t)row * N + col] = __float2bfloat16(v);
                }
            }
        }
    }
}

// ---------------------------------------------------------------------------
// bf16 MFMA GEMM (128-tile, double-buffered counted-vmcnt) — qkv/proj/W2.
// EPI: 0 f32 C0 ; 1 +res f32 C0 ; 2 leaky bf16 Cbf ; 3 qkv scatter bf16 ;
//      4 raw partial f32 -> C0 + z*M*N
// ---------------------------------------------------------------------------
template<int BM, int EPI>
__global__ __launch_bounds__(256) void mm_bf16_kernel(
        const short* __restrict__ A, const short* __restrict__ BT,
        const float* __restrict__ bias0, const float* __restrict__ bias1,
        const float* __restrict__ bias2, const float* __restrict__ res,
        float* __restrict__ C0, float* __restrict__ C1, float* __restrict__ C2,
        __hip_bfloat16* __restrict__ Cbf, int N, int Kloop, int lda) {
    constexpr int MI = BM / 32;
    __shared__ __align__(16) char As[2][BM * 128];
    __shared__ __align__(16) char Bs[2][128 * 128];
    int nwg = gridDim.x * gridDim.y;
    int bid = blockIdx.y * gridDim.x + blockIdx.x;
    int bx = blockIdx.x, by = blockIdx.y;
    if (!(nwg & 7)) {
        int s = (bid & 7) * (nwg >> 3) + (bid >> 3);
        bx = s % gridDim.x; by = s / gridDim.x;
    }
    int tid = threadIdx.x;
    int lane = tid & 63, wid = tid >> 6;
    int wr = wid >> 1, wc = wid & 1;
    int l15 = lane & 15, l16 = lane >> 4;
    int m0 = bx * BM, n0 = by * 128;
    f32x4 acc[MI][4] = {};

    const size_t lda2 = (size_t)lda * 2;
    const char* Agc = (const char*)A + (size_t)m0 * lda2 + (size_t)blockIdx.z * Kloop * 2;
    const char* Bgc = (const char*)BT + (size_t)n0 * lda2 + (size_t)blockIdx.z * Kloop * 2;

    auto stage = [&](int buf, int kbyte) {
        #pragma unroll
        for (int i = 0; i < BM / 32; ++i) {
            int o = i * 4096 + tid * 16;
            int row = o >> 7, col = o & 127;
            gload16(Agc + (size_t)row * lda2 + kbyte + (col ^ ((row & 7) << 4)),
                    As[buf] + o);
        }
        #pragma unroll
        for (int i = 0; i < 4; ++i) {
            int o = i * 4096 + tid * 16;
            int row = o >> 7, col = o & 127;
            gload16(Bgc + (size_t)row * lda2 + kbyte + (col ^ ((row & 7) << 4)),
                    Bs[buf] + o);
        }
    };
    auto compute = [&](int buf) {
        #pragma unroll
        for (int kk = 0; kk < 2; ++kk) {
            bf16x8 af[MI], bfr[4];
            #pragma unroll
            for (int mi = 0; mi < MI; ++mi) {
                int row = wr * (BM / 2) + mi * 16 + l15;
                af[mi] = *(const bf16x8*)(As[buf] + row * 128 +
                          ((kk * 64 + l16 * 16) ^ ((row & 7) << 4)));
            }
            #pragma unroll
            for (int ni = 0; ni < 4; ++ni) {
                int row = wc * 64 + ni * 16 + l15;
                bfr[ni] = *(const bf16x8*)(Bs[buf] + row * 128 +
                          ((kk * 64 + l16 * 16) ^ ((row & 7) << 4)));
            }
            __builtin_amdgcn_s_setprio(1);
            #pragma unroll
            for (int mi = 0; mi < MI; ++mi)
                #pragma unroll
                for (int ni = 0; ni < 4; ++ni)
                    acc[mi][ni] = __builtin_amdgcn_mfma_f32_16x16x32_bf16(
                        af[mi], bfr[ni], acc[mi][ni], 0, 0, 0);
            __builtin_amdgcn_s_setprio(0);
        }
    };

    const int NT = Kloop / 64;
    stage(0, 0);
    stage(1, 128);
    for (int t = 0; t < NT; ++t) {
        if (t < NT - 1) {
            if constexpr (BM == 128) asm volatile("s_waitcnt vmcnt(8)" ::: "memory");
            else                     asm volatile("s_waitcnt vmcnt(6)" ::: "memory");
        } else {
            asm volatile("s_waitcnt vmcnt(0)" ::: "memory");
        }
        __builtin_amdgcn_sched_barrier(0);
        __builtin_amdgcn_s_barrier();
        __builtin_amdgcn_sched_barrier(0);
        compute(t & 1);
        __builtin_amdgcn_s_barrier();
        __builtin_amdgcn_sched_barrier(0);
        if (t + 2 < NT) stage(t & 1, (t + 2) * 128);
    }

    int rbase = m0 + wr * (BM / 2) + l16 * 4;
    int cbase = n0 + wc * 64 + l15;
    size_t zoff = (EPI == 4) ? (size_t)blockIdx.z * M * N : 0;
    #pragma unroll
    for (int mi = 0; mi < MI; ++mi) {
        #pragma unroll
        for (int ni = 0; ni < 4; ++ni) {
            int col = cbase + ni * 16;
            float bv = 0.f;
            if (EPI == 3) {
                int z = col >> 10, nn = col & 1023;
                bv = (z == 0 ? bias0 : z == 1 ? bias1 : bias2)[nn];
            } else if (EPI != 4) bv = bias0[col];
            #pragma unroll
            for (int r = 0; r < 4; ++r) {
                int row = rbase + mi * 16 + r;
                float v = acc[mi][ni][r] + bv;
                if (EPI == 0) {
                    C0[(size_t)row * N + col] = v;
                } else if (EPI == 1) {
                    C0[(size_t)row * N + col] = v + res[(size_t)row * N + col];
                } else if (EPI == 2) {
                    v = v > 0.f ? v : 0.01f * v;
                    Cbf[(size_t)row * N + col] = __float2bfloat16(v);
                } else if (EPI == 4) {
                    C0[zoff + (size_t)row * N + col] = v;
                } else {
                    int z = col >> 10;
                    int hh = (col >> 6) & 15, e = col & 63;
                    int b = row >> 10, t2 = row & (T - 1);
                    __hip_bfloat16* dst = (__hip_bfloat16*)(z == 0 ? C0 : (z == 1 ? C1 : C2));
                    dst[(((size_t)(b * H + hh)) * T + t2) * HS + e] = __float2bfloat16(v);
                }
            }
        }
    }
}

// ---------------------------------------------------------------------------
// MFMA flash attention, bf16, KVBLK=128. grid (T/64, B*H), 4 waves.
// ---------------------------------------------------------------------------
template<int CAUSAL>
__global__ __launch_bounds__(256) void attn_mfma_kernel(
        const short* __restrict__ q, const short* __restrict__ k,
        const short* __restrict__ vt, __hip_bfloat16* __restrict__ att) {
    __shared__ __align__(16) short Ks[128 * 64];
    __shared__ __align__(16) short Vs[64 * 128];
    __shared__ __align__(16) short Ps[4][16 * 128];
    int bh = blockIdx.y;
    int bI = bh >> 4, h = bh & 15;
    int tix = blockIdx.x;
    if (CAUSAL) tix = (tix & 1) ? (15 - (tix >> 1)) : (tix >> 1);
    int t0 = tix * 64;
    int tid = threadIdx.x;
    int lane = tid & 63, w = tid >> 6;
    int l15 = lane & 15, l16 = lane >> 4;

    const short* Qg = q + ((size_t)bh * T + t0 + w * 16 + l15) * HS + l16 * 8;
    bf16x8 qf0 = *(const bf16x8*)Qg;
    bf16x8 qf1 = *(const bf16x8*)(Qg + 32);

    const char* Kg = (const char*)(k + (size_t)bh * T * HS);
    const char* Vg = (const char*)(vt + (size_t)bh * HS * T);

    float m_run[4] = {-1e30f, -1e30f, -1e30f, -1e30f};
    float l_run[4] = {0.f, 0.f, 0.f, 0.f};
    f32x4 acc_o[4] = {};
    char* Pw = (char*)Ps[w];
    int pswz = l15 << 4;

    int n_tiles = CAUSAL ? (t0 / 128 + 1) : (T / 128);
    for (int it = 0; it < n_tiles; ++it) {
        int s0 = it * 128;
        __syncthreads();
        #pragma unroll
        for (int i = 0; i < 4; ++i) {
            int o = i * 4096 + tid * 16;
            int row = o >> 7, bir = o & 127;
            gload16(Kg + (size_t)(s0 + row) * 128 + (bir ^ ((row & 7) << 4)),
                    (char*)Ks + o);
        }
        #pragma unroll
        for (int i = 0; i < 4; ++i) {
            int o = i * 4096 + tid * 16;
            int row = o >> 8, bb = o & 255;
            gload16(Vg + (size_t)row * 2048 + s0 * 2 + (bb ^ ((row & 15) << 4)),
                    (char*)Vs + o);
        }
        __syncthreads();

        f32x4 acc_s[8] = {};
        __builtin_amdgcn_s_setprio(1);
        #pragma unroll
        for (int c = 0; c < 8; ++c) {
            int row = c * 16 + l15;
            const char* kb_ = (const char*)Ks + row * 128;
            int swz = (row & 7) << 4;
            bf16x8 kf0 = *(const bf16x8*)(kb_ + ((l16 * 16) ^ swz));
            bf16x8 kf1 = *(const bf16x8*)(kb_ + ((64 + l16 * 16) ^ swz));
            acc_s[c] = __builtin_amdgcn_mfma_f32_16x16x32_bf16(qf0, kf0, acc_s[c], 0, 0, 0);
            acc_s[c] = __builtin_amdgcn_mfma_f32_16x16x32_bf16(qf1, kf1, acc_s[c], 0, 0, 0);
        }
        __builtin_amdgcn_s_setprio(0);

        bool domask = CAUSAL && (it == n_tiles - 1);
        #pragma unroll
        for (int r = 0; r < 4; ++r) {
            float sc[8];
            #pragma unroll
            for (int c = 0; c < 8; ++c) {
                float s = acc_s[c][r];
                if (domask && (s0 + c * 16 + l15) > (t0 + w * 16 + l16 * 4 + r)) s = -1e30f;
                sc[c] = s;
            }
            float tm = fmaxf(fmaxf(fmaxf(sc[0], sc[1]), fmaxf(sc[2], sc[3])),
                             fmaxf(fmaxf(sc[4], sc[5]), fmaxf(sc[6], sc[7])));
            tm = fmaxf(tm, __shfl_xor(tm, 1, 16));
            tm = fmaxf(tm, __shfl_xor(tm, 2, 16));
            tm = fmaxf(tm, __shfl_xor(tm, 4, 16));
            tm = fmaxf(tm, __shfl_xor(tm, 8, 16));
            float mn = fmaxf(m_run[r], tm);
            int prow = l16 * 4 + r;
            int pswzr = prow << 4;
            float ls = 0.f;
            #pragma unroll
            for (int c = 0; c < 8; ++c) {
                float pv = __expf(0.125f * (sc[c] - mn));
                int pbyte = prow * 256 + (((c * 16 + l15) * 2) ^ pswzr);
                *(__hip_bfloat16*)(Pw + pbyte) = __float2bfloat16(pv);
                ls += pv;
            }
            ls += __shfl_xor(ls, 1, 16);
            ls += __shfl_xor(ls, 2, 16);
            ls += __shfl_xor(ls, 4, 16);
            ls += __shfl_xor(ls, 8, 16);
            float alpha = __expf(0.125f * (m_run[r] - mn));
            l_run[r] = l_run[r] * alpha + ls;
            m_run[r] = mn;
            acc_o[0][r] *= alpha; acc_o[1][r] *= alpha;
            acc_o[2][r] *= alpha; acc_o[3][r] *= alpha;
        }

        const char* Pb = Pw + l15 * 256;
        bf16x8 pa[4];
        #pragma unroll
        for (int t = 0; t < 4; ++t)
            pa[t] = *(const bf16x8*)(Pb + ((t * 64 + l16 * 16) ^ pswz));
        __builtin_amdgcn_s_setprio(1);
        #pragma unroll
        for (int ni = 0; ni < 4; ++ni) {
            int row = ni * 16 + l15;
            const char* vb_ = (const char*)Vs + row * 256;
            int swz = (row & 15) << 4;
            #pragma unroll
            for (int t = 0; t < 4; ++t) {
                bf16x8 vf = *(const bf16x8*)(vb_ + ((t * 64 + l16 * 16) ^ swz));
                acc_o[ni] = __builtin_amdgcn_mfma_f32_16x16x32_bf16(pa[t], vf, acc_o[ni], 0, 0, 0);
            }
        }
        __builtin_amdgcn_s_setprio(0);
    }

    float inv[4];
    #pragma unroll
    for (int r = 0; r < 4; ++r) inv[r] = 1.0f / l_run[r];
    #pragma unroll
    for (int ni = 0; ni < 4; ++ni) {
        #pragma unroll
        for (int r = 0; r < 4; ++r) {
            size_t orow = ((size_t)(bI * T) + t0 + w * 16 + l16 * 4 + r) * D
                        + h * HS + ni * 16 + l15;
            att[orow] = __float2bfloat16(acc_o[ni][r] * inv[r]);
        }
    }
}

// ---------------------------------------------------------------------------
extern "C" void kernel_launch(void* const* d_in, const int* in_sizes, int n_in,
                              void* d_out, int out_size, void* d_ws, size_t ws_size,
                              hipStream_t stream) {
    const int*   idx     = (const int*)d_in[0];
    const float* tok_emb = (const float*)d_in[1];
    const float* pos_emb = (const float*)d_in[2];
    const float* Wq_u = (const float*)d_in[3],  *bq_u = (const float*)d_in[4];
    const float* Wk_u = (const float*)d_in[5],  *bk_u = (const float*)d_in[6];
    const float* Wv_u = (const float*)d_in[7],  *bv_u = (const float*)d_in[8];
    const float* Wp_u = (const float*)d_in[9],  *bp_u = (const float*)d_in[10];
    const float* Wq_m = (const float*)d_in[11], *bq_m = (const float*)d_in[12];
    const float* Wk_m = (const float*)d_in[13], *bk_m = (const float*)d_in[14];
    const float* Wv_m = (const float*)d_in[15], *bv_m = (const float*)d_in[16];
    const float* Wp_m = (const float*)d_in[17], *bp_m = (const float*)d_in[18];
    const float* W1   = (const float*)d_in[19], *b1   = (const float*)d_in[20];
    const float* W2   = (const float*)d_in[21], *b2   = (const float*)d_in[22];
    const float* lnf_g = (const float*)d_in[23], *lnf_b = (const float*)d_in[24];
    const float* n1_g  = (const float*)d_in[25], *n1_b  = (const float*)d_in[26];
    const float* n2_g  = (const float*)d_in[27], *n2_b  = (const float*)d_in[28];
    const float* nf_g  = (const float*)d_in[29], *nf_b  = (const float*)d_in[30];
    const float* Wfin  = (const float*)d_in[31], *bfin  = (const float*)d_in[32];
    float* out = (float*)d_out;

    char* p = (char*)d_ws;
    auto alloc = [&](size_t bytes) { char* r = p; p += (bytes + 255) & ~255ull; return r; };
    float* x    = (float*)alloc((size_t)M * D * 4);
    float* x2   = (float*)alloc((size_t)M * D * 4);
    float* w2p  = (float*)alloc((size_t)4 * M * D * 4);
    short* qbf  = (short*)alloc((size_t)M * D * 2);
    short* kbf  = (short*)alloc((size_t)M * D * 2);
    short* vbf  = (short*)alloc((size_t)M * D * 2);
    short* vtb  = (short*)alloc((size_t)M * D * 2);
    short* xnb  = (short*)alloc((size_t)M * D * 2);
    short* attb = (short*)alloc((size_t)M * D * 2);
    short* hb   = (short*)alloc((size_t)M * DFF * 2);
    short* WqkvT= (short*)alloc((size_t)3 * 1024 * 1024 * 2);
    short* WpT  = (short*)alloc((size_t)1024 * 1024 * 2);
    short* W1T  = (short*)alloc((size_t)D * DFF * 2);
    short* W2T  = (short*)alloc((size_t)DFF * D * 2);
    short* WfT  = (short*)alloc((size_t)D * V * 2);

    // embed + first pre-attn LN (layer-0 n1) fused
    embed_ln_kernel<<<M / 4, 256, 0, stream>>>(idx, tok_emb, pos_emb,
        n1_g, n1_b, x, (__hip_bfloat16*)xnb);
    transpose_bf16_kernel<<<dim3(V / 32, D / 32), 256, 0, stream>>>(
        Wfin, (__hip_bfloat16*)WfT, D, V);

    for (int l = 0; l < LNUM; ++l) {
        const float *n1g = n1_g + l * D, *n1b = n1_b + l * D;
        const float *n2g = n2_g + l * D, *n2b = n2_b + l * D;
        const float *lfg = lnf_g + l * D, *lfb = lnf_b + l * D;
        const float *W1l = W1 + (size_t)l * D * DFF, *b1l = b1 + l * DFF;
        const float *W2l = W2 + (size_t)l * DFF * D, *b2l = b2 + l * D;
        trans_w12_kernel<<<dim3(160, 32, 2), 256, 0, stream>>>(
            W1l, W2l, W1T, W2T);
        for (int half = 0; half < 2; ++half) {
            const float *Wq_, *bq_, *Wk_, *bk_, *Wv_, *bv_, *Wp_, *bp_;
            if (half == 0) { Wq_ = Wq_u; bq_ = bq_u; Wk_ = Wk_u; bk_ = bk_u;
                             Wv_ = Wv_u; bv_ = bv_u; Wp_ = Wp_u; bp_ = bp_u; }
            else           { Wq_ = Wq_m; bq_ = bq_m; Wk_ = Wk_m; bk_ = bk_m;
                             Wv_ = Wv_m; bv_ = bv_m; Wp_ = Wp_m; bp_ = bp_m; }
            Wq_ += (size_t)l * H * D * HS;  bq_ += l * H * HS;
            Wk_ += (size_t)l * H * D * HS;  bk_ += l * H * HS;
            Wv_ += (size_t)l * H * D * HS;  bv_ += l * H * HS;
            Wp_ += (size_t)l * D * D;       bp_ += l * D;

            trans_qkvp_kernel<<<dim3(32, 32, 4), 256, 0, stream>>>(
                Wq_, Wk_, Wv_, Wp_, WqkvT, WpT);

            // q,k,v = xn @ Wqkv -> bf16 [B,H,T,HS]
            mm_bf16_kernel<128, 3><<<dim3(M / 128, 3072 / 128), 256, 0, stream>>>(
                xnb, WqkvT, bq_, bk_, bv_, nullptr,
                (float*)qbf, (float*)kbf, (float*)vbf, nullptr, 3072, D, D);
            transpose_v_kernel<<<dim3(HS / 32, T / 32, BB * H), 256, 0, stream>>>(vbf, vtb);
            if (half == 0)
                attn_mfma_kernel<0><<<dim3(T / 64, BB * H), 256, 0, stream>>>(
                    qbf, kbf, vtb, (__hip_bfloat16*)attb);
            else
                attn_mfma_kernel<1><<<dim3(T / 64, BB * H), 256, 0, stream>>>(
                    qbf, kbf, vtb, (__hip_bfloat16*)attb);
            // x2 = x + att @ Wp + bp
            mm_bf16_kernel<64, 1><<<dim3(M / 64, D / 128), 256, 0, stream>>>(
                attb, WpT, bp_, nullptr, nullptr, x, x2, nullptr, nullptr, nullptr, D, D, D);
            // xn = ln(x2, n2) -> bf16
            ln_bf16_w4_kernel<<<M / 4, 256, 0, stream>>>(x2, n2g, n2b, (__hip_bfloat16*)xnb);
            // h = leaky(xn @ W1 + b1) -> bf16  (256^2, 2-phase counted)
            mm256_kernel<2><<<(M / 256) * (DFF / 256), 512, 0, stream>>>(
                xnb, W1T, b1l, nullptr, (__hip_bfloat16*)hb, DFF, D, D);
            // W2 split-K x4 -> partials
            mm_bf16_kernel<128, 4><<<dim3(M / 128, D / 128, 4), 256, 0, stream>>>(
                hb, W2T, nullptr, nullptr, nullptr, nullptr, w2p, nullptr, nullptr,
                nullptr, D, DFF / 4, DFF);
            const float* og = half ? n2g : n1g;
            const float* ob = half ? n2b : n1b;
            const float* gn; const float* bn;
            if (half == 0)      { gn = n1g; bn = n1b; }
            else if (l < LNUM-1){ gn = n1_g + (l+1)*D; bn = n1_b + (l+1)*D; }
            else                { gn = nf_g; bn = nf_b; }
            ffn_tail_kernel<4><<<M / 4, 256, 0, stream>>>(
                w2p, b2l, lfg, lfb, og, ob, x2, x, gn, bn, (__hip_bfloat16*)xnb);
        }
    }
    // vocab head: 256^2 2-phase counted
    mm256_kernel<0><<<(M / 256) * (V / 256), 512, 0, stream>>>(
        xnb, WfT, bfin, out, nullptr, V, D, D);
}